// Round 5
// baseline (895.027 us; speedup 1.0000x reference)
//
#include <hip/hip_runtime.h>
#include <math.h>
#include <stdint.h>

// Problem constants (fixed instance)
#define LSEQ 2048
#define DM   1024
#define DI   2048
#define NC   32     // scan chunks per sequence
#define CL   64     // scan chunk length (NC*CL == LSEQ)

// ---------------------------------------------------------------------------
// Workspace layout (float units). Total 62,914,560 floats = 251.7 MB.
//  X  [0,          16777216)  : x half of in_proj output; later delta (in place)
//  Z  [16777216,   33554432)  : z half
//  U  [33554432,   50331648)  : conv output u; scan_pass3 overwrites each slot
//                               with packed u32 (lo_bf16<<16 | hi_bf16) of y
//  S  [50331648,   58720256)  : A1' (hs split bf16) until gemm1 done, then
//                               cs(+xdbl split-K partials)/sdt/xdbl/feats/Aws
//  B1 [58720256,   62914560)  : B1' (in_proj split) -> B2' (out_proj split)
// ---------------------------------------------------------------------------
#define OFF_X     ((size_t)0)
#define OFF_Z     ((size_t)16777216)
#define OFF_U     ((size_t)33554432)
#define OFF_S     ((size_t)50331648)
#define OFF_CS    (OFF_S)                      // 4,194,304 floats (also xdbl partials)
#define OFF_SDT   (OFF_S + 4194304)            //   262,144
#define OFF_XDBL  (OFF_S + 4456448)            //   786,432
#define OFF_FEAT  (OFF_S + 5242880)            //    65,536
#define OFF_AWS   (OFF_S + 5308448)            //    32,768
#define OFF_B1    ((size_t)58720256)

__device__ __forceinline__ float silu_(float x) { return x / (1.f + __expf(-x)); }
__device__ __forceinline__ float softplus_(float x) {
  return fmaxf(x, 0.f) + log1pf(__expf(-fabsf(x)));
}
__device__ __forceinline__ unsigned short f2bf(float x) {
  unsigned int u = __float_as_uint(x);
  u += 0x7fffu + ((u >> 16) & 1u);      // RNE (inputs finite)
  return (unsigned short)(u >> 16);
}
__device__ __forceinline__ float bf2f(unsigned short h) {
  return __uint_as_float(((unsigned int)h) << 16);
}

typedef __attribute__((ext_vector_type(8))) short bf16x8;
typedef __attribute__((ext_vector_type(4))) float f32x4;

__device__ __forceinline__ void gl2lds16(const void* g, void* l) {
  __builtin_amdgcn_global_load_lds(
      (const __attribute__((address_space(1))) unsigned int*)(uintptr_t)g,
      (__attribute__((address_space(3))) unsigned int*)(uintptr_t)l,
      16, 0, 0);
}

// barrier that is also a compiler memory fence (NOT __syncthreads: that drains
// vmcnt(0) and kills the staged-load pipeline)
#define BARRIER_()                                   \
  do {                                               \
    asm volatile("" ::: "memory");                   \
    __builtin_amdgcn_s_barrier();                    \
    asm volatile("" ::: "memory");                   \
  } while (0)

// ---------------------------------------------------------------------------
// Split fp32 -> [hi | lo] bf16 per row, two tensors in one dispatch.
// Each thread handles ONE float4. Tensor a = first na4 float4-slots.
// ---------------------------------------------------------------------------
__global__ __launch_bounds__(256) void split2_w(
    const float* __restrict__ a, unsigned short* __restrict__ oa, int ksa,
    size_t na4,
    const float* __restrict__ b, unsigned short* __restrict__ ob, int ksb)
{
  size_t i4 = ((size_t)blockIdx.x << 8) + threadIdx.x;
  const float* src; unsigned short* dst; int ks;
  if (i4 < na4) { src = a; dst = oa; ks = ksa; }
  else          { src = b; dst = ob; ks = ksb; i4 -= na4; }
  const size_t flat = i4 << 2;
  const int K = 1 << ks;
  const size_t row = flat >> ks;
  const int k = (int)(flat & (size_t)(K - 1));
  float4 v = *(const float4*)(src + flat);
  float f[4] = {v.x, v.y, v.z, v.w};
  unsigned short h[4], lo[4];
#pragma unroll
  for (int c = 0; c < 4; ++c) { h[c] = f2bf(f[c]); lo[c] = f2bf(f[c] - bf2f(h[c])); }
  unsigned short* o = dst + (row << (ks + 1)) + k;
  *(uint2*)(o)     = make_uint2((unsigned)h[0]  | ((unsigned)h[1]  << 16),
                                (unsigned)h[2]  | ((unsigned)h[3]  << 16));
  *(uint2*)(o + K) = make_uint2((unsigned)lo[0] | ((unsigned)lo[1] << 16),
                                (unsigned)lo[2] | ((unsigned)lo[3] << 16));
}

// ---------------------------------------------------------------------------
// 256x256-tile phase-split split-bf16 MFMA GEMM: C[M,N] = A·B^T.
// T3+T4+T5 schedule (counted vmcnt, never drained in main loop; setprio
// around MFMA clusters; 1 barrier per phase). BK=32, 8 waves (2M x 4N),
// per-wave 128x64 output (8x4 frags). 4 phases per K-tile, one C-quadrant
// each: 24 MFMA + 12 ds_read_b128 (NPASS=3) between barriers.
// LDS: [2 dbuf][4 tensors AH,BH,AL,BL][256x32] = 128 KiB (NPASS=3).
// XOR chunk swizzle (measured 0 bank conflicts): stage slot c of row r holds
// global k-chunk c^((r>>1)&3); reader uses quad^((lm>>1)&3).
// ---------------------------------------------------------------------------
template <int NPASS, int MH, int NH>
__device__ __forceinline__ void phase_mfma(
    const unsigned short* __restrict__ shc, f32x4 (&acc)[8][4],
    int wm, int wn, int lm, int roff)
{
  bf16x8 aH[4], bH[2], aL[4], bL[2];
#pragma unroll
  for (int ii = 0; ii < 4; ++ii) {
    const int ar = (wm + (MH * 4 + ii) * 16 + lm) * 32 + roff;
    aH[ii] = *(const bf16x8*)(shc + ar);
    if constexpr (NPASS > 1) aL[ii] = *(const bf16x8*)(shc + 2 * 8192 + ar);
  }
#pragma unroll
  for (int jj = 0; jj < 2; ++jj) {
    const int br = (wn + (NH * 2 + jj) * 16 + lm) * 32 + roff;
    bH[jj] = *(const bf16x8*)(shc + 8192 + br);
    if constexpr (NPASS > 1) bL[jj] = *(const bf16x8*)(shc + 3 * 8192 + br);
  }
  __builtin_amdgcn_s_setprio(1);
#pragma unroll
  for (int ii = 0; ii < 4; ++ii)
#pragma unroll
    for (int jj = 0; jj < 2; ++jj) {
      const int i = MH * 4 + ii, j = NH * 2 + jj;
      acc[i][j] = __builtin_amdgcn_mfma_f32_16x16x32_bf16(aH[ii], bH[jj], acc[i][j], 0, 0, 0);
      if constexpr (NPASS > 1) {
        acc[i][j] = __builtin_amdgcn_mfma_f32_16x16x32_bf16(aH[ii], bL[jj], acc[i][j], 0, 0, 0);
        acc[i][j] = __builtin_amdgcn_mfma_f32_16x16x32_bf16(aL[ii], bH[jj], acc[i][j], 0, 0, 0);
      }
    }
  __builtin_amdgcn_s_setprio(0);
}

template <int NPASS>
__global__ __launch_bounds__(512, 2) void gemm_8ph(
    const unsigned short* __restrict__ Ap, const unsigned short* __restrict__ Bp,
    float* __restrict__ C, int K, int ldc)
{
  constexpr int NTEN = (NPASS > 1) ? 4 : 2;      // AH,BH[,AL,BL]
  __shared__ unsigned short sh[2][NTEN][256 * 32];
  const int tid = threadIdx.x;
  const int bn = blockIdx.x << 8;
  const int bm = blockIdx.y << 8;
  const int K2 = K * 2;
  const int wave = tid >> 6, lane = tid & 63;
  const int wm = (wave >> 2) << 7;               // 0 / 128
  const int wn = (wave & 3) << 6;                // 0 / 64 / 128 / 192
  const int lm = lane & 15, quad = lane >> 4;
  const int roff = ((quad ^ ((lm >> 1) & 3)) << 3);

  const int r0 = tid >> 2;
  const int kq = (((tid & 3) ^ ((r0 >> 1) & 3)) << 3);
  const unsigned short* a0 = Ap + (size_t)(bm + r0) * K2 + kq;        // rows 0-127
  const unsigned short* a1 = a0 + (size_t)128 * K2;                   // rows 128-255
  const unsigned short* b0 = Bp + (size_t)(bn + r0) * K2 + kq;
  const unsigned short* b1 = b0 + (size_t)128 * K2;
  const int ls0 = tid * 8, ls1 = 4096 + tid * 8; // ushort offsets in a tensor buf

  f32x4 acc[8][4] = {};
  const int NT = K >> 5;

  // prologue: stage tile 0 into buffer 0
  {
    unsigned short* s = &sh[0][0][0];
    gl2lds16(a0, s + ls0);
    gl2lds16(a1, s + ls1);
    if constexpr (NPASS > 1) {
      gl2lds16(a0 + K, s + 2 * 8192 + ls0);
      gl2lds16(a1 + K, s + 2 * 8192 + ls1);
    }
    gl2lds16(b0, s + 8192 + ls0);
    gl2lds16(b1, s + 8192 + ls1);
    if constexpr (NPASS > 1) {
      gl2lds16(b0 + K, s + 3 * 8192 + ls0);
      gl2lds16(b1 + K, s + 3 * 8192 + ls1);
    }
  }

  for (int t = 0; t < NT - 1; ++t) {
    const unsigned short* cur = &sh[t & 1][0][0];
    unsigned short* nxt = &sh[(t + 1) & 1][0][0];
    const int kn = (t + 1) << 5;

    // ---- phase 0: issue next-tile A units, publish current tile ----
    gl2lds16(a0 + kn, nxt + ls0);
    gl2lds16(a1 + kn, nxt + ls1);
    if constexpr (NPASS > 1) {
      gl2lds16(a0 + K + kn, nxt + 2 * 8192 + ls0);
      gl2lds16(a1 + K + kn, nxt + 2 * 8192 + ls1);
      asm volatile("s_waitcnt vmcnt(4)" ::: "memory");  // current tile's 8 landed
    } else {
      asm volatile("s_waitcnt vmcnt(2)" ::: "memory");  // current tile's 4 landed
    }
    BARRIER_();
    phase_mfma<NPASS, 0, 0>(cur, acc, wm, wn, lm, roff);
    BARRIER_();
    // ---- phase 1: issue next-tile B units ----
    gl2lds16(b0 + kn, nxt + 8192 + ls0);
    gl2lds16(b1 + kn, nxt + 8192 + ls1);
    if constexpr (NPASS > 1) {
      gl2lds16(b0 + K + kn, nxt + 3 * 8192 + ls0);
      gl2lds16(b1 + K + kn, nxt + 3 * 8192 + ls1);
    }
    phase_mfma<NPASS, 0, 1>(cur, acc, wm, wn, lm, roff);
    BARRIER_();
    // ---- phase 2 ----
    phase_mfma<NPASS, 1, 0>(cur, acc, wm, wn, lm, roff);
    BARRIER_();
    // ---- phase 3 (trailing barrier protects next tile's stage overwrite) ----
    phase_mfma<NPASS, 1, 1>(cur, acc, wm, wn, lm, roff);
    BARRIER_();
  }

  // peeled last tile: nothing left to issue -> drain is allowed here only
  {
    const unsigned short* cur = &sh[(NT - 1) & 1][0][0];
    asm volatile("s_waitcnt vmcnt(0)" ::: "memory");
    BARRIER_();
    phase_mfma<NPASS, 0, 0>(cur, acc, wm, wn, lm, roff);
    BARRIER_();
    phase_mfma<NPASS, 0, 1>(cur, acc, wm, wn, lm, roff);
    BARRIER_();
    phase_mfma<NPASS, 1, 0>(cur, acc, wm, wn, lm, roff);
    BARRIER_();
    phase_mfma<NPASS, 1, 1>(cur, acc, wm, wn, lm, roff);
  }

  // epilogue: C/D layout col=lane&15 (n), row=quad*4+reg (m)
#pragma unroll
  for (int i = 0; i < 8; ++i) {
    const int m = bm + wm + i * 16 + quad * 4;
#pragma unroll
    for (int j = 0; j < 4; ++j) {
      const int n = bn + wn + j * 16 + lm;
#pragma unroll
      for (int r = 0; r < 4; ++r)
        C[(size_t)(m + r) * ldc + n] = acc[i][j][r];
    }
  }
}

// ---------------------------------------------------------------------------
// gemm8 v3 (gemm8_pk): out[8192,1024] = y[8192,2048]·out_proj^T, 3-pass.
// A = PACKED u32 (lo<<16|hi) from scan_pass3, staged RAW into LDS via
// gl2lds16 (same bytes as hi+lo split); de-interleave at READ time with
// __byte_perm (1 v_perm_b32/word). Swizzle folded into the GLOBAL source
// address (LDS dest stays lane-linear): LDS 16B-slot (r,s) holds global
// unit s^(r&7); reader lane (lm,quad) reads slots (2q)^(r&7),(2q+1)^(r&7).
// Bank profile = 8 lanes / 4-bank window (same as proven split-B layout).
// BM=256 BN=128 -> grid 8x32 = 256 blocks = 1/CU; blockIdx.x = n-tile = XCD.
// 2 phases/K-tile (24 MFMA each), 3 barriers/tile; all 6 staging units
// (4 A + 2 B) issued once per tile -> vmcnt(6): full-tile prefetch lead for
// BOTH operands (rounds 2-3 failed with 1-phase lead on reg-staged A).
// MFMA order per acc: hiH, hiL, loH, k ascending -> same output as r2-r4.
// ---------------------------------------------------------------------------
template <int MH>
__device__ __forceinline__ void phase_pk(
    const unsigned int* __restrict__ ap,
    const unsigned short* __restrict__ bh, const unsigned short* __restrict__ bl,
    f32x4 (&acc)[8][2], int wm, int wn, int lm, int quad, int roffB)
{
  bf16x8 aH[4], aL[4], bH[2], bL[2];
#pragma unroll
  for (int ii = 0; ii < 4; ++ii) {
    const int r = wm + (MH * 4 + ii) * 16 + lm;
    const int s0 = (2 * quad) ^ (r & 7);
    const int s1 = (2 * quad + 1) ^ (r & 7);
    const uint4 w0 = *(const uint4*)(ap + ((size_t)(r * 8 + s0) << 2));
    const uint4 w1 = *(const uint4*)(ap + ((size_t)(r * 8 + s1) << 2));
    union { unsigned u[4]; bf16x8 v; } ch, cl;
    ch.u[0] = __byte_perm(w0.x, w0.y, 0x5410u);
    ch.u[1] = __byte_perm(w0.z, w0.w, 0x5410u);
    ch.u[2] = __byte_perm(w1.x, w1.y, 0x5410u);
    ch.u[3] = __byte_perm(w1.z, w1.w, 0x5410u);
    cl.u[0] = __byte_perm(w0.x, w0.y, 0x7632u);
    cl.u[1] = __byte_perm(w0.z, w0.w, 0x7632u);
    cl.u[2] = __byte_perm(w1.x, w1.y, 0x7632u);
    cl.u[3] = __byte_perm(w1.z, w1.w, 0x7632u);
    aH[ii] = ch.v;
    aL[ii] = cl.v;
  }
#pragma unroll
  for (int jj = 0; jj < 2; ++jj) {
    const int br = (wn + jj * 16 + lm) * 32 + roffB;
    bH[jj] = *(const bf16x8*)(bh + br);
    bL[jj] = *(const bf16x8*)(bl + br);
  }
  __builtin_amdgcn_s_setprio(1);
#pragma unroll
  for (int ii = 0; ii < 4; ++ii)
#pragma unroll
    for (int jj = 0; jj < 2; ++jj) {
      const int i = MH * 4 + ii;
      acc[i][jj] = __builtin_amdgcn_mfma_f32_16x16x32_bf16(aH[ii], bH[jj], acc[i][jj], 0, 0, 0);
      acc[i][jj] = __builtin_amdgcn_mfma_f32_16x16x32_bf16(aH[ii], bL[jj], acc[i][jj], 0, 0, 0);
      acc[i][jj] = __builtin_amdgcn_mfma_f32_16x16x32_bf16(aL[ii], bH[jj], acc[i][jj], 0, 0, 0);
    }
  __builtin_amdgcn_s_setprio(0);
}

__global__ __launch_bounds__(512, 2) void gemm8_pk(
    const unsigned int* __restrict__ Ay,   // [8192][2048] packed (lo<<16|hi)
    const unsigned short* __restrict__ Bp, // pre-split [1024][2*2048]
    float* __restrict__ C)
{
  constexpr int K = 2048, K2 = 4096, ldc = 1024, NT = 64;
  __shared__ unsigned int   APk[2][2048 * 4];     // 32 KiB per buf
  __shared__ unsigned short BHs[2][128 * 32];     // 8 KiB per buf
  __shared__ unsigned short BLs[2][128 * 32];
  const int tid = threadIdx.x;
  const int bn = blockIdx.x << 7;
  const int bm = blockIdx.y << 8;
  const int wave = tid >> 6, lane = tid & 63;
  const int wm = (wave >> 2) << 7;               // 0 / 128
  const int wn = (wave & 3) << 5;                // 0 / 32 / 64 / 96
  const int lm = lane & 15, quad = lane >> 4;
  const int roffB = ((quad ^ ((lm >> 1) & 3)) << 3);

  // A staging: thread -> 4 LDS 16B-slots l = j*512+tid; (r,s)=(l>>3, l&7);
  // content = global unit u = s^(r&7) (r&7 == (tid>>3)&7 for all j since
  // j*64 % 8 == 0). Global addr = Ay + (bm+r)*K + u*4 + t*32.
  const int ar0 = tid >> 3;
  const int au = (tid & 7) ^ (ar0 & 7);
  const unsigned int* ag = Ay + (size_t)(bm + ar0) * K + (au << 2);

  // B staging (128 rows x 32 k, split hi/lo): proven layout
  const int rb = tid >> 2;
  const int kqb = (((tid & 3) ^ ((rb >> 1) & 3)) << 3);
  const unsigned short* bg = Bp + (size_t)(bn + rb) * K2 + kqb;
  const int lsb = tid * 8;

  f32x4 acc[8][2] = {};

#define STAGE_(buf, kn) do {                                                   \
    gl2lds16(ag + (kn),                  &APk[buf][((size_t)(0 * 512 + tid)) << 2]); \
    gl2lds16(ag + (size_t)64  * K + (kn), &APk[buf][((size_t)(1 * 512 + tid)) << 2]); \
    gl2lds16(ag + (size_t)128 * K + (kn), &APk[buf][((size_t)(2 * 512 + tid)) << 2]); \
    gl2lds16(ag + (size_t)192 * K + (kn), &APk[buf][((size_t)(3 * 512 + tid)) << 2]); \
    gl2lds16(bg + (kn),     &BHs[buf][lsb]);                                   \
    gl2lds16(bg + K + (kn), &BLs[buf][lsb]);                                   \
  } while (0)

  // prologue: tile 0 -> buffer 0 (6 outstanding)
  STAGE_(0, 0);

  for (int t = 0; t < NT - 1; ++t) {
    const int cb = t & 1, nb = cb ^ 1;
    // issue ALL of next tile (into nxt buf; safe: nxt last read at t-1,
    // protected by t-1's trailing barrier)
    STAGE_(nb, (t + 1) << 5);
    asm volatile("s_waitcnt vmcnt(6)" ::: "memory"); // drains tile t's 6 units
    BARRIER_();
    phase_pk<0>(APk[cb], BHs[cb], BLs[cb], acc, wm, wn, lm, quad, roffB);
    BARRIER_();
    phase_pk<1>(APk[cb], BHs[cb], BLs[cb], acc, wm, wn, lm, quad, roffB);
    BARRIER_();
  }

  // peeled last tile: drain allowed here only
  {
    const int cb = (NT - 1) & 1;
    asm volatile("s_waitcnt vmcnt(0)" ::: "memory");
    BARRIER_();
    phase_pk<0>(APk[cb], BHs[cb], BLs[cb], acc, wm, wn, lm, quad, roffB);
    BARRIER_();
    phase_pk<1>(APk[cb], BHs[cb], BLs[cb], acc, wm, wn, lm, quad, roffB);
  }
#undef STAGE_

  // epilogue: C/D layout col=lane&15 (n), row=quad*4+reg (m)
#pragma unroll
  for (int i = 0; i < 8; ++i) {
    const int m = bm + wm + i * 16 + quad * 4;
#pragma unroll
    for (int j = 0; j < 2; ++j) {
      const int n = bn + wn + j * 16 + lm;
#pragma unroll
      for (int r = 0; r < 4; ++r)
        C[(size_t)(m + r) * ldc + n] = acc[i][j][r];
    }
  }
}

// ---------------------------------------------------------------------------
// fp32 NT GEMM (small shapes): C[M,N] = A[M,K]·B[N,K]^T. 64x64 tile, BK=16.
// EPI: 0 none, 1 softplus(acc + bias[n]). Split-K via blockIdx.z: segment z
// reads k-window [z*K, (z+1)*K) and writes C + z*cseg.
// ---------------------------------------------------------------------------
template <int EPI>
__global__ __launch_bounds__(256) void gemm_nt(
    const float* __restrict__ A, int lda,
    const float* __restrict__ B, int ldb,
    float* __restrict__ C, int ldc,
    int N, int K, const float* __restrict__ bias, size_t cseg)
{
  __shared__ float As[16][68];
  __shared__ float Bs[16][68];
  const int tid = threadIdx.x;
  const int bm = blockIdx.y << 6;
  const int bn = blockIdx.x << 6;
  const int kz = blockIdx.z;
  A += (size_t)kz * K;
  B += (size_t)kz * K;
  C += (size_t)kz * cseg;
  const int lr = tid >> 2;
  const int lk = (tid & 3) << 2;
  const int tx = tid & 15, ty = tid >> 4;

  float acc[4][4];
#pragma unroll
  for (int i = 0; i < 4; ++i)
#pragma unroll
    for (int j = 0; j < 4; ++j) acc[i][j] = 0.f;

  const float* Apt = A + (size_t)(bm + lr) * lda + lk;
  const float* Bpt = B + (size_t)(bn + lr) * ldb + lk;
  const bool bv = (bn + lr) < N;

  for (int k0 = 0; k0 < K; k0 += 16) {
    float4 a4 = *(const float4*)(Apt + k0);
    float4 b4 = bv ? *(const float4*)(Bpt + k0) : make_float4(0.f, 0.f, 0.f, 0.f);
    __syncthreads();
    As[lk + 0][lr] = a4.x; As[lk + 1][lr] = a4.y;
    As[lk + 2][lr] = a4.z; As[lk + 3][lr] = a4.w;
    Bs[lk + 0][lr] = b4.x; Bs[lk + 1][lr] = b4.y;
    Bs[lk + 2][lr] = b4.z; Bs[lk + 3][lr] = b4.w;
    __syncthreads();
#pragma unroll
    for (int k = 0; k < 16; ++k) {
      const float4 av = *(const float4*)(&As[k][ty << 2]);
      const float4 bw = *(const float4*)(&Bs[k][tx << 2]);
      float a4r[4] = {av.x, av.y, av.z, av.w};
      float b4r[4] = {bw.x, bw.y, bw.z, bw.w};
#pragma unroll
      for (int i = 0; i < 4; ++i)
#pragma unroll
        for (int j = 0; j < 4; ++j)
          acc[i][j] = fmaf(a4r[i], b4r[j], acc[i][j]);
    }
  }

  const int m = bm + (ty << 2);
  const int n = bn + (tx << 2);
#pragma unroll
  for (int i = 0; i < 4; ++i) {
    float v[4] = {acc[i][0], acc[i][1], acc[i][2], acc[i][3]};
    if (EPI == 1) {
#pragma unroll
      for (int j = 0; j < 4; ++j)
        if (n + j < N) v[j] = softplus_(v[j] + bias[n + j]);
    }
    if (n + 3 < N) {
      *(float4*)(C + (size_t)(m + i) * ldc + n) = make_float4(v[0], v[1], v[2], v[3]);
    } else {
#pragma unroll
      for (int j = 0; j < 4; ++j)
        if (n + j < N) C[(size_t)(m + i) * ldc + n + j] = v[j];
    }
  }
}

// ---------------------------------------------------------------------------
// 4-way split-K reduce: O[i] = sum_z P[z*seg + i], over n4 float4s.
// ---------------------------------------------------------------------------
__global__ __launch_bounds__(256) void reduce4(
    const float* __restrict__ P, float* __restrict__ O, size_t seg)
{
  const size_t i = ((size_t)blockIdx.x << 8) + threadIdx.x;
  float4 a = ((const float4*)P)[i];
  float4 b = ((const float4*)(P + seg))[i];
  float4 c = ((const float4*)(P + 2 * seg))[i];
  float4 d = ((const float4*)(P + 3 * seg))[i];
  ((float4*)O)[i] = make_float4(a.x + b.x + c.x + d.x,
                                a.y + b.y + c.y + d.y,
                                a.z + b.z + c.z + d.z,
                                a.w + b.w + c.w + d.w);
}

// ---------------------------------------------------------------------------
// Channel alignment features (rfft2 16x16 magnitude band ratio). X stride 2048.
// ---------------------------------------------------------------------------
__global__ __launch_bounds__(256) void feat_kernel(
    const float* __restrict__ X, float* __restrict__ features)
{
  __shared__ float xin[256][17];
  __shared__ float Rf[16 * 315];
  __shared__ float tc[16], ts[16];
  __shared__ float part2[16][16][2];

  const int tid = threadIdx.x;
  const int frame = blockIdx.x >> 7;
  const int cg = blockIdx.x & 127;
  const int b = frame >> 3, t = frame & 7;
  const int c0 = cg << 4;

  if (tid < 16) {
    float ang = 0.39269908169872414f * (float)tid;
    tc[tid] = cosf(ang);
    ts[tid] = sinf(ang);
  }
  const float* xb = X + ((size_t)(b * LSEQ + t * 256) << 11) + c0;
  for (int i = tid; i < 256 * 16; i += 256) {
    int hw = i >> 4, ci = i & 15;
    xin[hw][ci] = xb[((size_t)hw << 11) + ci];
  }
  __syncthreads();

  {
    const int ci = tid & 15, h = tid >> 4;
    float re[9], im[9];
#pragma unroll
    for (int kw = 0; kw < 9; ++kw) { re[kw] = 0.f; im[kw] = 0.f; }
#pragma unroll
    for (int w = 0; w < 16; ++w) {
      float x = xin[(h << 4) + w][ci];
#pragma unroll
      for (int kw = 0; kw < 9; ++kw) {
        int ph = (kw * w) & 15;
        re[kw] = fmaf(x, tc[ph], re[kw]);
        im[kw] = fmaf(-x, ts[ph], im[kw]);
      }
    }
#pragma unroll
    for (int kw = 0; kw < 9; ++kw) {
      Rf[ci * 315 + kw * 35 + 2 * h]     = re[kw];
      Rf[ci * 315 + kw * 35 + 2 * h + 1] = im[kw];
    }
  }
  __syncthreads();

  {
    const int ci = tid & 15, kh = tid >> 4;
    float ut = 0.f, tt = 0.f;
    for (int kw = 0; kw < 9; ++kw) {
      float fre = 0.f, fim = 0.f;
#pragma unroll
      for (int h = 0; h < 16; ++h) {
        int ph = (kh * h) & 15;
        float c = tc[ph], s = ts[ph];
        float rr = Rf[ci * 315 + kw * 35 + 2 * h];
        float ri = Rf[ci * 315 + kw * 35 + 2 * h + 1];
        fre += rr * c + ri * s;
        fim += ri * c - rr * s;
      }
      float mag = sqrtf(fre * fre + fim * fim + 1e-8f);
      int sh = (kh + 8) & 15;
      int sw2 = kw + 4; if (sw2 >= 9) sw2 -= 9;
      float dh = (float)(sh - 8) / 16.0f;
      float dw = (float)(sw2 - 4) / 9.0f;
      tt += mag;
      if (dh * dh + dw * dw >= 0.25f) ut += mag;
    }
    part2[ci][kh][0] = ut;
    part2[ci][kh][1] = tt;
  }
  __syncthreads();

  if (tid < 16) {
    float ut = 0.f, tt = 0.f;
    for (int kh = 0; kh < 16; ++kh) { ut += part2[tid][kh][0]; tt += part2[tid][kh][1]; }
    features[frame * DI + c0 + tid] = ut / (tt + 1e-8f);
  }
}

// ---------------------------------------------------------------------------
// loss + norms + softmax(mean feat) + attention + A_max/A_min + A out. 1 block.
// Aws is pre-scaled by log2(e): scan kernels use native exp2.
// ---------------------------------------------------------------------------
__global__ __launch_bounds__(256) void alpha_kernel(
    const float* __restrict__ feats, const float* __restrict__ A_log,
    float* __restrict__ Aws, float* __restrict__ loss_out)
{
  __shared__ float red[256];
  __shared__ float invn[32];
  __shared__ float PT[32][257];
  __shared__ float AM[256][17];
  __shared__ float sAmax[16], sAmin[16];
  const int tid = threadIdx.x;

  float pn[32];
#pragma unroll
  for (int i = 0; i < 32; ++i) pn[i] = 0.f;
  float md[8];
#pragma unroll
  for (int j = 0; j < 8; ++j) md[j] = 0.f;
  for (int i = 0; i < 32; ++i) {
#pragma unroll
    for (int j = 0; j < 8; ++j) {
      float v = feats[(i << 11) + tid + (j << 8)];
      pn[i] = fmaf(v, v, pn[i]);
      md[j] += v;
    }
  }
#pragma unroll
  for (int j = 0; j < 8; ++j) md[j] *= (1.f / 32.f);
#pragma unroll
  for (int i = 0; i < 32; ++i) PT[i][tid] = pn[i];
  __syncthreads();
  if (tid < 32) {
    float s = 0.f;
    for (int k = 0; k < 256; ++k) s += PT[tid][k];
    invn[tid] = 1.f / fmaxf(sqrtf(s), 1e-12f);
  }
  __syncthreads();

  float gsq = 0.f;
#pragma unroll
  for (int j = 0; j < 8; ++j) {
    float gd = 0.f;
    for (int i = 0; i < 32; ++i)
      gd = fmaf(feats[(i << 11) + tid + (j << 8)], invn[i], gd);
    gsq = fmaf(gd, gd, gsq);
  }
  red[tid] = gsq; __syncthreads();
  for (int s = 128; s > 0; s >>= 1) { if (tid < s) red[tid] += red[tid + s]; __syncthreads(); }
  if (tid == 0) loss_out[0] = 1.f - red[0] * (1.f / 1024.f);
  __syncthreads();

  float lm = md[0];
#pragma unroll
  for (int j = 1; j < 8; ++j) lm = fmaxf(lm, md[j]);
  red[tid] = lm; __syncthreads();
  for (int s = 128; s > 0; s >>= 1) { if (tid < s) red[tid] = fmaxf(red[tid], red[tid + s]); __syncthreads(); }
  const float mmax = red[0]; __syncthreads();

  float p[8]; float ps = 0.f;
#pragma unroll
  for (int j = 0; j < 8; ++j) { p[j] = __expf(md[j] - mmax); ps += p[j]; }
  red[tid] = ps; __syncthreads();
  for (int s = 128; s > 0; s >>= 1) { if (tid < s) red[tid] += red[tid + s]; __syncthreads(); }
  const float psum = red[0]; __syncthreads();

  float amaxl[16], aminl[16], rn[8];
#pragma unroll
  for (int n = 0; n < 16; ++n) { amaxl[n] = -1e30f; aminl[n] = 1e30f; }
#pragma unroll
  for (int j = 0; j < 8; ++j) {
    const int d = tid + (j << 8);
    float ss = 0.f;
#pragma unroll
    for (int n = 0; n < 16; ++n) {
      float a = A_log[(d << 4) + n];
      float e = __expf(a);
      ss = fmaf(e, e, ss);
      amaxl[n] = fmaxf(amaxl[n], a);
      aminl[n] = fminf(aminl[n], a);
    }
    rn[j] = sqrtf(ss);
  }
  float rm = rn[0];
#pragma unroll
  for (int j = 1; j < 8; ++j) rm = fmaxf(rm, rn[j]);
  red[tid] = rm; __syncthreads();
  for (int s = 128; s > 0; s >>= 1) { if (tid < s) red[tid] = fmaxf(red[tid], red[tid + s]); __syncthreads(); }
  const float rnmax = red[0]; __syncthreads();

#pragma unroll
  for (int n = 0; n < 16; ++n) AM[tid][n] = amaxl[n];
  __syncthreads();
  if (tid < 16) { float m = -1e30f; for (int i = 0; i < 256; ++i) m = fmaxf(m, AM[i][tid]); sAmax[tid] = m; }
  __syncthreads();
#pragma unroll
  for (int n = 0; n < 16; ++n) AM[tid][n] = aminl[n];
  __syncthreads();
  if (tid < 16) { float m = 1e30f; for (int i = 0; i < 256; ++i) m = fminf(m, AM[i][tid]); sAmin[tid] = m; }
  __syncthreads();

  const float irn = 1.f / (rnmax + 1e-8f);
#pragma unroll
  for (int j = 0; j < 8; ++j) {
    const int d = tid + (j << 8);
    const float att = rn[j] * irn;
    const float f = p[j] / psum;
    const float alpha = fminf(fmaxf(f * (1.f - att), 0.f), 1.f);
#pragma unroll
    for (int n = 0; n < 16; ++n) {
      float a = A_log[(d << 4) + n];
      float fl = sAmax[n] + sAmin[n] - a;
      float an = (1.f - alpha) * a + alpha * fl;
      // pre-fold log2(e) so scan kernels can use native v_exp_f32 (exp2)
      Aws[(d << 4) + n] = -__expf(an) * 1.4426950408889634f;
    }
  }
}

// ---------------------------------------------------------------------------
// Depthwise causal conv (k=4) + bias + SiLU, float4 per thread.
// X (b,l,2048) -> U (b,l,2048)
// ---------------------------------------------------------------------------
__global__ __launch_bounds__(256) void conv_kernel(
    const float* __restrict__ X, const float* __restrict__ cw,
    const float* __restrict__ cb, float* __restrict__ U)
{
  const size_t i4 = ((size_t)blockIdx.x << 8) + threadIdx.x;  // < 4,194,304
  const int e4 = (int)(i4 & 511);
  const size_t row = i4 >> 9;          // b*2048 + l
  const int l = (int)(row & 2047);
  const float* xr = X + (row << 11) + (e4 << 2);
  const float4 z4 = make_float4(0.f, 0.f, 0.f, 0.f);
  float4 x0 = *(const float4*)xr;
  float4 x1 = (l >= 1) ? *(const float4*)(xr - 2048) : z4;
  float4 x2 = (l >= 2) ? *(const float4*)(xr - 4096) : z4;
  float4 x3 = (l >= 3) ? *(const float4*)(xr - 6144) : z4;
  const float4* cwf = (const float4*)cw;
  float4 bi = *(const float4*)(cb + (e4 << 2));
  float x0a[4] = {x0.x, x0.y, x0.z, x0.w};
  float x1a[4] = {x1.x, x1.y, x1.z, x1.w};
  float x2a[4] = {x2.x, x2.y, x2.z, x2.w};
  float x3a[4] = {x3.x, x3.y, x3.z, x3.w};
  float bia[4] = {bi.x, bi.y, bi.z, bi.w};
  float o[4];
#pragma unroll
  for (int c = 0; c < 4; ++c) {
    float4 w = cwf[(e4 << 2) + c];
    float acc = bia[c];
    acc = fmaf(x3a[c], w.x, acc);
    acc = fmaf(x2a[c], w.y, acc);
    acc = fmaf(x1a[c], w.z, acc);
    acc = fmaf(x0a[c], w.w, acc);
    o[c] = silu_(acc);
  }
  *(float4*)(U + (i4 << 2)) = make_float4(o[0], o[1], o[2], o[3]);
}

// ---------------------------------------------------------------------------
// Chunked selective scan (delta in X region stride 2048, z in Z stride 2048).
// Aws carries log2(e) factor -> exp2 (single v_exp_f32, no mul).
// ---------------------------------------------------------------------------
__global__ __launch_bounds__(256) void scan_pass1(
    const float* __restrict__ delta, const float* __restrict__ U,
    const float* __restrict__ xdbl, const float* __restrict__ Aws,
    float* __restrict__ cs, float* __restrict__ sdt)
{
  __shared__ float blds[CL * 16];
  const int tid = threadIdx.x;
  const int dg = blockIdx.x & 7;
  const int chunk = (blockIdx.x >> 3) & 31;
  const int b = blockIdx.x >> 8;
  const int d = (dg << 8) | tid;
  const int l0 = chunk * CL;

  for (int i = tid; i < CL * 16; i += 256) {
    int l = i >> 4, j = i & 15;
    blds[i] = xdbl[(size_t)(b * LSEQ + l0 + l) * 96 + 64 + j];
  }
  __syncthreads();

  float Ar[16];
#pragma unroll
  for (int n = 0; n < 16; ++n) Ar[n] = Aws[(d << 4) + n];
  float s[16];
#pragma unroll
  for (int n = 0; n < 16; ++n) s[n] = 0.f;
  float sumdt = 0.f;

  const float* dp = delta + ((size_t)b << 22) + ((size_t)l0 << 11) + d;
  const float* up = U + ((size_t)b << 22) + ((size_t)l0 << 11) + d;

  for (int l = 0; l < CL; ++l) {
    const float dt = dp[(size_t)l << 11];
    const float u = up[(size_t)l << 11];
    sumdt += dt;
    const float du = dt * u;
    const float* bl = &blds[l << 4];
#pragma unroll
    for (int n = 0; n < 16; ++n)
      s[n] = fmaf(s[n], __builtin_amdgcn_exp2f(dt * Ar[n]), du * bl[n]);
  }

  float* csp = cs + ((((size_t)b * NC + chunk) * 2048 + d) << 4);
#pragma unroll
  for (int n = 0; n < 4; ++n)
    *(float4*)(csp + (n << 2)) = make_float4(s[4*n], s[4*n+1], s[4*n+2], s[4*n+3]);
  sdt[((size_t)b * NC + chunk) * 2048 + d] = sumdt;
}

__global__ __launch_bounds__(256) void scan_mid(
    float* __restrict__ cs, const float* __restrict__ sdt,
    const float* __restrict__ Aws)
{
  const int b = blockIdx.x >> 3;
  const int d = ((blockIdx.x & 7) << 8) | threadIdx.x;
  float Ar[16];
#pragma unroll
  for (int n = 0; n < 16; ++n) Ar[n] = Aws[(d << 4) + n];
  float si[16];
#pragma unroll
  for (int n = 0; n < 16; ++n) si[n] = 0.f;

  for (int c = 0; c < NC; ++c) {
    const size_t base = ((size_t)b * NC + c) * 2048 + d;
    float* csp = cs + (base << 4);
    float sl[16];
#pragma unroll
    for (int n = 0; n < 4; ++n) {
      float4 v = *(const float4*)(csp + (n << 2));
      sl[4*n] = v.x; sl[4*n+1] = v.y; sl[4*n+2] = v.z; sl[4*n+3] = v.w;
    }
    const float sm = sdt[base];
#pragma unroll
    for (int n = 0; n < 4; ++n)
      *(float4*)(csp + (n << 2)) = make_float4(si[4*n], si[4*n+1], si[4*n+2], si[4*n+3]);
#pragma unroll
    for (int n = 0; n < 16; ++n)
      si[n] = fmaf(si[n], __builtin_amdgcn_exp2f(sm * Ar[n]), sl[n]);
  }
}

// scan_pass3 writes y as PACKED u32 (lo_bf16<<16 | hi_bf16) into the same U
// slot it reads u from (same thread, read-then-write, no cross-block hazard).
// gemm8_pk consumes this directly -> no fp32 split pass for the out GEMM.
__global__ __launch_bounds__(256) void scan_pass3(
    const float* __restrict__ delta, const float* __restrict__ Z,
    float* __restrict__ U,
    const float* __restrict__ xdbl, const float* __restrict__ Aws,
    const float* __restrict__ Dp, const float* __restrict__ cs)
{
  __shared__ float bclds[CL * 32];
  const int tid = threadIdx.x;
  const int dg = blockIdx.x & 7;
  const int chunk = (blockIdx.x >> 3) & 31;
  const int b = blockIdx.x >> 8;
  const int d = (dg << 8) | tid;
  const int l0 = chunk * CL;

  for (int i = tid; i < CL * 32; i += 256) {
    int l = i >> 5, j = i & 31;
    bclds[i] = xdbl[(size_t)(b * LSEQ + l0 + l) * 96 + 64 + j];
  }
  __syncthreads();

  float Ar[16];
#pragma unroll
  for (int n = 0; n < 16; ++n) Ar[n] = Aws[(d << 4) + n];
  const float Dd = Dp[d];

  const float* csp = cs + ((((size_t)b * NC + chunk) * 2048 + d) << 4);
  float s[16];
#pragma unroll
  for (int n = 0; n < 4; ++n) {
    float4 v = *(const float4*)(csp + (n << 2));
    s[4*n] = v.x; s[4*n+1] = v.y; s[4*n+2] = v.z; s[4*n+3] = v.w;
  }

  const float* dp = delta + ((size_t)b << 22) + ((size_t)l0 << 11) + d;
  const float* zp = Z + ((size_t)b << 22) + ((size_t)l0 << 11) + d;
  float* up = U + ((size_t)b << 22) + ((size_t)l0 << 11) + d;

  for (int l = 0; l < CL; ++l) {
    const float dt = dp[(size_t)l << 11];
    const float u = up[(size_t)l << 11];
    const float z = zp[(size_t)l << 11];
    const float du = dt * u;
    const float* bcl = &bclds[l << 5];
    float y = 0.f;
#pragma unroll
    for (int n = 0; n < 16; ++n) {
      s[n] = fmaf(s[n], __builtin_amdgcn_exp2f(dt * Ar[n]), du * bcl[n]);
      y = fmaf(s[n], bcl[16 + n], y);
    }
    const float yv = fmaf(u, Dd, y);
    const float yo = yv * silu_(z);
    const unsigned short h = f2bf(yo);
    const unsigned short lo = f2bf(yo - bf2f(h));
    ((unsigned int*)up)[(size_t)l << 11] = (unsigned)h | ((unsigned)lo << 16);
  }
}

// ---------------------------------------------------------------------------
extern "C" void kernel_launch(void* const* d_in, const int* in_sizes, int n_in,
                              void* d_out, int out_size, void* d_ws, size_t ws_size,
                              hipStream_t stream)
{
  const float* hs         = (const float*)d_in[0];
  const float* in_proj_w  = (const float*)d_in[4];
  const float* conv_w     = (const float*)d_in[5];
  const float* conv_b     = (const float*)d_in[6];
  const float* x_proj_w   = (const float*)d_in[7];
  const float* dt_proj_w  = (const float*)d_in[8];
  const float* dt_proj_b  = (const float*)d_in[9];
  const float* A_log      = (const float*)d_in[10];
  const float* Dp         = (const float*)d_in[11];
  const float* out_proj_w = (const float*)d_in[12];
  float* out = (float*)d_out;
  float* ws = (float*)d_ws;

  float* X     = ws + OFF_X;
  float* Z     = ws + OFF_Z;
  float* U     = ws + OFF_U;
  float* cs    = ws + OFF_CS;
  float* sdt   = ws + OFF_SDT;
  float* xdbl  = ws + OFF_XDBL;
  float* feats = ws + OFF_FEAT;
  float* Aws   = ws + OFF_AWS;
  unsigned short* A1s = (unsigned short*)(ws + OFF_S);
  unsigned short* B1s = (unsigned short*)(ws + OFF_B1);
  unsigned short* B2s = (unsigned short*)(ws + OFF_B1);

  const dim3 blk(256);

  // 0. split hs (2,097,152 float4s) + in_proj_w (1,048,576 float4s)
  split2_w<<<12288, blk, 0, stream>>>(hs, A1s, 10, (size_t)2097152,
                                      in_proj_w, B1s, 10);
  // 1a. X half: hs @ in_proj_w[0:2048]^T, full 3-pass (M=8192,N=2048,K=1024)
  //     256^2-tile phase-split schedule; blockIdx.x = n-tile = XCD.
  gemm_8ph<3><<<dim3(8, 32), dim3(512), 0, stream>>>(A1s, B1s, X, 1024, 2048);
  // 1b. Z half: hs @ in_proj_w[2048:4096]^T, hi*hi only (silu-gate budget)
  gemm_8ph<1><<<dim3(8, 32), dim3(512), 0, stream>>>(A1s, B1s + (size_t)2048 * 2048, Z, 1024, 2048);
  // 2. channel-alignment features (reads X)
  feat_kernel<<<4096, blk, 0, stream>>>(X, feats);
  // 3. depthwise conv + silu (X -> U)
  conv_kernel<<<16384, blk, 0, stream>>>(X, conv_w, conv_b, U);
  // 3b. split out_proj_w (524,288 float4s) -> 2048 blocks (overlays dead B1s)
  split2_w<<<2048, blk, 0, stream>>>(out_proj_w, B2s, 11, (size_t)524288,
                                     out_proj_w, B2s, 11);
  // 4. loss + norms + alpha + A
  alpha_kernel<<<1, blk, 0, stream>>>(feats, A_log, Aws, out + 8388608);
  // 5. x_dbl = U @ x_proj_w^T (M=8192,N=96,K=2048) — split-K=4 into cs region
  gemm_nt<0><<<dim3(2, 128, 4), blk, 0, stream>>>(U, DI, x_proj_w, DI, cs, 96, 96, 512, nullptr, (size_t)786432);
  reduce4<<<768, blk, 0, stream>>>(cs, xdbl, (size_t)786432);
  // 6. delta = softplus(x_dbl[:, :64] @ dt_proj_w^T + b) -> X region (dead x)
  gemm_nt<1><<<dim3(32, 128, 1), blk, 0, stream>>>(xdbl, 96, dt_proj_w, 64, X, DI, DI, 64, dt_proj_b, 0);
  // 7. chunked selective scan; y overwrites U as packed bf16 hi/lo u32
  scan_pass1<<<1024, blk, 0, stream>>>(X, U, xdbl, Aws, cs, sdt);
  scan_mid<<<32, blk, 0, stream>>>(cs, sdt, Aws);
  scan_pass3<<<1024, blk, 0, stream>>>(X, Z, U, xdbl, Aws, Dp, cs);
  // 8. out = y @ out_proj_w^T — phase-split counted-vmcnt kernel; A = packed
  //    u32 y staged RAW via gl2lds, de-interleaved at read with v_perm.
  gemm8_pk<<<dim3(8, 32), dim3(512), 0, stream>>>((const unsigned int*)U, B2s, out);
}

// Round 6
// 884.208 us; speedup vs baseline: 1.0122x; 1.0122x over previous
//
#include <hip/hip_runtime.h>
#include <math.h>
#include <stdint.h>

// Problem constants (fixed instance)
#define LSEQ 2048
#define DM   1024
#define DI   2048
#define NC   32     // scan chunks per sequence
#define CL   64     // scan chunk length (NC*CL == LSEQ)

// ---------------------------------------------------------------------------
// Workspace layout (float units). Total 62,914,560 floats = 251.7 MB.
//  X  [0,          16777216)  : x half of in_proj output; later delta (in place)
//  Z  [16777216,   33554432)  : z half
//  U  [33554432,   50331648)  : conv output u; scan_pass3 overwrites each slot
//                               with packed u32 (lo_bf16<<16 | hi_bf16) of y
//  S  [50331648,   58720256)  : A1' (hs split bf16) until gemm1 done, then
//                               cs(+xdbl split-K partials)/sdt/xdbl/feats/Aws
//  B1 [58720256,   62914560)  : B1' (in_proj split) -> B2' (out_proj split)
// ---------------------------------------------------------------------------
#define OFF_X     ((size_t)0)
#define OFF_Z     ((size_t)16777216)
#define OFF_U     ((size_t)33554432)
#define OFF_S     ((size_t)50331648)
#define OFF_CS    (OFF_S)                      // 4,194,304 floats (also xdbl partials)
#define OFF_SDT   (OFF_S + 4194304)            //   262,144
#define OFF_XDBL  (OFF_S + 4456448)            //   786,432
#define OFF_FEAT  (OFF_S + 5242880)            //    65,536
#define OFF_AWS   (OFF_S + 5308448)            //    32,768
#define OFF_B1    ((size_t)58720256)

__device__ __forceinline__ float silu_(float x) { return x / (1.f + __expf(-x)); }
__device__ __forceinline__ float softplus_(float x) {
  return fmaxf(x, 0.f) + log1pf(__expf(-fabsf(x)));
}
__device__ __forceinline__ unsigned short f2bf(float x) {
  unsigned int u = __float_as_uint(x);
  u += 0x7fffu + ((u >> 16) & 1u);      // RNE (inputs finite)
  return (unsigned short)(u >> 16);
}
__device__ __forceinline__ float bf2f(unsigned short h) {
  return __uint_as_float(((unsigned int)h) << 16);
}

typedef __attribute__((ext_vector_type(8))) short bf16x8;
typedef __attribute__((ext_vector_type(4))) float f32x4;

__device__ __forceinline__ void gl2lds16(const void* g, void* l) {
  __builtin_amdgcn_global_load_lds(
      (const __attribute__((address_space(1))) unsigned int*)(uintptr_t)g,
      (__attribute__((address_space(3))) unsigned int*)(uintptr_t)l,
      16, 0, 0);
}

// barrier that is also a compiler memory fence (NOT __syncthreads: that drains
// vmcnt(0) and kills the staged-load pipeline)
#define BARRIER_()                                   \
  do {                                               \
    asm volatile("" ::: "memory");                   \
    __builtin_amdgcn_s_barrier();                    \
    asm volatile("" ::: "memory");                   \
  } while (0)

// ---------------------------------------------------------------------------
// Split fp32 -> [hi | lo] bf16 per row, two tensors in one dispatch.
// Each thread handles ONE float4. Tensor a = first na4 float4-slots.
// ---------------------------------------------------------------------------
__global__ __launch_bounds__(256) void split2_w(
    const float* __restrict__ a, unsigned short* __restrict__ oa, int ksa,
    size_t na4,
    const float* __restrict__ b, unsigned short* __restrict__ ob, int ksb)
{
  size_t i4 = ((size_t)blockIdx.x << 8) + threadIdx.x;
  const float* src; unsigned short* dst; int ks;
  if (i4 < na4) { src = a; dst = oa; ks = ksa; }
  else          { src = b; dst = ob; ks = ksb; i4 -= na4; }
  const size_t flat = i4 << 2;
  const int K = 1 << ks;
  const size_t row = flat >> ks;
  const int k = (int)(flat & (size_t)(K - 1));
  float4 v = *(const float4*)(src + flat);
  float f[4] = {v.x, v.y, v.z, v.w};
  unsigned short h[4], lo[4];
#pragma unroll
  for (int c = 0; c < 4; ++c) { h[c] = f2bf(f[c]); lo[c] = f2bf(f[c] - bf2f(h[c])); }
  unsigned short* o = dst + (row << (ks + 1)) + k;
  *(uint2*)(o)     = make_uint2((unsigned)h[0]  | ((unsigned)h[1]  << 16),
                                (unsigned)h[2]  | ((unsigned)h[3]  << 16));
  *(uint2*)(o + K) = make_uint2((unsigned)lo[0] | ((unsigned)lo[1] << 16),
                                (unsigned)lo[2] | ((unsigned)lo[3] << 16));
}

// ---------------------------------------------------------------------------
// 256x256-tile phase-split split-bf16 MFMA GEMM: C[M,N] = A·B^T.
// T3+T4+T5 schedule (counted vmcnt, never drained in main loop; setprio
// around MFMA clusters; 1 barrier per phase). BK=32, 8 waves (2M x 4N),
// per-wave 128x64 output (8x4 frags). 4 phases per K-tile, one C-quadrant
// each: 24 MFMA + 12 ds_read_b128 (NPASS=3) between barriers.
// LDS: [2 dbuf][4 tensors AH,BH,AL,BL][256x32] = 128 KiB (NPASS=3).
// XOR chunk swizzle (measured 0 bank conflicts): stage slot c of row r holds
// global k-chunk c^((r>>1)&3); reader uses quad^((lm>>1)&3).
// XCD AFFINITY (r6): the 8 blocks sharing one A-panel (same bm) land on the
// SAME XCD: bm-tile = x*4 + (y>>3), bn-tile = y&7 (linear id % 8 == x = XCD).
// Fixes A re-fetched 8x across XCD L2s (FETCH 266MB ~= 8x A + B).
// ---------------------------------------------------------------------------
template <int NPASS, int MH, int NH>
__device__ __forceinline__ void phase_mfma(
    const unsigned short* __restrict__ shc, f32x4 (&acc)[8][4],
    int wm, int wn, int lm, int roff)
{
  bf16x8 aH[4], bH[2], aL[4], bL[2];
#pragma unroll
  for (int ii = 0; ii < 4; ++ii) {
    const int ar = (wm + (MH * 4 + ii) * 16 + lm) * 32 + roff;
    aH[ii] = *(const bf16x8*)(shc + ar);
    if constexpr (NPASS > 1) aL[ii] = *(const bf16x8*)(shc + 2 * 8192 + ar);
  }
#pragma unroll
  for (int jj = 0; jj < 2; ++jj) {
    const int br = (wn + (NH * 2 + jj) * 16 + lm) * 32 + roff;
    bH[jj] = *(const bf16x8*)(shc + 8192 + br);
    if constexpr (NPASS > 1) bL[jj] = *(const bf16x8*)(shc + 3 * 8192 + br);
  }
  __builtin_amdgcn_s_setprio(1);
#pragma unroll
  for (int ii = 0; ii < 4; ++ii)
#pragma unroll
    for (int jj = 0; jj < 2; ++jj) {
      const int i = MH * 4 + ii, j = NH * 2 + jj;
      acc[i][j] = __builtin_amdgcn_mfma_f32_16x16x32_bf16(aH[ii], bH[jj], acc[i][j], 0, 0, 0);
      if constexpr (NPASS > 1) {
        acc[i][j] = __builtin_amdgcn_mfma_f32_16x16x32_bf16(aH[ii], bL[jj], acc[i][j], 0, 0, 0);
        acc[i][j] = __builtin_amdgcn_mfma_f32_16x16x32_bf16(aL[ii], bH[jj], acc[i][j], 0, 0, 0);
      }
    }
  __builtin_amdgcn_s_setprio(0);
}

template <int NPASS>
__global__ __launch_bounds__(512, 2) void gemm_8ph(
    const unsigned short* __restrict__ Ap, const unsigned short* __restrict__ Bp,
    float* __restrict__ C, int K, int ldc)
{
  constexpr int NTEN = (NPASS > 1) ? 4 : 2;      // AH,BH[,AL,BL]
  __shared__ unsigned short sh[2][NTEN][256 * 32];
  const int tid = threadIdx.x;
  // XCD affinity: all 8 bn-blocks of a bm-panel on one XCD (x = XCD id)
  const int bm = (((blockIdx.x << 2) | (blockIdx.y >> 3)) << 8);
  const int bn = ((blockIdx.y & 7) << 8);
  const int K2 = K * 2;
  const int wave = tid >> 6, lane = tid & 63;
  const int wm = (wave >> 2) << 7;               // 0 / 128
  const int wn = (wave & 3) << 6;                // 0 / 64 / 128 / 192
  const int lm = lane & 15, quad = lane >> 4;
  const int roff = ((quad ^ ((lm >> 1) & 3)) << 3);

  const int r0 = tid >> 2;
  const int kq = (((tid & 3) ^ ((r0 >> 1) & 3)) << 3);
  const unsigned short* a0 = Ap + (size_t)(bm + r0) * K2 + kq;        // rows 0-127
  const unsigned short* a1 = a0 + (size_t)128 * K2;                   // rows 128-255
  const unsigned short* b0 = Bp + (size_t)(bn + r0) * K2 + kq;
  const unsigned short* b1 = b0 + (size_t)128 * K2;
  const int ls0 = tid * 8, ls1 = 4096 + tid * 8; // ushort offsets in a tensor buf

  f32x4 acc[8][4] = {};
  const int NT = K >> 5;

  // prologue: stage tile 0 into buffer 0
  {
    unsigned short* s = &sh[0][0][0];
    gl2lds16(a0, s + ls0);
    gl2lds16(a1, s + ls1);
    if constexpr (NPASS > 1) {
      gl2lds16(a0 + K, s + 2 * 8192 + ls0);
      gl2lds16(a1 + K, s + 2 * 8192 + ls1);
    }
    gl2lds16(b0, s + 8192 + ls0);
    gl2lds16(b1, s + 8192 + ls1);
    if constexpr (NPASS > 1) {
      gl2lds16(b0 + K, s + 3 * 8192 + ls0);
      gl2lds16(b1 + K, s + 3 * 8192 + ls1);
    }
  }

  for (int t = 0; t < NT - 1; ++t) {
    const unsigned short* cur = &sh[t & 1][0][0];
    unsigned short* nxt = &sh[(t + 1) & 1][0][0];
    const int kn = (t + 1) << 5;

    // ---- phase 0: issue next-tile A units, publish current tile ----
    gl2lds16(a0 + kn, nxt + ls0);
    gl2lds16(a1 + kn, nxt + ls1);
    if constexpr (NPASS > 1) {
      gl2lds16(a0 + K + kn, nxt + 2 * 8192 + ls0);
      gl2lds16(a1 + K + kn, nxt + 2 * 8192 + ls1);
      asm volatile("s_waitcnt vmcnt(4)" ::: "memory");  // current tile's 8 landed
    } else {
      asm volatile("s_waitcnt vmcnt(2)" ::: "memory");  // current tile's 4 landed
    }
    BARRIER_();
    phase_mfma<NPASS, 0, 0>(cur, acc, wm, wn, lm, roff);
    BARRIER_();
    // ---- phase 1: issue next-tile B units ----
    gl2lds16(b0 + kn, nxt + 8192 + ls0);
    gl2lds16(b1 + kn, nxt + 8192 + ls1);
    if constexpr (NPASS > 1) {
      gl2lds16(b0 + K + kn, nxt + 3 * 8192 + ls0);
      gl2lds16(b1 + K + kn, nxt + 3 * 8192 + ls1);
    }
    phase_mfma<NPASS, 0, 1>(cur, acc, wm, wn, lm, roff);
    BARRIER_();
    // ---- phase 2 ----
    phase_mfma<NPASS, 1, 0>(cur, acc, wm, wn, lm, roff);
    BARRIER_();
    // ---- phase 3 (trailing barrier protects next tile's stage overwrite) ----
    phase_mfma<NPASS, 1, 1>(cur, acc, wm, wn, lm, roff);
    BARRIER_();
  }

  // peeled last tile: nothing left to issue -> drain is allowed here only
  {
    const unsigned short* cur = &sh[(NT - 1) & 1][0][0];
    asm volatile("s_waitcnt vmcnt(0)" ::: "memory");
    BARRIER_();
    phase_mfma<NPASS, 0, 0>(cur, acc, wm, wn, lm, roff);
    BARRIER_();
    phase_mfma<NPASS, 0, 1>(cur, acc, wm, wn, lm, roff);
    BARRIER_();
    phase_mfma<NPASS, 1, 0>(cur, acc, wm, wn, lm, roff);
    BARRIER_();
    phase_mfma<NPASS, 1, 1>(cur, acc, wm, wn, lm, roff);
  }

  // epilogue: C/D layout col=lane&15 (n), row=quad*4+reg (m)
#pragma unroll
  for (int i = 0; i < 8; ++i) {
    const int m = bm + wm + i * 16 + quad * 4;
#pragma unroll
    for (int j = 0; j < 4; ++j) {
      const int n = bn + wn + j * 16 + lm;
#pragma unroll
      for (int r = 0; r < 4; ++r)
        C[(size_t)(m + r) * ldc + n] = acc[i][j][r];
    }
  }
}

// ---------------------------------------------------------------------------
// gemm8 v4 (gemm8_pk): out[8192,1024] = y[8192,2048]·out_proj^T, 3-pass.
// A = PACKED u32 (lo<<16|hi) from scan_pass3, staged RAW via gl2lds16;
// de-interleave at READ with __byte_perm.
// BANK FIX (r6): r5's flat [r][8x16B] layout (128B row stride) had NO row bit
// in the bank index -> 8.4M conflicts (4 extra cyc per A ds_read_b128).
// New layout = two k-half REGIONS (units 0-3 / 4-7), each [r][4 slots] at
// 64B/row with slot = unit ^ ((r>>1)&3) — byte-identical banking to the
// measured-0-conflict split layouts (bank = (r&1)*16 + slot*4 + word).
// Reader: region = quad>>1, slots ((2q+j)&3)^((lm>>1)&3).
// XCD AFFINITY (r6): bm-tile = x*4+(y>>3), bn-tile = y&7 (A-panel per XCD).
// Schedule unchanged: 2 phases/K-tile, vmcnt(6), 3 barriers/tile.
// MFMA order per acc: hiH, hiL, loH, k ascending -> same output as r2-r5.
// ---------------------------------------------------------------------------
template <int MH>
__device__ __forceinline__ void phase_pk(
    const unsigned int* __restrict__ ap,
    const unsigned short* __restrict__ bh, const unsigned short* __restrict__ bl,
    f32x4 (&acc)[8][2], int wm, int wn, int lm, int quad, int roffB)
{
  bf16x8 aH[4], aL[4], bH[2], bL[2];
  const int sw = (lm >> 1) & 3;
  const int Rg = (quad >> 1) * 4096;               // region base (u32)
  const int s0 = ((2 * quad) & 3) ^ sw;
  const int s1 = ((2 * quad + 1) & 3) ^ sw;
#pragma unroll
  for (int ii = 0; ii < 4; ++ii) {
    const int r = wm + (MH * 4 + ii) * 16 + lm;
    const uint4 w0 = *(const uint4*)(ap + Rg + ((r * 4 + s0) << 2));
    const uint4 w1 = *(const uint4*)(ap + Rg + ((r * 4 + s1) << 2));
    union { unsigned u[4]; bf16x8 v; } ch, cl;
    ch.u[0] = __byte_perm(w0.x, w0.y, 0x5410u);
    ch.u[1] = __byte_perm(w0.z, w0.w, 0x5410u);
    ch.u[2] = __byte_perm(w1.x, w1.y, 0x5410u);
    ch.u[3] = __byte_perm(w1.z, w1.w, 0x5410u);
    cl.u[0] = __byte_perm(w0.x, w0.y, 0x7632u);
    cl.u[1] = __byte_perm(w0.z, w0.w, 0x7632u);
    cl.u[2] = __byte_perm(w1.x, w1.y, 0x7632u);
    cl.u[3] = __byte_perm(w1.z, w1.w, 0x7632u);
    aH[ii] = ch.v;
    aL[ii] = cl.v;
  }
#pragma unroll
  for (int jj = 0; jj < 2; ++jj) {
    const int br = (wn + jj * 16 + lm) * 32 + roffB;
    bH[jj] = *(const bf16x8*)(bh + br);
    bL[jj] = *(const bf16x8*)(bl + br);
  }
  __builtin_amdgcn_s_setprio(1);
#pragma unroll
  for (int ii = 0; ii < 4; ++ii)
#pragma unroll
    for (int jj = 0; jj < 2; ++jj) {
      const int i = MH * 4 + ii;
      acc[i][jj] = __builtin_amdgcn_mfma_f32_16x16x32_bf16(aH[ii], bH[jj], acc[i][jj], 0, 0, 0);
      acc[i][jj] = __builtin_amdgcn_mfma_f32_16x16x32_bf16(aH[ii], bL[jj], acc[i][jj], 0, 0, 0);
      acc[i][jj] = __builtin_amdgcn_mfma_f32_16x16x32_bf16(aL[ii], bH[jj], acc[i][jj], 0, 0, 0);
    }
  __builtin_amdgcn_s_setprio(0);
}

__global__ __launch_bounds__(512, 2) void gemm8_pk(
    const unsigned int* __restrict__ Ay,   // [8192][2048] packed (lo<<16|hi)
    const unsigned short* __restrict__ Bp, // pre-split [1024][2*2048]
    float* __restrict__ C)
{
  constexpr int K = 2048, K2 = 4096, ldc = 1024, NT = 64;
  __shared__ unsigned int   APk[2][2048 * 4];     // 32 KiB per buf (2 regions)
  __shared__ unsigned short BHs[2][128 * 32];     // 8 KiB per buf
  __shared__ unsigned short BLs[2][128 * 32];
  const int tid = threadIdx.x;
  // XCD affinity: 4 bm-panels per XCD; all 8 bn-blocks of a panel co-XCD
  const int bm = (((blockIdx.x << 2) | (blockIdx.y >> 3)) << 8);
  const int bn = ((blockIdx.y & 7) << 7);
  const int wave = tid >> 6, lane = tid & 63;
  const int wm = (wave >> 2) << 7;               // 0 / 128
  const int wn = (wave & 3) << 5;                // 0 / 32 / 64 / 96
  const int lm = lane & 15, quad = lane >> 4;
  const int roffB = ((quad ^ ((lm >> 1) & 3)) << 3);

  // A staging: position P = j*512 + tid (16B units). Region R = P>>10,
  // p = P&1023, r = p>>2, s' = p&3. Content = global unit R*4 + (s'^((r>>1)&3))
  // of row bm + r (+ t*32 k-offset). For all j: r ≡ tid>>2 (mod 128),
  // (r>>1)&3 = (tid>>3)&3, s' = tid&3 -> one per-thread global base + strides.
  const int ar = tid >> 2;
  const int ko = (((tid & 3) ^ ((tid >> 3) & 3)) << 2);  // u32 offset in region
  const unsigned int* ag = Ay + (size_t)(bm + ar) * K + ko;

  // B staging (128 rows x 32 k, split hi/lo): proven layout
  const int rb = tid >> 2;
  const int kqb = (((tid & 3) ^ ((rb >> 1) & 3)) << 3);
  const unsigned short* bg = Bp + (size_t)(bn + rb) * K2 + kqb;
  const int lsb = tid * 8;

  f32x4 acc[8][2] = {};

#define STAGE_(buf, kn) do {                                                   \
    gl2lds16(ag + (kn),                       &APk[buf][(size_t)(tid)        << 2]); \
    gl2lds16(ag + (size_t)128 * K + (kn),     &APk[buf][(size_t)(512 + tid)  << 2]); \
    gl2lds16(ag + 16 + (kn),                  &APk[buf][(size_t)(1024 + tid) << 2]); \
    gl2lds16(ag + (size_t)128 * K + 16 + (kn),&APk[buf][(size_t)(1536 + tid) << 2]); \
    gl2lds16(bg + (kn),     &BHs[buf][lsb]);                                   \
    gl2lds16(bg + K + (kn), &BLs[buf][lsb]);                                   \
  } while (0)

  // prologue: tile 0 -> buffer 0 (6 outstanding)
  STAGE_(0, 0);

  for (int t = 0; t < NT - 1; ++t) {
    const int cb = t & 1, nb = cb ^ 1;
    // issue ALL of next tile (into nxt buf; safe: nxt last read at t-1,
    // protected by t-1's trailing barrier)
    STAGE_(nb, (t + 1) << 5);
    asm volatile("s_waitcnt vmcnt(6)" ::: "memory"); // drains tile t's 6 units
    BARRIER_();
    phase_pk<0>(APk[cb], BHs[cb], BLs[cb], acc, wm, wn, lm, quad, roffB);
    BARRIER_();
    phase_pk<1>(APk[cb], BHs[cb], BLs[cb], acc, wm, wn, lm, quad, roffB);
    BARRIER_();
  }

  // peeled last tile: drain allowed here only
  {
    const int cb = (NT - 1) & 1;
    asm volatile("s_waitcnt vmcnt(0)" ::: "memory");
    BARRIER_();
    phase_pk<0>(APk[cb], BHs[cb], BLs[cb], acc, wm, wn, lm, quad, roffB);
    BARRIER_();
    phase_pk<1>(APk[cb], BHs[cb], BLs[cb], acc, wm, wn, lm, quad, roffB);
  }
#undef STAGE_

  // epilogue: C/D layout col=lane&15 (n), row=quad*4+reg (m)
#pragma unroll
  for (int i = 0; i < 8; ++i) {
    const int m = bm + wm + i * 16 + quad * 4;
#pragma unroll
    for (int j = 0; j < 2; ++j) {
      const int n = bn + wn + j * 16 + lm;
#pragma unroll
      for (int r = 0; r < 4; ++r)
        C[(size_t)(m + r) * ldc + n] = acc[i][j][r];
    }
  }
}

// ---------------------------------------------------------------------------
// Split-bf16 MFMA GEMM (m97-style 128x128) — FALLBACK for gemm8 (116µs, r4).
// A_PACKED=1: A is u32 (lo<<16|hi); staging de-interleaves in-register.
// ---------------------------------------------------------------------------
template <int NPASS, int A_PACKED>
__global__ __launch_bounds__(256) void gemm_mfma(
    const void* __restrict__ Avp, const unsigned short* __restrict__ Bp,
    float* __restrict__ C, int K, int ldc, int nxs)
{
  __shared__ unsigned short AsH[128 * 32];
  __shared__ unsigned short BsH[128 * 32];
  __shared__ unsigned short AsL[(NPASS > 1) ? 128 * 32 : 8];
  __shared__ unsigned short BsL[(NPASS > 1) ? 128 * 32 : 8];
  const int tid = threadIdx.x;
  const int lin = blockIdx.y * gridDim.x + blockIdx.x;
  const int xcd = lin & 7;
  const int t = lin >> 3;
  const int nmask = (1 << nxs) - 1;
  const int bn = (((t & nmask) << 3) | xcd) << 7;
  const int bm = (t >> nxs) << 7;
  const int K2 = K * 2;

  const int wave = tid >> 6, lane = tid & 63;
  const int wm = (wave >> 1) << 6, wn = (wave & 1) << 6;
  const int lm = lane & 15, quad = lane >> 4;
  const int sw = (lm >> 1) & 3;        // reader swizzle (row>>1)&3 == (lm>>1)&3

  f32x4 acc[4][4] = {};

  const int r0 = tid >> 2;
  const int kq = ((tid & 3) ^ ((r0 >> 1) & 3)) << 3;   // element offset
  const unsigned short* BgH0 = Bp + (size_t)(bn + r0) * K2 + kq;
  const unsigned short* BgH1 = Bp + (size_t)(bn + 64 + r0) * K2 + kq;
  unsigned short* lA0 = &AsH[(size_t)tid * 8];
  unsigned short* lA1 = &AsH[(size_t)(256 + tid) * 8];
  unsigned short* lB0 = &BsH[(size_t)tid * 8];
  unsigned short* lB1 = &BsH[(size_t)(256 + tid) * 8];
  unsigned short* lAl0 = (NPASS > 1) ? &AsL[(size_t)tid * 8] : nullptr;
  unsigned short* lAl1 = (NPASS > 1) ? &AsL[(size_t)(256 + tid) * 8] : nullptr;
  unsigned short* lBl0 = (NPASS > 1) ? &BsL[(size_t)tid * 8] : nullptr;
  unsigned short* lBl1 = (NPASS > 1) ? &BsL[(size_t)(256 + tid) * 8] : nullptr;

  const unsigned short* AgH0 = nullptr; const unsigned short* AgH1 = nullptr;
  const unsigned int* Apk0 = nullptr; const unsigned int* Apk1 = nullptr;
  if (A_PACKED) {
    const unsigned int* Au = (const unsigned int*)Avp;
    Apk0 = Au + (size_t)(bm + r0) * K + kq;
    Apk1 = Au + (size_t)(bm + 64 + r0) * K + kq;
  } else {
    const unsigned short* Ab = (const unsigned short*)Avp;
    AgH0 = Ab + (size_t)(bm + r0) * K2 + kq;
    AgH1 = Ab + (size_t)(bm + 64 + r0) * K2 + kq;
  }

  for (int k0 = 0; k0 < K; k0 += 32) {
    __syncthreads();
    if (A_PACKED) {
      uint4 u0 = *(const uint4*)(Apk0 + k0);
      uint4 u1 = *(const uint4*)(Apk0 + k0 + 4);
      uint4 v0 = *(const uint4*)(Apk1 + k0);
      uint4 v1 = *(const uint4*)(Apk1 + k0 + 4);
      unsigned p[8] = {u0.x, u0.y, u0.z, u0.w, u1.x, u1.y, u1.z, u1.w};
      unsigned q[8] = {v0.x, v0.y, v0.z, v0.w, v1.x, v1.y, v1.z, v1.w};
      unsigned hu[4], lu[4], hv[4], lv[4];
#pragma unroll
      for (int c = 0; c < 4; ++c) {
        hu[c] = (p[2*c] & 0xffffu) | (p[2*c+1] << 16);
        lu[c] = (p[2*c] >> 16)     | (p[2*c+1] & 0xffff0000u);
        hv[c] = (q[2*c] & 0xffffu) | (q[2*c+1] << 16);
        lv[c] = (q[2*c] >> 16)     | (q[2*c+1] & 0xffff0000u);
      }
      *(uint4*)lA0  = make_uint4(hu[0], hu[1], hu[2], hu[3]);
      *(uint4*)lA1  = make_uint4(hv[0], hv[1], hv[2], hv[3]);
      if (NPASS > 1) {
        *(uint4*)lAl0 = make_uint4(lu[0], lu[1], lu[2], lu[3]);
        *(uint4*)lAl1 = make_uint4(lv[0], lv[1], lv[2], lv[3]);
      }
    } else {
      gl2lds16(AgH0 + k0, lA0);
      gl2lds16(AgH1 + k0, lA1);
      if (NPASS > 1) {
        gl2lds16(AgH0 + K + k0, lAl0);
        gl2lds16(AgH1 + K + k0, lAl1);
      }
    }
    gl2lds16(BgH0 + k0, lB0);
    gl2lds16(BgH1 + k0, lB1);
    if (NPASS > 1) {
      gl2lds16(BgH0 + K + k0, lBl0);
      gl2lds16(BgH1 + K + k0, lBl1);
    }
    __syncthreads();

    bf16x8 aH[4], bH[4];
#pragma unroll
    for (int i = 0; i < 4; ++i)
      aH[i] = *(const bf16x8*)&AsH[(wm + i * 16 + lm) * 32 + ((quad ^ sw) << 3)];
#pragma unroll
    for (int j = 0; j < 4; ++j)
      bH[j] = *(const bf16x8*)&BsH[(wn + j * 16 + lm) * 32 + ((quad ^ sw) << 3)];
#pragma unroll
    for (int i = 0; i < 4; ++i)
#pragma unroll
      for (int j = 0; j < 4; ++j)
        acc[i][j] = __builtin_amdgcn_mfma_f32_16x16x32_bf16(aH[i], bH[j], acc[i][j], 0, 0, 0);
    if (NPASS > 1) {
      bf16x8 aL[4], bL[4];
#pragma unroll
      for (int i = 0; i < 4; ++i)
        aL[i] = *(const bf16x8*)&AsL[(wm + i * 16 + lm) * 32 + ((quad ^ sw) << 3)];
#pragma unroll
      for (int j = 0; j < 4; ++j)
        bL[j] = *(const bf16x8*)&BsL[(wn + j * 16 + lm) * 32 + ((quad ^ sw) << 3)];
#pragma unroll
      for (int i = 0; i < 4; ++i)
#pragma unroll
        for (int j = 0; j < 4; ++j) {
          acc[i][j] = __builtin_amdgcn_mfma_f32_16x16x32_bf16(aH[i], bL[j], acc[i][j], 0, 0, 0);
          acc[i][j] = __builtin_amdgcn_mfma_f32_16x16x32_bf16(aL[i], bH[j], acc[i][j], 0, 0, 0);
        }
    }
  }

  // epilogue: C/D layout col=lane&15 (n, from B), row=quad*4+reg (m, from A)
#pragma unroll
  for (int i = 0; i < 4; ++i) {
    const int m = bm + wm + i * 16 + quad * 4;
#pragma unroll
    for (int j = 0; j < 4; ++j) {
      const int n = bn + wn + j * 16 + lm;
#pragma unroll
      for (int r = 0; r < 4; ++r)
        C[(size_t)(m + r) * ldc + n] = acc[i][j][r];
    }
  }
}

// ---------------------------------------------------------------------------
// fp32 NT GEMM (small shapes): C[M,N] = A[M,K]·B[N,K]^T. 64x64 tile, BK=16.
// EPI: 0 none, 1 softplus(acc + bias[n]). Split-K via blockIdx.z: segment z
// reads k-window [z*K, (z+1)*K) and writes C + z*cseg.
// ---------------------------------------------------------------------------
template <int EPI>
__global__ __launch_bounds__(256) void gemm_nt(
    const float* __restrict__ A, int lda,
    const float* __restrict__ B, int ldb,
    float* __restrict__ C, int ldc,
    int N, int K, const float* __restrict__ bias, size_t cseg)
{
  __shared__ float As[16][68];
  __shared__ float Bs[16][68];
  const int tid = threadIdx.x;
  const int bm = blockIdx.y << 6;
  const int bn = blockIdx.x << 6;
  const int kz = blockIdx.z;
  A += (size_t)kz * K;
  B += (size_t)kz * K;
  C += (size_t)kz * cseg;
  const int lr = tid >> 2;
  const int lk = (tid & 3) << 2;
  const int tx = tid & 15, ty = tid >> 4;

  float acc[4][4];
#pragma unroll
  for (int i = 0; i < 4; ++i)
#pragma unroll
    for (int j = 0; j < 4; ++j) acc[i][j] = 0.f;

  const float* Apt = A + (size_t)(bm + lr) * lda + lk;
  const float* Bpt = B + (size_t)(bn + lr) * ldb + lk;
  const bool bv = (bn + lr) < N;

  for (int k0 = 0; k0 < K; k0 += 16) {
    float4 a4 = *(const float4*)(Apt + k0);
    float4 b4 = bv ? *(const float4*)(Bpt + k0) : make_float4(0.f, 0.f, 0.f, 0.f);
    __syncthreads();
    As[lk + 0][lr] = a4.x; As[lk + 1][lr] = a4.y;
    As[lk + 2][lr] = a4.z; As[lk + 3][lr] = a4.w;
    Bs[lk + 0][lr] = b4.x; Bs[lk + 1][lr] = b4.y;
    Bs[lk + 2][lr] = b4.z; Bs[lk + 3][lr] = b4.w;
    __syncthreads();
#pragma unroll
    for (int k = 0; k < 16; ++k) {
      const float4 av = *(const float4*)(&As[k][ty << 2]);
      const float4 bw = *(const float4*)(&Bs[k][tx << 2]);
      float a4r[4] = {av.x, av.y, av.z, av.w};
      float b4r[4] = {bw.x, bw.y, bw.z, bw.w};
#pragma unroll
      for (int i = 0; i < 4; ++i)
#pragma unroll
        for (int j = 0; j < 4; ++j)
          acc[i][j] = fmaf(a4r[i], b4r[j], acc[i][j]);
    }
  }

  const int m = bm + (ty << 2);
  const int n = bn + (tx << 2);
#pragma unroll
  for (int i = 0; i < 4; ++i) {
    float v[4] = {acc[i][0], acc[i][1], acc[i][2], acc[i][3]};
    if (EPI == 1) {
#pragma unroll
      for (int j = 0; j < 4; ++j)
        if (n + j < N) v[j] = softplus_(v[j] + bias[n + j]);
    }
    if (n + 3 < N) {
      *(float4*)(C + (size_t)(m + i) * ldc + n) = make_float4(v[0], v[1], v[2], v[3]);
    } else {
#pragma unroll
      for (int j = 0; j < 4; ++j)
        if (n + j < N) C[(size_t)(m + i) * ldc + n + j] = v[j];
    }
  }
}

// ---------------------------------------------------------------------------
// 4-way split-K reduce: O[i] = sum_z P[z*seg + i], over n4 float4s.
// ---------------------------------------------------------------------------
__global__ __launch_bounds__(256) void reduce4(
    const float* __restrict__ P, float* __restrict__ O, size_t seg)
{
  const size_t i = ((size_t)blockIdx.x << 8) + threadIdx.x;
  float4 a = ((const float4*)P)[i];
  float4 b = ((const float4*)(P + seg))[i];
  float4 c = ((const float4*)(P + 2 * seg))[i];
  float4 d = ((const float4*)(P + 3 * seg))[i];
  ((float4*)O)[i] = make_float4(a.x + b.x + c.x + d.x,
                                a.y + b.y + c.y + d.y,
                                a.z + b.z + c.z + d.z,
                                a.w + b.w + c.w + d.w);
}

// ---------------------------------------------------------------------------
// Channel alignment features (rfft2 16x16 magnitude band ratio). X stride 2048.
// ---------------------------------------------------------------------------
__global__ __launch_bounds__(256) void feat_kernel(
    const float* __restrict__ X, float* __restrict__ features)
{
  __shared__ float xin[256][17];
  __shared__ float Rf[16 * 315];
  __shared__ float tc[16], ts[16];
  __shared__ float part2[16][16][2];

  const int tid = threadIdx.x;
  const int frame = blockIdx.x >> 7;
  const int cg = blockIdx.x & 127;
  const int b = frame >> 3, t = frame & 7;
  const int c0 = cg << 4;

  if (tid < 16) {
    float ang = 0.39269908169872414f * (float)tid;
    tc[tid] = cosf(ang);
    ts[tid] = sinf(ang);
  }
  const float* xb = X + ((size_t)(b * LSEQ + t * 256) << 11) + c0;
  for (int i = tid; i < 256 * 16; i += 256) {
    int hw = i >> 4, ci = i & 15;
    xin[hw][ci] = xb[((size_t)hw << 11) + ci];
  }
  __syncthreads();

  {
    const int ci = tid & 15, h = tid >> 4;
    float re[9], im[9];
#pragma unroll
    for (int kw = 0; kw < 9; ++kw) { re[kw] = 0.f; im[kw] = 0.f; }
#pragma unroll
    for (int w = 0; w < 16; ++w) {
      float x = xin[(h << 4) + w][ci];
#pragma unroll
      for (int kw = 0; kw < 9; ++kw) {
        int ph = (kw * w) & 15;
        re[kw] = fmaf(x, tc[ph], re[kw]);
        im[kw] = fmaf(-x, ts[ph], im[kw]);
      }
    }
#pragma unroll
    for (int kw = 0; kw < 9; ++kw) {
      Rf[ci * 315 + kw * 35 + 2 * h]     = re[kw];
      Rf[ci * 315 + kw * 35 + 2 * h + 1] = im[kw];
    }
  }
  __syncthreads();

  {
    const int ci = tid & 15, kh = tid >> 4;
    float ut = 0.f, tt = 0.f;
    for (int kw = 0; kw < 9; ++kw) {
      float fre = 0.f, fim = 0.f;
#pragma unroll
      for (int h = 0; h < 16; ++h) {
        int ph = (kh * h) & 15;
        float c = tc[ph], s = ts[ph];
        float rr = Rf[ci * 315 + kw * 35 + 2 * h];
        float ri = Rf[ci * 315 + kw * 35 + 2 * h + 1];
        fre += rr * c + ri * s;
        fim += ri * c - rr * s;
      }
      float mag = sqrtf(fre * fre + fim * fim + 1e-8f);
      int sh = (kh + 8) & 15;
      int sw2 = kw + 4; if (sw2 >= 9) sw2 -= 9;
      float dh = (float)(sh - 8) / 16.0f;
      float dw = (float)(sw2 - 4) / 9.0f;
      tt += mag;
      if (dh * dh + dw * dw >= 0.25f) ut += mag;
    }
    part2[ci][kh][0] = ut;
    part2[ci][kh][1] = tt;
  }
  __syncthreads();

  if (tid < 16) {
    float ut = 0.f, tt = 0.f;
    for (int kh = 0; kh < 16; ++kh) { ut += part2[tid][kh][0]; tt += part2[tid][kh][1]; }
    features[frame * DI + c0 + tid] = ut / (tt + 1e-8f);
  }
}

// ---------------------------------------------------------------------------
// loss + norms + softmax(mean feat) + attention + A_max/A_min + A out. 1 block.
// Aws is pre-scaled by log2(e): scan kernels use native exp2.
// ---------------------------------------------------------------------------
__global__ __launch_bounds__(256) void alpha_kernel(
    const float* __restrict__ feats, const float* __restrict__ A_log,
    float* __restrict__ Aws, float* __restrict__ loss_out)
{
  __shared__ float red[256];
  __shared__ float invn[32];
  __shared__ float PT[32][257];
  __shared__ float AM[256][17];
  __shared__ float sAmax[16], sAmin[16];
  const int tid = threadIdx.x;

  float pn[32];
#pragma unroll
  for (int i = 0; i < 32; ++i) pn[i] = 0.f;
  float md[8];
#pragma unroll
  for (int j = 0; j < 8; ++j) md[j] = 0.f;
  for (int i = 0; i < 32; ++i) {
#pragma unroll
    for (int j = 0; j < 8; ++j) {
      float v = feats[(i << 11) + tid + (j << 8)];
      pn[i] = fmaf(v, v, pn[i]);
      md[j] += v;
    }
  }
#pragma unroll
  for (int j = 0; j < 8; ++j) md[j] *= (1.f / 32.f);
#pragma unroll
  for (int i = 0; i < 32; ++i) PT[i][tid] = pn[i];
  __syncthreads();
  if (tid < 32) {
    float s = 0.f;
    for (int k = 0; k < 256; ++k) s += PT[tid][k];
    invn[tid] = 1.f / fmaxf(sqrtf(s), 1e-12f);
  }
  __syncthreads();

  float gsq = 0.f;
#pragma unroll
  for (int j = 0; j < 8; ++j) {
    float gd = 0.f;
    for (int i = 0; i < 32; ++i)
      gd = fmaf(feats[(i << 11) + tid + (j << 8)], invn[i], gd);
    gsq = fmaf(gd, gd, gsq);
  }
  red[tid] = gsq; __syncthreads();
  for (int s = 128; s > 0; s >>= 1) { if (tid < s) red[tid] += red[tid + s]; __syncthreads(); }
  if (tid == 0) loss_out[0] = 1.f - red[0] * (1.f / 1024.f);
  __syncthreads();

  float lm = md[0];
#pragma unroll
  for (int j = 1; j < 8; ++j) lm = fmaxf(lm, md[j]);
  red[tid] = lm; __syncthreads();
  for (int s = 128; s > 0; s >>= 1) { if (tid < s) red[tid] = fmaxf(red[tid], red[tid + s]); __syncthreads(); }
  const float mmax = red[0]; __syncthreads();

  float p[8]; float ps = 0.f;
#pragma unroll
  for (int j = 0; j < 8; ++j) { p[j] = __expf(md[j] - mmax); ps += p[j]; }
  red[tid] = ps; __syncthreads();
  for (int s = 128; s > 0; s >>= 1) { if (tid < s) red[tid] += red[tid + s]; __syncthreads(); }
  const float psum = red[0]; __syncthreads();

  float amaxl[16], aminl[16], rn[8];
#pragma unroll
  for (int n = 0; n < 16; ++n) { amaxl[n] = -1e30f; aminl[n] = 1e30f; }
#pragma unroll
  for (int j = 0; j < 8; ++j) {
    const int d = tid + (j << 8);
    float ss = 0.f;
#pragma unroll
    for (int n = 0; n < 16; ++n) {
      float a = A_log[(d << 4) + n];
      float e = __expf(a);
      ss = fmaf(e, e, ss);
      amaxl[n] = fmaxf(amaxl[n], a);
      aminl[n] = fminf(aminl[n], a);
    }
    rn[j] = sqrtf(ss);
  }
  float rm = rn[0];
#pragma unroll
  for (int j = 1; j < 8; ++j) rm = fmaxf(rm, rn[j]);
  red[tid] = rm; __syncthreads();
  for (int s = 128; s > 0; s >>= 1) { if (tid < s) red[tid] = fmaxf(red[tid], red[tid + s]); __syncthreads(); }
  const float rnmax = red[0]; __syncthreads();

#pragma unroll
  for (int n = 0; n < 16; ++n) AM[tid][n] = amaxl[n];
  __syncthreads();
  if (tid < 16) { float m = -1e30f; for (int i = 0; i < 256; ++i) m = fmaxf(m, AM[i][tid]); sAmax[tid] = m; }
  __syncthreads();
#pragma unroll
  for (int n = 0; n < 16; ++n) AM[tid][n] = aminl[n];
  __syncthreads();
  if (tid < 16) { float m = 1e30f; for (int i = 0; i < 256; ++i) m = fminf(m, AM[i][tid]); sAmin[tid] = m; }
  __syncthreads();

  const float irn = 1.f / (rnmax + 1e-8f);
#pragma unroll
  for (int j = 0; j < 8; ++j) {
    const int d = tid + (j << 8);
    const float att = rn[j] * irn;
    const float f = p[j] / psum;
    const float alpha = fminf(fmaxf(f * (1.f - att), 0.f), 1.f);
#pragma unroll
    for (int n = 0; n < 16; ++n) {
      float a = A_log[(d << 4) + n];
      float fl = sAmax[n] + sAmin[n] - a;
      float an = (1.f - alpha) * a + alpha * fl;
      // pre-fold log2(e) so scan kernels can use native v_exp_f32 (exp2)
      Aws[(d << 4) + n] = -__expf(an) * 1.4426950408889634f;
    }
  }
}

// ---------------------------------------------------------------------------
// Depthwise causal conv (k=4) + bias + SiLU, float4 per thread.
// X (b,l,2048) -> U (b,l,2048)
// ---------------------------------------------------------------------------
__global__ __launch_bounds__(256) void conv_kernel(
    const float* __restrict__ X, const float* __restrict__ cw,
    const float* __restrict__ cb, float* __restrict__ U)
{
  const size_t i4 = ((size_t)blockIdx.x << 8) + threadIdx.x;  // < 4,194,304
  const int e4 = (int)(i4 & 511);
  const size_t row = i4 >> 9;          // b*2048 + l
  const int l = (int)(row & 2047);
  const float* xr = X + (row << 11) + (e4 << 2);
  const float4 z4 = make_float4(0.f, 0.f, 0.f, 0.f);
  float4 x0 = *(const float4*)xr;
  float4 x1 = (l >= 1) ? *(const float4*)(xr - 2048) : z4;
  float4 x2 = (l >= 2) ? *(const float4*)(xr - 4096) : z4;
  float4 x3 = (l >= 3) ? *(const float4*)(xr - 6144) : z4;
  const float4* cwf = (const float4*)cw;
  float4 bi = *(const float4*)(cb + (e4 << 2));
  float x0a[4] = {x0.x, x0.y, x0.z, x0.w};
  float x1a[4] = {x1.x, x1.y, x1.z, x1.w};
  float x2a[4] = {x2.x, x2.y, x2.z, x2.w};
  float x3a[4] = {x3.x, x3.y, x3.z, x3.w};
  float bia[4] = {bi.x, bi.y, bi.z, bi.w};
  float o[4];
#pragma unroll
  for (int c = 0; c < 4; ++c) {
    float4 w = cwf[(e4 << 2) + c];
    float acc = bia[c];
    acc = fmaf(x3a[c], w.x, acc);
    acc = fmaf(x2a[c], w.y, acc);
    acc = fmaf(x1a[c], w.z, acc);
    acc = fmaf(x0a[c], w.w, acc);
    o[c] = silu_(acc);
  }
  *(float4*)(U + (i4 << 2)) = make_float4(o[0], o[1], o[2], o[3]);
}

// ---------------------------------------------------------------------------
// Chunked selective scan (delta in X region stride 2048, z in Z stride 2048).
// Aws carries log2(e) factor -> exp2 (single v_exp_f32, no mul).
// ---------------------------------------------------------------------------
__global__ __launch_bounds__(256) void scan_pass1(
    const float* __restrict__ delta, const float* __restrict__ U,
    const float* __restrict__ xdbl, const float* __restrict__ Aws,
    float* __restrict__ cs, float* __restrict__ sdt)
{
  __shared__ float blds[CL * 16];
  const int tid = threadIdx.x;
  const int dg = blockIdx.x & 7;
  const int chunk = (blockIdx.x >> 3) & 31;
  const int b = blockIdx.x >> 8;
  const int d = (dg << 8) | tid;
  const int l0 = chunk * CL;

  for (int i = tid; i < CL * 16; i += 256) {
    int l = i >> 4, j = i & 15;
    blds[i] = xdbl[(size_t)(b * LSEQ + l0 + l) * 96 + 64 + j];
  }
  __syncthreads();

  float Ar[16];
#pragma unroll
  for (int n = 0; n < 16; ++n) Ar[n] = Aws[(d << 4) + n];
  float s[16];
#pragma unroll
  for (int n = 0; n < 16; ++n) s[n] = 0.f;
  float sumdt = 0.f;

  const float* dp = delta + ((size_t)b << 22) + ((size_t)l0 << 11) + d;
  const float* up = U + ((size_t)b << 22) + ((size_t)l0 << 11) + d;

  for (int l = 0; l < CL; ++l) {
    const float dt = dp[(size_t)l << 11];
    const float u = up[(size_t)l << 11];
    sumdt += dt;
    const float du = dt * u;
    const float* bl = &blds[l << 4];
#pragma unroll
    for (int n = 0; n < 16; ++n)
      s[n] = fmaf(s[n], __builtin_amdgcn_exp2f(dt * Ar[n]), du * bl[n]);
  }

  float* csp = cs + ((((size_t)b * NC + chunk) * 2048 + d) << 4);
#pragma unroll
  for (int n = 0; n < 4; ++n)
    *(float4*)(csp + (n << 2)) = make_float4(s[4*n], s[4*n+1], s[4*n+2], s[4*n+3]);
  sdt[((size_t)b * NC + chunk) * 2048 + d] = sumdt;
}

__global__ __launch_bounds__(256) void scan_mid(
    float* __restrict__ cs, const float* __restrict__ sdt,
    const float* __restrict__ Aws)
{
  const int b = blockIdx.x >> 3;
  const int d = ((blockIdx.x & 7) << 8) | threadIdx.x;
  float Ar[16];
#pragma unroll
  for (int n = 0; n < 16; ++n) Ar[n] = Aws[(d << 4) + n];
  float si[16];
#pragma unroll
  for (int n = 0; n < 16; ++n) si[n] = 0.f;

  for (int c = 0; c < NC; ++c) {
    const size_t base = ((size_t)b * NC + c) * 2048 + d;
    float* csp = cs + (base << 4);
    float sl[16];
#pragma unroll
    for (int n = 0; n < 4; ++n) {
      float4 v = *(const float4*)(csp + (n << 2));
      sl[4*n] = v.x; sl[4*n+1] = v.y; sl[4*n+2] = v.z; sl[4*n+3] = v.w;
    }
    const float sm = sdt[base];
#pragma unroll
    for (int n = 0; n < 4; ++n)
      *(float4*)(csp + (n << 2)) = make_float4(si[4*n], si[4*n+1], si[4*n+2], si[4*n+3]);
#pragma unroll
    for (int n = 0; n < 16; ++n)
      si[n] = fmaf(si[n], __builtin_amdgcn_exp2f(sm * Ar[n]), sl[n]);
  }
}

// scan_pass3 writes y as PACKED u32 (lo_bf16<<16 | hi_bf16) into the same U
// slot it reads u from (same thread, read-then-write, no cross-block hazard).
// gemm8_pk consumes this directly -> no fp32 split pass for the out GEMM.
__global__ __launch_bounds__(256) void scan_pass3(
    const float* __restrict__ delta, const float* __restrict__ Z,
    float* __restrict__ U,
    const float* __restrict__ xdbl, const float* __restrict__ Aws,
    const float* __restrict__ Dp, const float* __restrict__ cs)
{
  __shared__ float bclds[CL * 32];
  const int tid = threadIdx.x;
  const int dg = blockIdx.x & 7;
  const int chunk = (blockIdx.x >> 3) & 31;
  const int b = blockIdx.x >> 8;
  const int d = (dg << 8) | tid;
  const int l0 = chunk * CL;

  for (int i = tid; i < CL * 32; i += 256) {
    int l = i >> 5, j = i & 31;
    bclds[i] = xdbl[(size_t)(b * LSEQ + l0 + l) * 96 + 64 + j];
  }
  __syncthreads();

  float Ar[16];
#pragma unroll
  for (int n = 0; n < 16; ++n) Ar[n] = Aws[(d << 4) + n];
  const float Dd = Dp[d];

  const float* csp = cs + ((((size_t)b * NC + chunk) * 2048 + d) << 4);
  float s[16];
#pragma unroll
  for (int n = 0; n < 4; ++n) {
    float4 v = *(const float4*)(csp + (n << 2));
    s[4*n] = v.x; s[4*n+1] = v.y; s[4*n+2] = v.z; s[4*n+3] = v.w;
  }

  const float* dp = delta + ((size_t)b << 22) + ((size_t)l0 << 11) + d;
  const float* zp = Z + ((size_t)b << 22) + ((size_t)l0 << 11) + d;
  float* up = U + ((size_t)b << 22) + ((size_t)l0 << 11) + d;

  for (int l = 0; l < CL; ++l) {
    const float dt = dp[(size_t)l << 11];
    const float u = up[(size_t)l << 11];
    const float z = zp[(size_t)l << 11];
    const float du = dt * u;
    const float* bcl = &bclds[l << 5];
    float y = 0.f;
#pragma unroll
    for (int n = 0; n < 16; ++n) {
      s[n] = fmaf(s[n], __builtin_amdgcn_exp2f(dt * Ar[n]), du * bcl[n]);
      y = fmaf(s[n], bcl[16 + n], y);
    }
    const float yv = fmaf(u, Dd, y);
    const float yo = yv * silu_(z);
    const unsigned short h = f2bf(yo);
    const unsigned short lo = f2bf(yo - bf2f(h));
    ((unsigned int*)up)[(size_t)l << 11] = (unsigned)h | ((unsigned)lo << 16);
  }
}

// ---------------------------------------------------------------------------
extern "C" void kernel_launch(void* const* d_in, const int* in_sizes, int n_in,
                              void* d_out, int out_size, void* d_ws, size_t ws_size,
                              hipStream_t stream)
{
  const float* hs         = (const float*)d_in[0];
  const float* in_proj_w  = (const float*)d_in[4];
  const float* conv_w     = (const float*)d_in[5];
  const float* conv_b     = (const float*)d_in[6];
  const float* x_proj_w   = (const float*)d_in[7];
  const float* dt_proj_w  = (const float*)d_in[8];
  const float* dt_proj_b  = (const float*)d_in[9];
  const float* A_log      = (const float*)d_in[10];
  const float* Dp         = (const float*)d_in[11];
  const float* out_proj_w = (const float*)d_in[12];
  float* out = (float*)d_out;
  float* ws = (float*)d_ws;

  float* X     = ws + OFF_X;
  float* Z     = ws + OFF_Z;
  float* U     = ws + OFF_U;
  float* cs    = ws + OFF_CS;
  float* sdt   = ws + OFF_SDT;
  float* xdbl  = ws + OFF_XDBL;
  float* feats = ws + OFF_FEAT;
  float* Aws   = ws + OFF_AWS;
  unsigned short* A1s = (unsigned short*)(ws + OFF_S);
  unsigned short* B1s = (unsigned short*)(ws + OFF_B1);
  unsigned short* B2s = (unsigned short*)(ws + OFF_B1);

  const dim3 blk(256);

  // 0. split hs (2,097,152 float4s) + in_proj_w (1,048,576 float4s)
  split2_w<<<12288, blk, 0, stream>>>(hs, A1s, 10, (size_t)2097152,
                                      in_proj_w, B1s, 10);
  // 1a. X half: hs @ in_proj_w[0:2048]^T, full 3-pass (M=8192,N=2048,K=1024)
  //     256^2-tile phase-split; bm-panel per XCD (A fetched once per XCD).
  gemm_8ph<3><<<dim3(8, 32), dim3(512), 0, stream>>>(A1s, B1s, X, 1024, 2048);
  // 1b. Z half: hs @ in_proj_w[2048:4096]^T, hi*hi only (silu-gate budget)
  gemm_8ph<1><<<dim3(8, 32), dim3(512), 0, stream>>>(A1s, B1s + (size_t)2048 * 2048, Z, 1024, 2048);
  // 2. channel-alignment features (reads X)
  feat_kernel<<<4096, blk, 0, stream>>>(X, feats);
  // 3. depthwise conv + silu (X -> U)
  conv_kernel<<<16384, blk, 0, stream>>>(X, conv_w, conv_b, U);
  // 3b. split out_proj_w (524,288 float4s) -> 2048 blocks (overlays dead B1s)
  split2_w<<<2048, blk, 0, stream>>>(out_proj_w, B2s, 11, (size_t)524288,
                                     out_proj_w, B2s, 11);
  // 4. loss + norms + alpha + A
  alpha_kernel<<<1, blk, 0, stream>>>(feats, A_log, Aws, out + 8388608);
  // 5. x_dbl = U @ x_proj_w^T (M=8192,N=96,K=2048) — split-K=4 into cs region
  gemm_nt<0><<<dim3(2, 128, 4), blk, 0, stream>>>(U, DI, x_proj_w, DI, cs, 96, 96, 512, nullptr, (size_t)786432);
  reduce4<<<768, blk, 0, stream>>>(cs, xdbl, (size_t)786432);
  // 6. delta = softplus(x_dbl[:, :64] @ dt_proj_w^T + b) -> X region (dead x)
  gemm_nt<1><<<dim3(32, 128, 1), blk, 0, stream>>>(xdbl, 96, dt_proj_w, 64, X, DI, DI, 64, dt_proj_b, 0);
  // 7. chunked selective scan; y overwrites U as packed bf16 hi/lo u32
  scan_pass1<<<1024, blk, 0, stream>>>(X, U, xdbl, Aws, cs, sdt);
  scan_mid<<<32, blk, 0, stream>>>(cs, sdt, Aws);
  scan_pass3<<<1024, blk, 0, stream>>>(X, Z, U, xdbl, Aws, Dp, cs);
  // 8. out = y @ out_proj_w^T — phase-split kernel; packed A in two-region
  //    64B-row-stride LDS layout (bank-conflict fix) + bm-per-XCD affinity.
  gemm8_pk<<<dim3(8, 32), dim3(512), 0, stream>>>((const unsigned int*)U, B2s, out);
}

// Round 7
// 880.603 us; speedup vs baseline: 1.0164x; 1.0041x over previous
//
#include <hip/hip_runtime.h>
#include <math.h>
#include <stdint.h>

// Problem constants (fixed instance)
#define LSEQ 2048
#define DM   1024
#define DI   2048
#define NC   32     // scan chunks per sequence
#define CL   64     // scan chunk length (NC*CL == LSEQ)

// ---------------------------------------------------------------------------
// Workspace layout (float units). Total 62,914,560 floats = 251.7 MB.
//  X  [0,          16777216)  : x half of in_proj output; later delta (in place)
//  Z  [16777216,   33554432)  : z half
//  U  [33554432,   50331648)  : conv output u; scan_pass3 overwrites each slot
//                               with packed u32 (lo_bf16<<16 | hi_bf16) of y
//  S  [50331648,   58720256)  : A1' (hs split bf16) until gemm1 done, then
//                               cs(+xdbl split-K partials)/sdt/xdbl/feats/Aws
//  B1 [58720256,   62914560)  : B1' (in_proj split) -> B2' (out_proj split)
// ---------------------------------------------------------------------------
#define OFF_X     ((size_t)0)
#define OFF_Z     ((size_t)16777216)
#define OFF_U     ((size_t)33554432)
#define OFF_S     ((size_t)50331648)
#define OFF_CS    (OFF_S)                      // 4,194,304 floats (also xdbl partials)
#define OFF_SDT   (OFF_S + 4194304)            //   262,144
#define OFF_XDBL  (OFF_S + 4456448)            //   786,432
#define OFF_FEAT  (OFF_S + 5242880)            //    65,536
#define OFF_AWS   (OFF_S + 5308448)            //    32,768
#define OFF_B1    ((size_t)58720256)

__device__ __forceinline__ float silu_(float x) { return x / (1.f + __expf(-x)); }
__device__ __forceinline__ float softplus_(float x) {
  return fmaxf(x, 0.f) + log1pf(__expf(-fabsf(x)));
}
__device__ __forceinline__ unsigned short f2bf(float x) {
  unsigned int u = __float_as_uint(x);
  u += 0x7fffu + ((u >> 16) & 1u);      // RNE (inputs finite)
  return (unsigned short)(u >> 16);
}
__device__ __forceinline__ float bf2f(unsigned short h) {
  return __uint_as_float(((unsigned int)h) << 16);
}

typedef __attribute__((ext_vector_type(8))) short bf16x8;
typedef __attribute__((ext_vector_type(4))) float f32x4;

__device__ __forceinline__ void gl2lds16(const void* g, void* l) {
  __builtin_amdgcn_global_load_lds(
      (const __attribute__((address_space(1))) unsigned int*)(uintptr_t)g,
      (__attribute__((address_space(3))) unsigned int*)(uintptr_t)l,
      16, 0, 0);
}

// barrier that is also a compiler memory fence (NOT __syncthreads: that drains
// vmcnt(0) and kills the staged-load pipeline)
#define BARRIER_()                                   \
  do {                                               \
    asm volatile("" ::: "memory");                   \
    __builtin_amdgcn_s_barrier();                    \
    asm volatile("" ::: "memory");                   \
  } while (0)

// ---------------------------------------------------------------------------
// Split fp32 -> [hi | lo] bf16 per row, two tensors in one dispatch.
// Each thread handles ONE float4. Tensor a = first na4 float4-slots.
// ---------------------------------------------------------------------------
__global__ __launch_bounds__(256) void split2_w(
    const float* __restrict__ a, unsigned short* __restrict__ oa, int ksa,
    size_t na4,
    const float* __restrict__ b, unsigned short* __restrict__ ob, int ksb)
{
  size_t i4 = ((size_t)blockIdx.x << 8) + threadIdx.x;
  const float* src; unsigned short* dst; int ks;
  if (i4 < na4) { src = a; dst = oa; ks = ksa; }
  else          { src = b; dst = ob; ks = ksb; i4 -= na4; }
  const size_t flat = i4 << 2;
  const int K = 1 << ks;
  const size_t row = flat >> ks;
  const int k = (int)(flat & (size_t)(K - 1));
  float4 v = *(const float4*)(src + flat);
  float f[4] = {v.x, v.y, v.z, v.w};
  unsigned short h[4], lo[4];
#pragma unroll
  for (int c = 0; c < 4; ++c) { h[c] = f2bf(f[c]); lo[c] = f2bf(f[c] - bf2f(h[c])); }
  unsigned short* o = dst + (row << (ks + 1)) + k;
  *(uint2*)(o)     = make_uint2((unsigned)h[0]  | ((unsigned)h[1]  << 16),
                                (unsigned)h[2]  | ((unsigned)h[3]  << 16));
  *(uint2*)(o + K) = make_uint2((unsigned)lo[0] | ((unsigned)lo[1] << 16),
                                (unsigned)lo[2] | ((unsigned)lo[3] << 16));
}

// ---------------------------------------------------------------------------
// 256x256-tile phase-split split-bf16 MFMA GEMM: C[M,N] = A·B^T.
// T3+T4+T5 schedule (counted vmcnt, never drained in main loop; setprio
// around MFMA clusters; 1 barrier per phase). BK=32, 8 waves (2M x 4N),
// per-wave 128x64 output (8x4 frags). 4 phases per K-tile, one C-quadrant
// each: 24 MFMA + 12 ds_read_b128 (NPASS=3) between barriers.
// LDS: [2 dbuf][4 tensors AH,BH,AL,BL][256x32] = 128 KiB (NPASS=3).
// XOR chunk swizzle: stage slot c of row r holds global k-chunk c^((r>>1)&3);
// reader uses quad^((lm>>1)&3).
// XCD AFFINITY (r6, verified: FETCH 266->66MB on gemm8_pk): the 8 blocks
// sharing one A-panel (same bm) land on the SAME XCD:
// bm-tile = x*4 + (y>>3), bn-tile = y&7 (linear id % 8 == x = XCD).
// ---------------------------------------------------------------------------
template <int NPASS, int MH, int NH>
__device__ __forceinline__ void phase_mfma(
    const unsigned short* __restrict__ shc, f32x4 (&acc)[8][4],
    int wm, int wn, int lm, int roff)
{
  bf16x8 aH[4], bH[2], aL[4], bL[2];
#pragma unroll
  for (int ii = 0; ii < 4; ++ii) {
    const int ar = (wm + (MH * 4 + ii) * 16 + lm) * 32 + roff;
    aH[ii] = *(const bf16x8*)(shc + ar);
    if constexpr (NPASS > 1) aL[ii] = *(const bf16x8*)(shc + 2 * 8192 + ar);
  }
#pragma unroll
  for (int jj = 0; jj < 2; ++jj) {
    const int br = (wn + (NH * 2 + jj) * 16 + lm) * 32 + roff;
    bH[jj] = *(const bf16x8*)(shc + 8192 + br);
    if constexpr (NPASS > 1) bL[jj] = *(const bf16x8*)(shc + 3 * 8192 + br);
  }
  __builtin_amdgcn_s_setprio(1);
#pragma unroll
  for (int ii = 0; ii < 4; ++ii)
#pragma unroll
    for (int jj = 0; jj < 2; ++jj) {
      const int i = MH * 4 + ii, j = NH * 2 + jj;
      acc[i][j] = __builtin_amdgcn_mfma_f32_16x16x32_bf16(aH[ii], bH[jj], acc[i][j], 0, 0, 0);
      if constexpr (NPASS > 1) {
        acc[i][j] = __builtin_amdgcn_mfma_f32_16x16x32_bf16(aH[ii], bL[jj], acc[i][j], 0, 0, 0);
        acc[i][j] = __builtin_amdgcn_mfma_f32_16x16x32_bf16(aL[ii], bH[jj], acc[i][j], 0, 0, 0);
      }
    }
  __builtin_amdgcn_s_setprio(0);
}

template <int NPASS>
__global__ __launch_bounds__(512, 2) void gemm_8ph(
    const unsigned short* __restrict__ Ap, const unsigned short* __restrict__ Bp,
    float* __restrict__ C, int K, int ldc)
{
  constexpr int NTEN = (NPASS > 1) ? 4 : 2;      // AH,BH[,AL,BL]
  __shared__ unsigned short sh[2][NTEN][256 * 32];
  const int tid = threadIdx.x;
  // XCD affinity: all 8 bn-blocks of a bm-panel on one XCD (x = XCD id)
  const int bm = (((blockIdx.x << 2) | (blockIdx.y >> 3)) << 8);
  const int bn = ((blockIdx.y & 7) << 8);
  const int K2 = K * 2;
  const int wave = tid >> 6, lane = tid & 63;
  const int wm = (wave >> 2) << 7;               // 0 / 128
  const int wn = (wave & 3) << 6;                // 0 / 64 / 128 / 192
  const int lm = lane & 15, quad = lane >> 4;
  const int roff = ((quad ^ ((lm >> 1) & 3)) << 3);

  const int r0 = tid >> 2;
  const int kq = (((tid & 3) ^ ((r0 >> 1) & 3)) << 3);
  const unsigned short* a0 = Ap + (size_t)(bm + r0) * K2 + kq;        // rows 0-127
  const unsigned short* a1 = a0 + (size_t)128 * K2;                   // rows 128-255
  const unsigned short* b0 = Bp + (size_t)(bn + r0) * K2 + kq;
  const unsigned short* b1 = b0 + (size_t)128 * K2;
  const int ls0 = tid * 8, ls1 = 4096 + tid * 8; // ushort offsets in a tensor buf

  f32x4 acc[8][4] = {};
  const int NT = K >> 5;

  // prologue: stage tile 0 into buffer 0
  {
    unsigned short* s = &sh[0][0][0];
    gl2lds16(a0, s + ls0);
    gl2lds16(a1, s + ls1);
    if constexpr (NPASS > 1) {
      gl2lds16(a0 + K, s + 2 * 8192 + ls0);
      gl2lds16(a1 + K, s + 2 * 8192 + ls1);
    }
    gl2lds16(b0, s + 8192 + ls0);
    gl2lds16(b1, s + 8192 + ls1);
    if constexpr (NPASS > 1) {
      gl2lds16(b0 + K, s + 3 * 8192 + ls0);
      gl2lds16(b1 + K, s + 3 * 8192 + ls1);
    }
  }

  for (int t = 0; t < NT - 1; ++t) {
    const unsigned short* cur = &sh[t & 1][0][0];
    unsigned short* nxt = &sh[(t + 1) & 1][0][0];
    const int kn = (t + 1) << 5;

    // ---- phase 0: issue next-tile A units, publish current tile ----
    gl2lds16(a0 + kn, nxt + ls0);
    gl2lds16(a1 + kn, nxt + ls1);
    if constexpr (NPASS > 1) {
      gl2lds16(a0 + K + kn, nxt + 2 * 8192 + ls0);
      gl2lds16(a1 + K + kn, nxt + 2 * 8192 + ls1);
      asm volatile("s_waitcnt vmcnt(4)" ::: "memory");  // current tile's 8 landed
    } else {
      asm volatile("s_waitcnt vmcnt(2)" ::: "memory");  // current tile's 4 landed
    }
    BARRIER_();
    phase_mfma<NPASS, 0, 0>(cur, acc, wm, wn, lm, roff);
    BARRIER_();
    // ---- phase 1: issue next-tile B units ----
    gl2lds16(b0 + kn, nxt + 8192 + ls0);
    gl2lds16(b1 + kn, nxt + 8192 + ls1);
    if constexpr (NPASS > 1) {
      gl2lds16(b0 + K + kn, nxt + 3 * 8192 + ls0);
      gl2lds16(b1 + K + kn, nxt + 3 * 8192 + ls1);
    }
    phase_mfma<NPASS, 0, 1>(cur, acc, wm, wn, lm, roff);
    BARRIER_();
    // ---- phase 2 ----
    phase_mfma<NPASS, 1, 0>(cur, acc, wm, wn, lm, roff);
    BARRIER_();
    // ---- phase 3 (trailing barrier protects next tile's stage overwrite) ----
    phase_mfma<NPASS, 1, 1>(cur, acc, wm, wn, lm, roff);
    BARRIER_();
  }

  // peeled last tile: nothing left to issue -> drain is allowed here only
  {
    const unsigned short* cur = &sh[(NT - 1) & 1][0][0];
    asm volatile("s_waitcnt vmcnt(0)" ::: "memory");
    BARRIER_();
    phase_mfma<NPASS, 0, 0>(cur, acc, wm, wn, lm, roff);
    BARRIER_();
    phase_mfma<NPASS, 0, 1>(cur, acc, wm, wn, lm, roff);
    BARRIER_();
    phase_mfma<NPASS, 1, 0>(cur, acc, wm, wn, lm, roff);
    BARRIER_();
    phase_mfma<NPASS, 1, 1>(cur, acc, wm, wn, lm, roff);
  }

  // epilogue: C/D layout col=lane&15 (n), row=quad*4+reg (m)
#pragma unroll
  for (int i = 0; i < 8; ++i) {
    const int m = bm + wm + i * 16 + quad * 4;
#pragma unroll
    for (int j = 0; j < 4; ++j) {
      const int n = bn + wn + j * 16 + lm;
#pragma unroll
      for (int r = 0; r < 4; ++r)
        C[(size_t)(m + r) * ldc + n] = acc[i][j][r];
    }
  }
}

// ---------------------------------------------------------------------------
// Split-bf16 MFMA GEMM (m97-style 128x128) — gemm8 (PROVEN 116µs, r4).
// A_PACKED=1: A is u32 (lo<<16|hi) from scan_pass3; staging de-interleaves
// in-register (~32 bitfield VALU/thread/tile).
// XCD AFFINITY (r7): grid 8x64; xcd = blockIdx.x; bm-tile = (bx<<3)|(by>>3),
// bn-tile = by&7 -> the 8 bn-blocks of each A-panel are co-XCD and temporally
// adjacent (A-tile L2-resident), replacing the old bn-per-XCD map that made
// every XCD stream ALL of A (FETCH 266MB).
// ---------------------------------------------------------------------------
template <int NPASS, int A_PACKED>
__global__ __launch_bounds__(256) void gemm_mfma(
    const void* __restrict__ Avp, const unsigned short* __restrict__ Bp,
    float* __restrict__ C, int K, int ldc)
{
  __shared__ unsigned short AsH[128 * 32];
  __shared__ unsigned short BsH[128 * 32];
  __shared__ unsigned short AsL[(NPASS > 1) ? 128 * 32 : 8];
  __shared__ unsigned short BsL[(NPASS > 1) ? 128 * 32 : 8];
  const int tid = threadIdx.x;
  // bm-panel-per-XCD affinity (x = XCD id under x-fastest linear dispatch)
  const int bm = (((blockIdx.x << 3) | (blockIdx.y >> 3)) << 7);
  const int bn = ((blockIdx.y & 7) << 7);
  const int K2 = K * 2;

  const int wave = tid >> 6, lane = tid & 63;
  const int wm = (wave >> 1) << 6, wn = (wave & 1) << 6;
  const int lm = lane & 15, quad = lane >> 4;
  const int sw = (lm >> 1) & 3;        // reader swizzle (row>>1)&3 == (lm>>1)&3

  f32x4 acc[4][4] = {};

  const int r0 = tid >> 2;
  const int kq = ((tid & 3) ^ ((r0 >> 1) & 3)) << 3;   // element offset
  const unsigned short* BgH0 = Bp + (size_t)(bn + r0) * K2 + kq;
  const unsigned short* BgH1 = Bp + (size_t)(bn + 64 + r0) * K2 + kq;
  unsigned short* lA0 = &AsH[(size_t)tid * 8];
  unsigned short* lA1 = &AsH[(size_t)(256 + tid) * 8];
  unsigned short* lB0 = &BsH[(size_t)tid * 8];
  unsigned short* lB1 = &BsH[(size_t)(256 + tid) * 8];
  unsigned short* lAl0 = (NPASS > 1) ? &AsL[(size_t)tid * 8] : nullptr;
  unsigned short* lAl1 = (NPASS > 1) ? &AsL[(size_t)(256 + tid) * 8] : nullptr;
  unsigned short* lBl0 = (NPASS > 1) ? &BsL[(size_t)tid * 8] : nullptr;
  unsigned short* lBl1 = (NPASS > 1) ? &BsL[(size_t)(256 + tid) * 8] : nullptr;

  const unsigned short* AgH0 = nullptr; const unsigned short* AgH1 = nullptr;
  const unsigned int* Apk0 = nullptr; const unsigned int* Apk1 = nullptr;
  if (A_PACKED) {
    const unsigned int* Au = (const unsigned int*)Avp;
    Apk0 = Au + (size_t)(bm + r0) * K + kq;
    Apk1 = Au + (size_t)(bm + 64 + r0) * K + kq;
  } else {
    const unsigned short* Ab = (const unsigned short*)Avp;
    AgH0 = Ab + (size_t)(bm + r0) * K2 + kq;
    AgH1 = Ab + (size_t)(bm + 64 + r0) * K2 + kq;
  }

  for (int k0 = 0; k0 < K; k0 += 32) {
    __syncthreads();
    if (A_PACKED) {
      uint4 u0 = *(const uint4*)(Apk0 + k0);
      uint4 u1 = *(const uint4*)(Apk0 + k0 + 4);
      uint4 v0 = *(const uint4*)(Apk1 + k0);
      uint4 v1 = *(const uint4*)(Apk1 + k0 + 4);
      unsigned p[8] = {u0.x, u0.y, u0.z, u0.w, u1.x, u1.y, u1.z, u1.w};
      unsigned q[8] = {v0.x, v0.y, v0.z, v0.w, v1.x, v1.y, v1.z, v1.w};
      unsigned hu[4], lu[4], hv[4], lv[4];
#pragma unroll
      for (int c = 0; c < 4; ++c) {
        hu[c] = (p[2*c] & 0xffffu) | (p[2*c+1] << 16);
        lu[c] = (p[2*c] >> 16)     | (p[2*c+1] & 0xffff0000u);
        hv[c] = (q[2*c] & 0xffffu) | (q[2*c+1] << 16);
        lv[c] = (q[2*c] >> 16)     | (q[2*c+1] & 0xffff0000u);
      }
      *(uint4*)lA0  = make_uint4(hu[0], hu[1], hu[2], hu[3]);
      *(uint4*)lA1  = make_uint4(hv[0], hv[1], hv[2], hv[3]);
      if (NPASS > 1) {
        *(uint4*)lAl0 = make_uint4(lu[0], lu[1], lu[2], lu[3]);
        *(uint4*)lAl1 = make_uint4(lv[0], lv[1], lv[2], lv[3]);
      }
    } else {
      gl2lds16(AgH0 + k0, lA0);
      gl2lds16(AgH1 + k0, lA1);
      if (NPASS > 1) {
        gl2lds16(AgH0 + K + k0, lAl0);
        gl2lds16(AgH1 + K + k0, lAl1);
      }
    }
    gl2lds16(BgH0 + k0, lB0);
    gl2lds16(BgH1 + k0, lB1);
    if (NPASS > 1) {
      gl2lds16(BgH0 + K + k0, lBl0);
      gl2lds16(BgH1 + K + k0, lBl1);
    }
    __syncthreads();

    bf16x8 aH[4], bH[4];
#pragma unroll
    for (int i = 0; i < 4; ++i)
      aH[i] = *(const bf16x8*)&AsH[(wm + i * 16 + lm) * 32 + ((quad ^ sw) << 3)];
#pragma unroll
    for (int j = 0; j < 4; ++j)
      bH[j] = *(const bf16x8*)&BsH[(wn + j * 16 + lm) * 32 + ((quad ^ sw) << 3)];
#pragma unroll
    for (int i = 0; i < 4; ++i)
#pragma unroll
      for (int j = 0; j < 4; ++j)
        acc[i][j] = __builtin_amdgcn_mfma_f32_16x16x32_bf16(aH[i], bH[j], acc[i][j], 0, 0, 0);
    if (NPASS > 1) {
      bf16x8 aL[4], bL[4];
#pragma unroll
      for (int i = 0; i < 4; ++i)
        aL[i] = *(const bf16x8*)&AsL[(wm + i * 16 + lm) * 32 + ((quad ^ sw) << 3)];
#pragma unroll
      for (int j = 0; j < 4; ++j)
        bL[j] = *(const bf16x8*)&BsL[(wn + j * 16 + lm) * 32 + ((quad ^ sw) << 3)];
#pragma unroll
      for (int i = 0; i < 4; ++i)
#pragma unroll
        for (int j = 0; j < 4; ++j) {
          acc[i][j] = __builtin_amdgcn_mfma_f32_16x16x32_bf16(aH[i], bL[j], acc[i][j], 0, 0, 0);
          acc[i][j] = __builtin_amdgcn_mfma_f32_16x16x32_bf16(aL[i], bH[j], acc[i][j], 0, 0, 0);
        }
    }
  }

  // epilogue: C/D layout col=lane&15 (n, from B), row=quad*4+reg (m, from A)
#pragma unroll
  for (int i = 0; i < 4; ++i) {
    const int m = bm + wm + i * 16 + quad * 4;
#pragma unroll
    for (int j = 0; j < 4; ++j) {
      const int n = bn + wn + j * 16 + lm;
#pragma unroll
      for (int r = 0; r < 4; ++r)
        C[(size_t)(m + r) * ldc + n] = acc[i][j][r];
    }
  }
}

// ---------------------------------------------------------------------------
// fp32 NT GEMM (small shapes): C[M,N] = A[M,K]·B[N,K]^T. 64x64 tile, BK=16.
// EPI: 0 none, 1 softplus(acc + bias[n]). Split-K via blockIdx.z: segment z
// reads k-window [z*K, (z+1)*K) and writes C + z*cseg.
// ---------------------------------------------------------------------------
template <int EPI>
__global__ __launch_bounds__(256) void gemm_nt(
    const float* __restrict__ A, int lda,
    const float* __restrict__ B, int ldb,
    float* __restrict__ C, int ldc,
    int N, int K, const float* __restrict__ bias, size_t cseg)
{
  __shared__ float As[16][68];
  __shared__ float Bs[16][68];
  const int tid = threadIdx.x;
  const int bm = blockIdx.y << 6;
  const int bn = blockIdx.x << 6;
  const int kz = blockIdx.z;
  A += (size_t)kz * K;
  B += (size_t)kz * K;
  C += (size_t)kz * cseg;
  const int lr = tid >> 2;
  const int lk = (tid & 3) << 2;
  const int tx = tid & 15, ty = tid >> 4;

  float acc[4][4];
#pragma unroll
  for (int i = 0; i < 4; ++i)
#pragma unroll
    for (int j = 0; j < 4; ++j) acc[i][j] = 0.f;

  const float* Apt = A + (size_t)(bm + lr) * lda + lk;
  const float* Bpt = B + (size_t)(bn + lr) * ldb + lk;
  const bool bv = (bn + lr) < N;

  for (int k0 = 0; k0 < K; k0 += 16) {
    float4 a4 = *(const float4*)(Apt + k0);
    float4 b4 = bv ? *(const float4*)(Bpt + k0) : make_float4(0.f, 0.f, 0.f, 0.f);
    __syncthreads();
    As[lk + 0][lr] = a4.x; As[lk + 1][lr] = a4.y;
    As[lk + 2][lr] = a4.z; As[lk + 3][lr] = a4.w;
    Bs[lk + 0][lr] = b4.x; Bs[lk + 1][lr] = b4.y;
    Bs[lk + 2][lr] = b4.z; Bs[lk + 3][lr] = b4.w;
    __syncthreads();
#pragma unroll
    for (int k = 0; k < 16; ++k) {
      const float4 av = *(const float4*)(&As[k][ty << 2]);
      const float4 bw = *(const float4*)(&Bs[k][tx << 2]);
      float a4r[4] = {av.x, av.y, av.z, av.w};
      float b4r[4] = {bw.x, bw.y, bw.z, bw.w};
#pragma unroll
      for (int i = 0; i < 4; ++i)
#pragma unroll
        for (int j = 0; j < 4; ++j)
          acc[i][j] = fmaf(a4r[i], b4r[j], acc[i][j]);
    }
  }

  const int m = bm + (ty << 2);
  const int n = bn + (tx << 2);
#pragma unroll
  for (int i = 0; i < 4; ++i) {
    float v[4] = {acc[i][0], acc[i][1], acc[i][2], acc[i][3]};
    if (EPI == 1) {
#pragma unroll
      for (int j = 0; j < 4; ++j)
        if (n + j < N) v[j] = softplus_(v[j] + bias[n + j]);
    }
    if (n + 3 < N) {
      *(float4*)(C + (size_t)(m + i) * ldc + n) = make_float4(v[0], v[1], v[2], v[3]);
    } else {
#pragma unroll
      for (int j = 0; j < 4; ++j)
        if (n + j < N) C[(size_t)(m + i) * ldc + n + j] = v[j];
    }
  }
}

// ---------------------------------------------------------------------------
// 4-way split-K reduce: O[i] = sum_z P[z*seg + i], over n4 float4s.
// ---------------------------------------------------------------------------
__global__ __launch_bounds__(256) void reduce4(
    const float* __restrict__ P, float* __restrict__ O, size_t seg)
{
  const size_t i = ((size_t)blockIdx.x << 8) + threadIdx.x;
  float4 a = ((const float4*)P)[i];
  float4 b = ((const float4*)(P + seg))[i];
  float4 c = ((const float4*)(P + 2 * seg))[i];
  float4 d = ((const float4*)(P + 3 * seg))[i];
  ((float4*)O)[i] = make_float4(a.x + b.x + c.x + d.x,
                                a.y + b.y + c.y + d.y,
                                a.z + b.z + c.z + d.z,
                                a.w + b.w + c.w + d.w);
}

// ---------------------------------------------------------------------------
// Channel alignment features (rfft2 16x16 magnitude band ratio). X stride 2048.
// ---------------------------------------------------------------------------
__global__ __launch_bounds__(256) void feat_kernel(
    const float* __restrict__ X, float* __restrict__ features)
{
  __shared__ float xin[256][17];
  __shared__ float Rf[16 * 315];
  __shared__ float tc[16], ts[16];
  __shared__ float part2[16][16][2];

  const int tid = threadIdx.x;
  const int frame = blockIdx.x >> 7;
  const int cg = blockIdx.x & 127;
  const int b = frame >> 3, t = frame & 7;
  const int c0 = cg << 4;

  if (tid < 16) {
    float ang = 0.39269908169872414f * (float)tid;
    tc[tid] = cosf(ang);
    ts[tid] = sinf(ang);
  }
  const float* xb = X + ((size_t)(b * LSEQ + t * 256) << 11) + c0;
  for (int i = tid; i < 256 * 16; i += 256) {
    int hw = i >> 4, ci = i & 15;
    xin[hw][ci] = xb[((size_t)hw << 11) + ci];
  }
  __syncthreads();

  {
    const int ci = tid & 15, h = tid >> 4;
    float re[9], im[9];
#pragma unroll
    for (int kw = 0; kw < 9; ++kw) { re[kw] = 0.f; im[kw] = 0.f; }
#pragma unroll
    for (int w = 0; w < 16; ++w) {
      float x = xin[(h << 4) + w][ci];
#pragma unroll
      for (int kw = 0; kw < 9; ++kw) {
        int ph = (kw * w) & 15;
        re[kw] = fmaf(x, tc[ph], re[kw]);
        im[kw] = fmaf(-x, ts[ph], im[kw]);
      }
    }
#pragma unroll
    for (int kw = 0; kw < 9; ++kw) {
      Rf[ci * 315 + kw * 35 + 2 * h]     = re[kw];
      Rf[ci * 315 + kw * 35 + 2 * h + 1] = im[kw];
    }
  }
  __syncthreads();

  {
    const int ci = tid & 15, kh = tid >> 4;
    float ut = 0.f, tt = 0.f;
    for (int kw = 0; kw < 9; ++kw) {
      float fre = 0.f, fim = 0.f;
#pragma unroll
      for (int h = 0; h < 16; ++h) {
        int ph = (kh * h) & 15;
        float c = tc[ph], s = ts[ph];
        float rr = Rf[ci * 315 + kw * 35 + 2 * h];
        float ri = Rf[ci * 315 + kw * 35 + 2 * h + 1];
        fre += rr * c + ri * s;
        fim += ri * c - rr * s;
      }
      float mag = sqrtf(fre * fre + fim * fim + 1e-8f);
      int sh = (kh + 8) & 15;
      int sw2 = kw + 4; if (sw2 >= 9) sw2 -= 9;
      float dh = (float)(sh - 8) / 16.0f;
      float dw = (float)(sw2 - 4) / 9.0f;
      tt += mag;
      if (dh * dh + dw * dw >= 0.25f) ut += mag;
    }
    part2[ci][kh][0] = ut;
    part2[ci][kh][1] = tt;
  }
  __syncthreads();

  if (tid < 16) {
    float ut = 0.f, tt = 0.f;
    for (int kh = 0; kh < 16; ++kh) { ut += part2[tid][kh][0]; tt += part2[tid][kh][1]; }
    features[frame * DI + c0 + tid] = ut / (tt + 1e-8f);
  }
}

// ---------------------------------------------------------------------------
// loss + norms + softmax(mean feat) + attention + A_max/A_min + A out. 1 block.
// Aws is pre-scaled by log2(e): scan kernels use native exp2.
// ---------------------------------------------------------------------------
__global__ __launch_bounds__(256) void alpha_kernel(
    const float* __restrict__ feats, const float* __restrict__ A_log,
    float* __restrict__ Aws, float* __restrict__ loss_out)
{
  __shared__ float red[256];
  __shared__ float invn[32];
  __shared__ float PT[32][257];
  __shared__ float AM[256][17];
  __shared__ float sAmax[16], sAmin[16];
  const int tid = threadIdx.x;

  float pn[32];
#pragma unroll
  for (int i = 0; i < 32; ++i) pn[i] = 0.f;
  float md[8];
#pragma unroll
  for (int j = 0; j < 8; ++j) md[j] = 0.f;
  for (int i = 0; i < 32; ++i) {
#pragma unroll
    for (int j = 0; j < 8; ++j) {
      float v = feats[(i << 11) + tid + (j << 8)];
      pn[i] = fmaf(v, v, pn[i]);
      md[j] += v;
    }
  }
#pragma unroll
  for (int j = 0; j < 8; ++j) md[j] *= (1.f / 32.f);
#pragma unroll
  for (int i = 0; i < 32; ++i) PT[i][tid] = pn[i];
  __syncthreads();
  if (tid < 32) {
    float s = 0.f;
    for (int k = 0; k < 256; ++k) s += PT[tid][k];
    invn[tid] = 1.f / fmaxf(sqrtf(s), 1e-12f);
  }
  __syncthreads();

  float gsq = 0.f;
#pragma unroll
  for (int j = 0; j < 8; ++j) {
    float gd = 0.f;
    for (int i = 0; i < 32; ++i)
      gd = fmaf(feats[(i << 11) + tid + (j << 8)], invn[i], gd);
    gsq = fmaf(gd, gd, gsq);
  }
  red[tid] = gsq; __syncthreads();
  for (int s = 128; s > 0; s >>= 1) { if (tid < s) red[tid] += red[tid + s]; __syncthreads(); }
  if (tid == 0) loss_out[0] = 1.f - red[0] * (1.f / 1024.f);
  __syncthreads();

  float lm = md[0];
#pragma unroll
  for (int j = 1; j < 8; ++j) lm = fmaxf(lm, md[j]);
  red[tid] = lm; __syncthreads();
  for (int s = 128; s > 0; s >>= 1) { if (tid < s) red[tid] = fmaxf(red[tid], red[tid + s]); __syncthreads(); }
  const float mmax = red[0]; __syncthreads();

  float p[8]; float ps = 0.f;
#pragma unroll
  for (int j = 0; j < 8; ++j) { p[j] = __expf(md[j] - mmax); ps += p[j]; }
  red[tid] = ps; __syncthreads();
  for (int s = 128; s > 0; s >>= 1) { if (tid < s) red[tid] += red[tid + s]; __syncthreads(); }
  const float psum = red[0]; __syncthreads();

  float amaxl[16], aminl[16], rn[8];
#pragma unroll
  for (int n = 0; n < 16; ++n) { amaxl[n] = -1e30f; aminl[n] = 1e30f; }
#pragma unroll
  for (int j = 0; j < 8; ++j) {
    const int d = tid + (j << 8);
    float ss = 0.f;
#pragma unroll
    for (int n = 0; n < 16; ++n) {
      float a = A_log[(d << 4) + n];
      float e = __expf(a);
      ss = fmaf(e, e, ss);
      amaxl[n] = fmaxf(amaxl[n], a);
      aminl[n] = fminf(aminl[n], a);
    }
    rn[j] = sqrtf(ss);
  }
  float rm = rn[0];
#pragma unroll
  for (int j = 1; j < 8; ++j) rm = fmaxf(rm, rn[j]);
  red[tid] = rm; __syncthreads();
  for (int s = 128; s > 0; s >>= 1) { if (tid < s) red[tid] = fmaxf(red[tid], red[tid + s]); __syncthreads(); }
  const float rnmax = red[0]; __syncthreads();

#pragma unroll
  for (int n = 0; n < 16; ++n) AM[tid][n] = amaxl[n];
  __syncthreads();
  if (tid < 16) { float m = -1e30f; for (int i = 0; i < 256; ++i) m = fmaxf(m, AM[i][tid]); sAmax[tid] = m; }
  __syncthreads();
#pragma unroll
  for (int n = 0; n < 16; ++n) AM[tid][n] = aminl[n];
  __syncthreads();
  if (tid < 16) { float m = 1e30f; for (int i = 0; i < 256; ++i) m = fminf(m, AM[i][tid]); sAmin[tid] = m; }
  __syncthreads();

  const float irn = 1.f / (rnmax + 1e-8f);
#pragma unroll
  for (int j = 0; j < 8; ++j) {
    const int d = tid + (j << 8);
    const float att = rn[j] * irn;
    const float f = p[j] / psum;
    const float alpha = fminf(fmaxf(f * (1.f - att), 0.f), 1.f);
#pragma unroll
    for (int n = 0; n < 16; ++n) {
      float a = A_log[(d << 4) + n];
      float fl = sAmax[n] + sAmin[n] - a;
      float an = (1.f - alpha) * a + alpha * fl;
      // pre-fold log2(e) so scan kernels can use native v_exp_f32 (exp2)
      Aws[(d << 4) + n] = -__expf(an) * 1.4426950408889634f;
    }
  }
}

// ---------------------------------------------------------------------------
// Depthwise causal conv (k=4) + bias + SiLU, float4 per thread.
// X (b,l,2048) -> U (b,l,2048)
// ---------------------------------------------------------------------------
__global__ __launch_bounds__(256) void conv_kernel(
    const float* __restrict__ X, const float* __restrict__ cw,
    const float* __restrict__ cb, float* __restrict__ U)
{
  const size_t i4 = ((size_t)blockIdx.x << 8) + threadIdx.x;  // < 4,194,304
  const int e4 = (int)(i4 & 511);
  const size_t row = i4 >> 9;          // b*2048 + l
  const int l = (int)(row & 2047);
  const float* xr = X + (row << 11) + (e4 << 2);
  const float4 z4 = make_float4(0.f, 0.f, 0.f, 0.f);
  float4 x0 = *(const float4*)xr;
  float4 x1 = (l >= 1) ? *(const float4*)(xr - 2048) : z4;
  float4 x2 = (l >= 2) ? *(const float4*)(xr - 4096) : z4;
  float4 x3 = (l >= 3) ? *(const float4*)(xr - 6144) : z4;
  const float4* cwf = (const float4*)cw;
  float4 bi = *(const float4*)(cb + (e4 << 2));
  float x0a[4] = {x0.x, x0.y, x0.z, x0.w};
  float x1a[4] = {x1.x, x1.y, x1.z, x1.w};
  float x2a[4] = {x2.x, x2.y, x2.z, x2.w};
  float x3a[4] = {x3.x, x3.y, x3.z, x3.w};
  float bia[4] = {bi.x, bi.y, bi.z, bi.w};
  float o[4];
#pragma unroll
  for (int c = 0; c < 4; ++c) {
    float4 w = cwf[(e4 << 2) + c];
    float acc = bia[c];
    acc = fmaf(x3a[c], w.x, acc);
    acc = fmaf(x2a[c], w.y, acc);
    acc = fmaf(x1a[c], w.z, acc);
    acc = fmaf(x0a[c], w.w, acc);
    o[c] = silu_(acc);
  }
  *(float4*)(U + (i4 << 2)) = make_float4(o[0], o[1], o[2], o[3]);
}

// ---------------------------------------------------------------------------
// Chunked selective scan (delta in X region stride 2048, z in Z stride 2048).
// Aws carries log2(e) factor -> exp2 (single v_exp_f32, no mul).
// ---------------------------------------------------------------------------
__global__ __launch_bounds__(256) void scan_pass1(
    const float* __restrict__ delta, const float* __restrict__ U,
    const float* __restrict__ xdbl, const float* __restrict__ Aws,
    float* __restrict__ cs, float* __restrict__ sdt)
{
  __shared__ float blds[CL * 16];
  const int tid = threadIdx.x;
  const int dg = blockIdx.x & 7;
  const int chunk = (blockIdx.x >> 3) & 31;
  const int b = blockIdx.x >> 8;
  const int d = (dg << 8) | tid;
  const int l0 = chunk * CL;

  for (int i = tid; i < CL * 16; i += 256) {
    int l = i >> 4, j = i & 15;
    blds[i] = xdbl[(size_t)(b * LSEQ + l0 + l) * 96 + 64 + j];
  }
  __syncthreads();

  float Ar[16];
#pragma unroll
  for (int n = 0; n < 16; ++n) Ar[n] = Aws[(d << 4) + n];
  float s[16];
#pragma unroll
  for (int n = 0; n < 16; ++n) s[n] = 0.f;
  float sumdt = 0.f;

  const float* dp = delta + ((size_t)b << 22) + ((size_t)l0 << 11) + d;
  const float* up = U + ((size_t)b << 22) + ((size_t)l0 << 11) + d;

  for (int l = 0; l < CL; ++l) {
    const float dt = dp[(size_t)l << 11];
    const float u = up[(size_t)l << 11];
    sumdt += dt;
    const float du = dt * u;
    const float* bl = &blds[l << 4];
#pragma unroll
    for (int n = 0; n < 16; ++n)
      s[n] = fmaf(s[n], __builtin_amdgcn_exp2f(dt * Ar[n]), du * bl[n]);
  }

  float* csp = cs + ((((size_t)b * NC + chunk) * 2048 + d) << 4);
#pragma unroll
  for (int n = 0; n < 4; ++n)
    *(float4*)(csp + (n << 2)) = make_float4(s[4*n], s[4*n+1], s[4*n+2], s[4*n+3]);
  sdt[((size_t)b * NC + chunk) * 2048 + d] = sumdt;
}

__global__ __launch_bounds__(256) void scan_mid(
    float* __restrict__ cs, const float* __restrict__ sdt,
    const float* __restrict__ Aws)
{
  const int b = blockIdx.x >> 3;
  const int d = ((blockIdx.x & 7) << 8) | threadIdx.x;
  float Ar[16];
#pragma unroll
  for (int n = 0; n < 16; ++n) Ar[n] = Aws[(d << 4) + n];
  float si[16];
#pragma unroll
  for (int n = 0; n < 16; ++n) si[n] = 0.f;

  for (int c = 0; c < NC; ++c) {
    const size_t base = ((size_t)b * NC + c) * 2048 + d;
    float* csp = cs + (base << 4);
    float sl[16];
#pragma unroll
    for (int n = 0; n < 4; ++n) {
      float4 v = *(const float4*)(csp + (n << 2));
      sl[4*n] = v.x; sl[4*n+1] = v.y; sl[4*n+2] = v.z; sl[4*n+3] = v.w;
    }
    const float sm = sdt[base];
#pragma unroll
    for (int n = 0; n < 4; ++n)
      *(float4*)(csp + (n << 2)) = make_float4(si[4*n], si[4*n+1], si[4*n+2], si[4*n+3]);
#pragma unroll
    for (int n = 0; n < 16; ++n)
      si[n] = fmaf(si[n], __builtin_amdgcn_exp2f(sm * Ar[n]), sl[n]);
  }
}

// scan_pass3 writes y as PACKED u32 (lo_bf16<<16 | hi_bf16) into the same U
// slot it reads u from (same thread, read-then-write, no cross-block hazard).
// gemm_mfma<3,1> (A_PACKED) consumes this directly -> no fp32 split in GEMM.
__global__ __launch_bounds__(256) void scan_pass3(
    const float* __restrict__ delta, const float* __restrict__ Z,
    float* __restrict__ U,
    const float* __restrict__ xdbl, const float* __restrict__ Aws,
    const float* __restrict__ Dp, const float* __restrict__ cs)
{
  __shared__ float bclds[CL * 32];
  const int tid = threadIdx.x;
  const int dg = blockIdx.x & 7;
  const int chunk = (blockIdx.x >> 3) & 31;
  const int b = blockIdx.x >> 8;
  const int d = (dg << 8) | tid;
  const int l0 = chunk * CL;

  for (int i = tid; i < CL * 32; i += 256) {
    int l = i >> 5, j = i & 31;
    bclds[i] = xdbl[(size_t)(b * LSEQ + l0 + l) * 96 + 64 + j];
  }
  __syncthreads();

  float Ar[16];
#pragma unroll
  for (int n = 0; n < 16; ++n) Ar[n] = Aws[(d << 4) + n];
  const float Dd = Dp[d];

  const float* csp = cs + ((((size_t)b * NC + chunk) * 2048 + d) << 4);
  float s[16];
#pragma unroll
  for (int n = 0; n < 4; ++n) {
    float4 v = *(const float4*)(csp + (n << 2));
    s[4*n] = v.x; s[4*n+1] = v.y; s[4*n+2] = v.z; s[4*n+3] = v.w;
  }

  const float* dp = delta + ((size_t)b << 22) + ((size_t)l0 << 11) + d;
  const float* zp = Z + ((size_t)b << 22) + ((size_t)l0 << 11) + d;
  float* up = U + ((size_t)b << 22) + ((size_t)l0 << 11) + d;

  for (int l = 0; l < CL; ++l) {
    const float dt = dp[(size_t)l << 11];
    const float u = up[(size_t)l << 11];
    const float z = zp[(size_t)l << 11];
    const float du = dt * u;
    const float* bcl = &bclds[l << 5];
    float y = 0.f;
#pragma unroll
    for (int n = 0; n < 16; ++n) {
      s[n] = fmaf(s[n], __builtin_amdgcn_exp2f(dt * Ar[n]), du * bcl[n]);
      y = fmaf(s[n], bcl[16 + n], y);
    }
    const float yv = fmaf(u, Dd, y);
    const float yo = yv * silu_(z);
    const unsigned short h = f2bf(yo);
    const unsigned short lo = f2bf(yo - bf2f(h));
    ((unsigned int*)up)[(size_t)l << 11] = (unsigned)h | ((unsigned)lo << 16);
  }
}

// ---------------------------------------------------------------------------
extern "C" void kernel_launch(void* const* d_in, const int* in_sizes, int n_in,
                              void* d_out, int out_size, void* d_ws, size_t ws_size,
                              hipStream_t stream)
{
  const float* hs         = (const float*)d_in[0];
  const float* in_proj_w  = (const float*)d_in[4];
  const float* conv_w     = (const float*)d_in[5];
  const float* conv_b     = (const float*)d_in[6];
  const float* x_proj_w   = (const float*)d_in[7];
  const float* dt_proj_w  = (const float*)d_in[8];
  const float* dt_proj_b  = (const float*)d_in[9];
  const float* A_log      = (const float*)d_in[10];
  const float* Dp         = (const float*)d_in[11];
  const float* out_proj_w = (const float*)d_in[12];
  float* out = (float*)d_out;
  float* ws = (float*)d_ws;

  float* X     = ws + OFF_X;
  float* Z     = ws + OFF_Z;
  float* U     = ws + OFF_U;
  float* cs    = ws + OFF_CS;
  float* sdt   = ws + OFF_SDT;
  float* xdbl  = ws + OFF_XDBL;
  float* feats = ws + OFF_FEAT;
  float* Aws   = ws + OFF_AWS;
  unsigned short* A1s = (unsigned short*)(ws + OFF_S);
  unsigned short* B1s = (unsigned short*)(ws + OFF_B1);
  unsigned short* B2s = (unsigned short*)(ws + OFF_B1);

  const dim3 blk(256);

  // 0. split hs (2,097,152 float4s) + in_proj_w (1,048,576 float4s)
  split2_w<<<12288, blk, 0, stream>>>(hs, A1s, 10, (size_t)2097152,
                                      in_proj_w, B1s, 10);
  // 1a. X half: hs @ in_proj_w[0:2048]^T, full 3-pass (M=8192,N=2048,K=1024)
  //     256^2-tile phase-split; bm-panel per XCD (A fetched once per XCD).
  gemm_8ph<3><<<dim3(8, 32), dim3(512), 0, stream>>>(A1s, B1s, X, 1024, 2048);
  // 1b. Z half: hs @ in_proj_w[2048:4096]^T, hi*hi only (silu-gate budget)
  gemm_8ph<1><<<dim3(8, 32), dim3(512), 0, stream>>>(A1s, B1s + (size_t)2048 * 2048, Z, 1024, 2048);
  // 2. channel-alignment features (reads X)
  feat_kernel<<<4096, blk, 0, stream>>>(X, feats);
  // 3. depthwise conv + silu (X -> U)
  conv_kernel<<<16384, blk, 0, stream>>>(X, conv_w, conv_b, U);
  // 3b. split out_proj_w (524,288 float4s) -> 2048 blocks (overlays dead B1s)
  split2_w<<<2048, blk, 0, stream>>>(out_proj_w, B2s, 11, (size_t)524288,
                                     out_proj_w, B2s, 11);
  // 4. loss + norms + alpha + A
  alpha_kernel<<<1, blk, 0, stream>>>(feats, A_log, Aws, out + 8388608);
  // 5. x_dbl = U @ x_proj_w^T (M=8192,N=96,K=2048) — split-K=4 into cs region
  gemm_nt<0><<<dim3(2, 128, 4), blk, 0, stream>>>(U, DI, x_proj_w, DI, cs, 96, 96, 512, nullptr, (size_t)786432);
  reduce4<<<768, blk, 0, stream>>>(cs, xdbl, (size_t)786432);
  // 6. delta = softplus(x_dbl[:, :64] @ dt_proj_w^T + b) -> X region (dead x)
  gemm_nt<1><<<dim3(32, 128, 1), blk, 0, stream>>>(xdbl, 96, dt_proj_w, 64, X, DI, DI, 64, dt_proj_b, 0);
  // 7. chunked selective scan; y overwrites U as packed bf16 hi/lo u32
  scan_pass1<<<1024, blk, 0, stream>>>(X, U, xdbl, Aws, cs, sdt);
  scan_mid<<<32, blk, 0, stream>>>(cs, sdt, Aws);
  scan_pass3<<<1024, blk, 0, stream>>>(X, Z, U, xdbl, Aws, Dp, cs);
  // 8. out = y @ out_proj_w^T — proven 128x128 kernel (r4, 116µs), packed A,
  //    with bm-panel-per-XCD affinity (r6-verified FETCH mechanism).
  gemm_mfma<3, 1><<<dim3(8, 64), blk, 0, stream>>>(U, B2s, out, 2048, 1024);
}

// Round 8
// 837.606 us; speedup vs baseline: 1.0686x; 1.0513x over previous
//
#include <hip/hip_runtime.h>
#include <math.h>
#include <stdint.h>

// Problem constants (fixed instance)
#define LSEQ 2048
#define DM   1024
#define DI   2048
#define NC   32     // scan chunks per sequence
#define CL   64     // scan chunk length (NC*CL == LSEQ)

// ---------------------------------------------------------------------------
// Workspace layout (float units). Total 62,914,560 floats = 251.7 MB.
//  X  [0,          16777216)  : x half of in_proj output; later delta (in place)
//  Z  [16777216,   33554432)  : z half
//  U  [33554432,   50331648)  : conv output u; scan_pass3 overwrites each slot
//                               with packed u32 (lo_bf16<<16 | hi_bf16) of y
//  S  [50331648,   58720256)  : A1' (hs split bf16) until gemm1 done, then
//                               cs(+xdbl split-K partials)/sdt/xdbl/feats/Aws
//  B1 [58720256,   62914560)  : B1' (in_proj split) -> B2' (out_proj split)
// ---------------------------------------------------------------------------
#define OFF_X     ((size_t)0)
#define OFF_Z     ((size_t)16777216)
#define OFF_U     ((size_t)33554432)
#define OFF_S     ((size_t)50331648)
#define OFF_CS    (OFF_S)                      // 4,194,304 floats (also xdbl partials)
#define OFF_SDT   (OFF_S + 4194304)            //   262,144
#define OFF_XDBL  (OFF_S + 4456448)            //   786,432
#define OFF_FEAT  (OFF_S + 5242880)            //    65,536
#define OFF_AWS   (OFF_S + 5308448)            //    32,768
#define OFF_B1    ((size_t)58720256)

__device__ __forceinline__ float silu_(float x) { return x / (1.f + __expf(-x)); }
__device__ __forceinline__ float softplus_(float x) {
  return fmaxf(x, 0.f) + log1pf(__expf(-fabsf(x)));
}
__device__ __forceinline__ unsigned short f2bf(float x) {
  unsigned int u = __float_as_uint(x);
  u += 0x7fffu + ((u >> 16) & 1u);      // RNE (inputs finite)
  return (unsigned short)(u >> 16);
}
__device__ __forceinline__ float bf2f(unsigned short h) {
  return __uint_as_float(((unsigned int)h) << 16);
}

typedef __attribute__((ext_vector_type(8))) short bf16x8;
typedef __attribute__((ext_vector_type(4))) float f32x4;

__device__ __forceinline__ void gl2lds16(const void* g, void* l) {
  __builtin_amdgcn_global_load_lds(
      (const __attribute__((address_space(1))) unsigned int*)(uintptr_t)g,
      (__attribute__((address_space(3))) unsigned int*)(uintptr_t)l,
      16, 0, 0);
}

// barrier that is also a compiler memory fence (NOT __syncthreads: that drains
// vmcnt(0) and kills the staged-load pipeline)
#define BARRIER_()                                   \
  do {                                               \
    asm volatile("" ::: "memory");                   \
    __builtin_amdgcn_s_barrier();                    \
    asm volatile("" ::: "memory");                   \
  } while (0)

// ---------------------------------------------------------------------------
// Split fp32 -> [hi | lo] bf16 per row, two tensors in one dispatch.
// Each thread handles ONE float4. Tensor a = first na4 float4-slots.
// ---------------------------------------------------------------------------
__global__ __launch_bounds__(256) void split2_w(
    const float* __restrict__ a, unsigned short* __restrict__ oa, int ksa,
    size_t na4,
    const float* __restrict__ b, unsigned short* __restrict__ ob, int ksb)
{
  size_t i4 = ((size_t)blockIdx.x << 8) + threadIdx.x;
  const float* src; unsigned short* dst; int ks;
  if (i4 < na4) { src = a; dst = oa; ks = ksa; }
  else          { src = b; dst = ob; ks = ksb; i4 -= na4; }
  const size_t flat = i4 << 2;
  const int K = 1 << ks;
  const size_t row = flat >> ks;
  const int k = (int)(flat & (size_t)(K - 1));
  float4 v = *(const float4*)(src + flat);
  float f[4] = {v.x, v.y, v.z, v.w};
  unsigned short h[4], lo[4];
#pragma unroll
  for (int c = 0; c < 4; ++c) { h[c] = f2bf(f[c]); lo[c] = f2bf(f[c] - bf2f(h[c])); }
  unsigned short* o = dst + (row << (ks + 1)) + k;
  *(uint2*)(o)     = make_uint2((unsigned)h[0]  | ((unsigned)h[1]  << 16),
                                (unsigned)h[2]  | ((unsigned)h[3]  << 16));
  *(uint2*)(o + K) = make_uint2((unsigned)lo[0] | ((unsigned)lo[1] << 16),
                                (unsigned)lo[2] | ((unsigned)lo[3] << 16));
}

// ---------------------------------------------------------------------------
// 256x256-tile phase-split split-bf16 MFMA GEMM: C[M,N] = A·B^T.
// T3+T4+T5 schedule (counted vmcnt, never drained in main loop; setprio
// around MFMA clusters; 1 barrier per phase). BK=32, 8 waves (2M x 4N),
// per-wave 128x64 output (8x4 frags). 4 phases per K-tile, one C-quadrant
// each: 24 MFMA + 12 ds_read_b128 (NPASS=3) between barriers.
// LDS: [2 dbuf][4 tensors AH,BH,AL,BL][256x32] = 128 KiB (NPASS=3).
// XOR chunk swizzle: stage slot c of row r holds global k-chunk c^((r>>1)&3);
// reader uses quad^((lm>>1)&3).
// XCD AFFINITY (r6, verified: FETCH 266->66MB): the 8 blocks sharing one
// A-panel (same bm) land on the SAME XCD:
// bm-tile = x*4 + (y>>3), bn-tile = y&7 (linear id % 8 == x = XCD).
// ---------------------------------------------------------------------------
template <int NPASS, int MH, int NH>
__device__ __forceinline__ void phase_mfma(
    const unsigned short* __restrict__ shc, f32x4 (&acc)[8][4],
    int wm, int wn, int lm, int roff)
{
  bf16x8 aH[4], bH[2], aL[4], bL[2];
#pragma unroll
  for (int ii = 0; ii < 4; ++ii) {
    const int ar = (wm + (MH * 4 + ii) * 16 + lm) * 32 + roff;
    aH[ii] = *(const bf16x8*)(shc + ar);
    if constexpr (NPASS > 1) aL[ii] = *(const bf16x8*)(shc + 2 * 8192 + ar);
  }
#pragma unroll
  for (int jj = 0; jj < 2; ++jj) {
    const int br = (wn + (NH * 2 + jj) * 16 + lm) * 32 + roff;
    bH[jj] = *(const bf16x8*)(shc + 8192 + br);
    if constexpr (NPASS > 1) bL[jj] = *(const bf16x8*)(shc + 3 * 8192 + br);
  }
  __builtin_amdgcn_s_setprio(1);
#pragma unroll
  for (int ii = 0; ii < 4; ++ii)
#pragma unroll
    for (int jj = 0; jj < 2; ++jj) {
      const int i = MH * 4 + ii, j = NH * 2 + jj;
      acc[i][j] = __builtin_amdgcn_mfma_f32_16x16x32_bf16(aH[ii], bH[jj], acc[i][j], 0, 0, 0);
      if constexpr (NPASS > 1) {
        acc[i][j] = __builtin_amdgcn_mfma_f32_16x16x32_bf16(aH[ii], bL[jj], acc[i][j], 0, 0, 0);
        acc[i][j] = __builtin_amdgcn_mfma_f32_16x16x32_bf16(aL[ii], bH[jj], acc[i][j], 0, 0, 0);
      }
    }
  __builtin_amdgcn_s_setprio(0);
}

template <int NPASS>
__global__ __launch_bounds__(512, 2) void gemm_8ph(
    const unsigned short* __restrict__ Ap, const unsigned short* __restrict__ Bp,
    float* __restrict__ C, int K, int ldc)
{
  constexpr int NTEN = (NPASS > 1) ? 4 : 2;      // AH,BH[,AL,BL]
  __shared__ unsigned short sh[2][NTEN][256 * 32];
  const int tid = threadIdx.x;
  // XCD affinity: all 8 bn-blocks of a bm-panel on one XCD (x = XCD id)
  const int bm = (((blockIdx.x << 2) | (blockIdx.y >> 3)) << 8);
  const int bn = ((blockIdx.y & 7) << 8);
  const int K2 = K * 2;
  const int wave = tid >> 6, lane = tid & 63;
  const int wm = (wave >> 2) << 7;               // 0 / 128
  const int wn = (wave & 3) << 6;                // 0 / 64 / 128 / 192
  const int lm = lane & 15, quad = lane >> 4;
  const int roff = ((quad ^ ((lm >> 1) & 3)) << 3);

  const int r0 = tid >> 2;
  const int kq = (((tid & 3) ^ ((r0 >> 1) & 3)) << 3);
  const unsigned short* a0 = Ap + (size_t)(bm + r0) * K2 + kq;        // rows 0-127
  const unsigned short* a1 = a0 + (size_t)128 * K2;                   // rows 128-255
  const unsigned short* b0 = Bp + (size_t)(bn + r0) * K2 + kq;
  const unsigned short* b1 = b0 + (size_t)128 * K2;
  const int ls0 = tid * 8, ls1 = 4096 + tid * 8; // ushort offsets in a tensor buf

  f32x4 acc[8][4] = {};
  const int NT = K >> 5;

  // prologue: stage tile 0 into buffer 0
  {
    unsigned short* s = &sh[0][0][0];
    gl2lds16(a0, s + ls0);
    gl2lds16(a1, s + ls1);
    if constexpr (NPASS > 1) {
      gl2lds16(a0 + K, s + 2 * 8192 + ls0);
      gl2lds16(a1 + K, s + 2 * 8192 + ls1);
    }
    gl2lds16(b0, s + 8192 + ls0);
    gl2lds16(b1, s + 8192 + ls1);
    if constexpr (NPASS > 1) {
      gl2lds16(b0 + K, s + 3 * 8192 + ls0);
      gl2lds16(b1 + K, s + 3 * 8192 + ls1);
    }
  }

  for (int t = 0; t < NT - 1; ++t) {
    const unsigned short* cur = &sh[t & 1][0][0];
    unsigned short* nxt = &sh[(t + 1) & 1][0][0];
    const int kn = (t + 1) << 5;

    // ---- phase 0: issue next-tile A units, publish current tile ----
    gl2lds16(a0 + kn, nxt + ls0);
    gl2lds16(a1 + kn, nxt + ls1);
    if constexpr (NPASS > 1) {
      gl2lds16(a0 + K + kn, nxt + 2 * 8192 + ls0);
      gl2lds16(a1 + K + kn, nxt + 2 * 8192 + ls1);
      asm volatile("s_waitcnt vmcnt(4)" ::: "memory");  // current tile's 8 landed
    } else {
      asm volatile("s_waitcnt vmcnt(2)" ::: "memory");  // current tile's 4 landed
    }
    BARRIER_();
    phase_mfma<NPASS, 0, 0>(cur, acc, wm, wn, lm, roff);
    BARRIER_();
    // ---- phase 1: issue next-tile B units ----
    gl2lds16(b0 + kn, nxt + 8192 + ls0);
    gl2lds16(b1 + kn, nxt + 8192 + ls1);
    if constexpr (NPASS > 1) {
      gl2lds16(b0 + K + kn, nxt + 3 * 8192 + ls0);
      gl2lds16(b1 + K + kn, nxt + 3 * 8192 + ls1);
    }
    phase_mfma<NPASS, 0, 1>(cur, acc, wm, wn, lm, roff);
    BARRIER_();
    // ---- phase 2 ----
    phase_mfma<NPASS, 1, 0>(cur, acc, wm, wn, lm, roff);
    BARRIER_();
    // ---- phase 3 (trailing barrier protects next tile's stage overwrite) ----
    phase_mfma<NPASS, 1, 1>(cur, acc, wm, wn, lm, roff);
    BARRIER_();
  }

  // peeled last tile: nothing left to issue -> drain is allowed here only
  {
    const unsigned short* cur = &sh[(NT - 1) & 1][0][0];
    asm volatile("s_waitcnt vmcnt(0)" ::: "memory");
    BARRIER_();
    phase_mfma<NPASS, 0, 0>(cur, acc, wm, wn, lm, roff);
    BARRIER_();
    phase_mfma<NPASS, 0, 1>(cur, acc, wm, wn, lm, roff);
    BARRIER_();
    phase_mfma<NPASS, 1, 0>(cur, acc, wm, wn, lm, roff);
    BARRIER_();
    phase_mfma<NPASS, 1, 1>(cur, acc, wm, wn, lm, roff);
  }

  // epilogue: C/D layout col=lane&15 (n), row=quad*4+reg (m)
#pragma unroll
  for (int i = 0; i < 8; ++i) {
    const int m = bm + wm + i * 16 + quad * 4;
#pragma unroll
    for (int j = 0; j < 4; ++j) {
      const int n = bn + wn + j * 16 + lm;
#pragma unroll
      for (int r = 0; r < 4; ++r)
        C[(size_t)(m + r) * ldc + n] = acc[i][j][r];
    }
  }
}

// ---------------------------------------------------------------------------
// Split-bf16 MFMA GEMM (m97-style 128x128) — gemm8 (structural floor 116µs).
// A_PACKED=1: A is u32 (lo<<16|hi) from scan_pass3; staging de-interleaves
// in-register (~32 bitfield VALU/thread/tile).
// XCD AFFINITY (r7-verified: FETCH 266->66MB): bm-tile = (bx<<3)|(by>>3),
// bn-tile = by&7 -> the 8 bn-blocks of each A-panel co-XCD.
// ---------------------------------------------------------------------------
template <int NPASS, int A_PACKED>
__global__ __launch_bounds__(256) void gemm_mfma(
    const void* __restrict__ Avp, const unsigned short* __restrict__ Bp,
    float* __restrict__ C, int K, int ldc)
{
  __shared__ unsigned short AsH[128 * 32];
  __shared__ unsigned short BsH[128 * 32];
  __shared__ unsigned short AsL[(NPASS > 1) ? 128 * 32 : 8];
  __shared__ unsigned short BsL[(NPASS > 1) ? 128 * 32 : 8];
  const int tid = threadIdx.x;
  // bm-panel-per-XCD affinity (x = XCD id under x-fastest linear dispatch)
  const int bm = (((blockIdx.x << 3) | (blockIdx.y >> 3)) << 7);
  const int bn = ((blockIdx.y & 7) << 7);
  const int K2 = K * 2;

  const int wave = tid >> 6, lane = tid & 63;
  const int wm = (wave >> 1) << 6, wn = (wave & 1) << 6;
  const int lm = lane & 15, quad = lane >> 4;
  const int sw = (lm >> 1) & 3;        // reader swizzle (row>>1)&3 == (lm>>1)&3

  f32x4 acc[4][4] = {};

  const int r0 = tid >> 2;
  const int kq = ((tid & 3) ^ ((r0 >> 1) & 3)) << 3;   // element offset
  const unsigned short* BgH0 = Bp + (size_t)(bn + r0) * K2 + kq;
  const unsigned short* BgH1 = Bp + (size_t)(bn + 64 + r0) * K2 + kq;
  unsigned short* lA0 = &AsH[(size_t)tid * 8];
  unsigned short* lA1 = &AsH[(size_t)(256 + tid) * 8];
  unsigned short* lB0 = &BsH[(size_t)tid * 8];
  unsigned short* lB1 = &BsH[(size_t)(256 + tid) * 8];
  unsigned short* lAl0 = (NPASS > 1) ? &AsL[(size_t)tid * 8] : nullptr;
  unsigned short* lAl1 = (NPASS > 1) ? &AsL[(size_t)(256 + tid) * 8] : nullptr;
  unsigned short* lBl0 = (NPASS > 1) ? &BsL[(size_t)tid * 8] : nullptr;
  unsigned short* lBl1 = (NPASS > 1) ? &BsL[(size_t)(256 + tid) * 8] : nullptr;

  const unsigned short* AgH0 = nullptr; const unsigned short* AgH1 = nullptr;
  const unsigned int* Apk0 = nullptr; const unsigned int* Apk1 = nullptr;
  if (A_PACKED) {
    const unsigned int* Au = (const unsigned int*)Avp;
    Apk0 = Au + (size_t)(bm + r0) * K + kq;
    Apk1 = Au + (size_t)(bm + 64 + r0) * K + kq;
  } else {
    const unsigned short* Ab = (const unsigned short*)Avp;
    AgH0 = Ab + (size_t)(bm + r0) * K2 + kq;
    AgH1 = Ab + (size_t)(bm + 64 + r0) * K2 + kq;
  }

  for (int k0 = 0; k0 < K; k0 += 32) {
    __syncthreads();
    if (A_PACKED) {
      uint4 u0 = *(const uint4*)(Apk0 + k0);
      uint4 u1 = *(const uint4*)(Apk0 + k0 + 4);
      uint4 v0 = *(const uint4*)(Apk1 + k0);
      uint4 v1 = *(const uint4*)(Apk1 + k0 + 4);
      unsigned p[8] = {u0.x, u0.y, u0.z, u0.w, u1.x, u1.y, u1.z, u1.w};
      unsigned q[8] = {v0.x, v0.y, v0.z, v0.w, v1.x, v1.y, v1.z, v1.w};
      unsigned hu[4], lu[4], hv[4], lv[4];
#pragma unroll
      for (int c = 0; c < 4; ++c) {
        hu[c] = (p[2*c] & 0xffffu) | (p[2*c+1] << 16);
        lu[c] = (p[2*c] >> 16)     | (p[2*c+1] & 0xffff0000u);
        hv[c] = (q[2*c] & 0xffffu) | (q[2*c+1] << 16);
        lv[c] = (q[2*c] >> 16)     | (q[2*c+1] & 0xffff0000u);
      }
      *(uint4*)lA0  = make_uint4(hu[0], hu[1], hu[2], hu[3]);
      *(uint4*)lA1  = make_uint4(hv[0], hv[1], hv[2], hv[3]);
      if (NPASS > 1) {
        *(uint4*)lAl0 = make_uint4(lu[0], lu[1], lu[2], lu[3]);
        *(uint4*)lAl1 = make_uint4(lv[0], lv[1], lv[2], lv[3]);
      }
    } else {
      gl2lds16(AgH0 + k0, lA0);
      gl2lds16(AgH1 + k0, lA1);
      if (NPASS > 1) {
        gl2lds16(AgH0 + K + k0, lAl0);
        gl2lds16(AgH1 + K + k0, lAl1);
      }
    }
    gl2lds16(BgH0 + k0, lB0);
    gl2lds16(BgH1 + k0, lB1);
    if (NPASS > 1) {
      gl2lds16(BgH0 + K + k0, lBl0);
      gl2lds16(BgH1 + K + k0, lBl1);
    }
    __syncthreads();

    bf16x8 aH[4], bH[4];
#pragma unroll
    for (int i = 0; i < 4; ++i)
      aH[i] = *(const bf16x8*)&AsH[(wm + i * 16 + lm) * 32 + ((quad ^ sw) << 3)];
#pragma unroll
    for (int j = 0; j < 4; ++j)
      bH[j] = *(const bf16x8*)&BsH[(wn + j * 16 + lm) * 32 + ((quad ^ sw) << 3)];
#pragma unroll
    for (int i = 0; i < 4; ++i)
#pragma unroll
      for (int j = 0; j < 4; ++j)
        acc[i][j] = __builtin_amdgcn_mfma_f32_16x16x32_bf16(aH[i], bH[j], acc[i][j], 0, 0, 0);
    if (NPASS > 1) {
      bf16x8 aL[4], bL[4];
#pragma unroll
      for (int i = 0; i < 4; ++i)
        aL[i] = *(const bf16x8*)&AsL[(wm + i * 16 + lm) * 32 + ((quad ^ sw) << 3)];
#pragma unroll
      for (int j = 0; j < 4; ++j)
        bL[j] = *(const bf16x8*)&BsL[(wn + j * 16 + lm) * 32 + ((quad ^ sw) << 3)];
#pragma unroll
      for (int i = 0; i < 4; ++i)
#pragma unroll
        for (int j = 0; j < 4; ++j) {
          acc[i][j] = __builtin_amdgcn_mfma_f32_16x16x32_bf16(aH[i], bL[j], acc[i][j], 0, 0, 0);
          acc[i][j] = __builtin_amdgcn_mfma_f32_16x16x32_bf16(aL[i], bH[j], acc[i][j], 0, 0, 0);
        }
    }
  }

  // epilogue: C/D layout col=lane&15 (n, from B), row=quad*4+reg (m, from A)
#pragma unroll
  for (int i = 0; i < 4; ++i) {
    const int m = bm + wm + i * 16 + quad * 4;
#pragma unroll
    for (int j = 0; j < 4; ++j) {
      const int n = bn + wn + j * 16 + lm;
#pragma unroll
      for (int r = 0; r < 4; ++r)
        C[(size_t)(m + r) * ldc + n] = acc[i][j][r];
    }
  }
}

// ---------------------------------------------------------------------------
// fp32 NT GEMM (small shapes): C[M,N] = A[M,K]·B[N,K]^T. 64x64 tile, BK=16.
// EPI: 0 none, 1 softplus(acc + bias[n]). Split-K via blockIdx.z.
// NB2=1 (r8): one block column computes TWO n-tiles (n in [0,128), bounds-
// checked) from a single staged A-tile -> halves A traffic for N=96 shapes
// (x_dbl GEMM previously read U twice: 134MB for 3.2 GFLOP).
// ---------------------------------------------------------------------------
template <int EPI, int NB2>
__global__ __launch_bounds__(256) void gemm_nt(
    const float* __restrict__ A, int lda,
    const float* __restrict__ B, int ldb,
    float* __restrict__ C, int ldc,
    int N, int K, const float* __restrict__ bias, size_t cseg)
{
  constexpr int NBT = NB2 ? 2 : 1;
  __shared__ float As[16][68];
  __shared__ float Bs[NBT][16][68];
  const int tid = threadIdx.x;
  const int bm = blockIdx.y << 6;
  const int bn = blockIdx.x << 6;
  const int kz = blockIdx.z;
  A += (size_t)kz * K;
  B += (size_t)kz * K;
  C += (size_t)kz * cseg;
  const int lr = tid >> 2;
  const int lk = (tid & 3) << 2;
  const int tx = tid & 15, ty = tid >> 4;

  float acc[NBT][4][4];
#pragma unroll
  for (int nb = 0; nb < NBT; ++nb)
#pragma unroll
    for (int i = 0; i < 4; ++i)
#pragma unroll
      for (int j = 0; j < 4; ++j) acc[nb][i][j] = 0.f;

  const float* Apt  = A + (size_t)(bm + lr) * lda + lk;
  const float* Bpt0 = B + (size_t)(bn + lr) * ldb + lk;
  const float* Bpt1 = NB2 ? (B + (size_t)(bn + 64 + lr) * ldb + lk) : nullptr;
  const bool bv0 = (bn + lr) < N;
  const bool bv1 = NB2 ? ((bn + 64 + lr) < N) : false;

  for (int k0 = 0; k0 < K; k0 += 16) {
    float4 a4 = *(const float4*)(Apt + k0);
    float4 b40 = bv0 ? *(const float4*)(Bpt0 + k0) : make_float4(0.f, 0.f, 0.f, 0.f);
    float4 b41 = (NB2 && bv1) ? *(const float4*)(Bpt1 + k0) : make_float4(0.f, 0.f, 0.f, 0.f);
    __syncthreads();
    As[lk + 0][lr] = a4.x; As[lk + 1][lr] = a4.y;
    As[lk + 2][lr] = a4.z; As[lk + 3][lr] = a4.w;
    Bs[0][lk + 0][lr] = b40.x; Bs[0][lk + 1][lr] = b40.y;
    Bs[0][lk + 2][lr] = b40.z; Bs[0][lk + 3][lr] = b40.w;
    if (NB2) {
      Bs[1][lk + 0][lr] = b41.x; Bs[1][lk + 1][lr] = b41.y;
      Bs[1][lk + 2][lr] = b41.z; Bs[1][lk + 3][lr] = b41.w;
    }
    __syncthreads();
#pragma unroll
    for (int k = 0; k < 16; ++k) {
      const float4 av = *(const float4*)(&As[k][ty << 2]);
      float a4r[4] = {av.x, av.y, av.z, av.w};
#pragma unroll
      for (int nb = 0; nb < NBT; ++nb) {
        const float4 bw = *(const float4*)(&Bs[nb][k][tx << 2]);
        float b4r[4] = {bw.x, bw.y, bw.z, bw.w};
#pragma unroll
        for (int i = 0; i < 4; ++i)
#pragma unroll
          for (int j = 0; j < 4; ++j)
            acc[nb][i][j] = fmaf(a4r[i], b4r[j], acc[nb][i][j]);
      }
    }
  }

  const int m = bm + (ty << 2);
#pragma unroll
  for (int nb = 0; nb < NBT; ++nb) {
    const int n = bn + nb * 64 + (tx << 2);
#pragma unroll
    for (int i = 0; i < 4; ++i) {
      float v[4] = {acc[nb][i][0], acc[nb][i][1], acc[nb][i][2], acc[nb][i][3]};
      if (EPI == 1) {
#pragma unroll
        for (int j = 0; j < 4; ++j)
          if (n + j < N) v[j] = softplus_(v[j] + bias[n + j]);
      }
      if (n + 3 < N) {
        *(float4*)(C + (size_t)(m + i) * ldc + n) = make_float4(v[0], v[1], v[2], v[3]);
      } else {
#pragma unroll
        for (int j = 0; j < 4; ++j)
          if (n + j < N) C[(size_t)(m + i) * ldc + n + j] = v[j];
      }
    }
  }
}

// ---------------------------------------------------------------------------
// 4-way split-K reduce: O[i] = sum_z P[z*seg + i], over n4 float4s.
// ---------------------------------------------------------------------------
__global__ __launch_bounds__(256) void reduce4(
    const float* __restrict__ P, float* __restrict__ O, size_t seg)
{
  const size_t i = ((size_t)blockIdx.x << 8) + threadIdx.x;
  float4 a = ((const float4*)P)[i];
  float4 b = ((const float4*)(P + seg))[i];
  float4 c = ((const float4*)(P + 2 * seg))[i];
  float4 d = ((const float4*)(P + 3 * seg))[i];
  ((float4*)O)[i] = make_float4(a.x + b.x + c.x + d.x,
                                a.y + b.y + c.y + d.y,
                                a.z + b.z + c.z + d.z,
                                a.w + b.w + c.w + d.w);
}

// ---------------------------------------------------------------------------
// Channel alignment features (rfft2 16x16 magnitude band ratio). X stride 2048.
// ---------------------------------------------------------------------------
__global__ __launch_bounds__(256) void feat_kernel(
    const float* __restrict__ X, float* __restrict__ features)
{
  __shared__ float xin[256][17];
  __shared__ float Rf[16 * 315];
  __shared__ float tc[16], ts[16];
  __shared__ float part2[16][16][2];

  const int tid = threadIdx.x;
  const int frame = blockIdx.x >> 7;
  const int cg = blockIdx.x & 127;
  const int b = frame >> 3, t = frame & 7;
  const int c0 = cg << 4;

  if (tid < 16) {
    float ang = 0.39269908169872414f * (float)tid;
    tc[tid] = cosf(ang);
    ts[tid] = sinf(ang);
  }
  const float* xb = X + ((size_t)(b * LSEQ + t * 256) << 11) + c0;
  for (int i = tid; i < 256 * 16; i += 256) {
    int hw = i >> 4, ci = i & 15;
    xin[hw][ci] = xb[((size_t)hw << 11) + ci];
  }
  __syncthreads();

  {
    const int ci = tid & 15, h = tid >> 4;
    float re[9], im[9];
#pragma unroll
    for (int kw = 0; kw < 9; ++kw) { re[kw] = 0.f; im[kw] = 0.f; }
#pragma unroll
    for (int w = 0; w < 16; ++w) {
      float x = xin[(h << 4) + w][ci];
#pragma unroll
      for (int kw = 0; kw < 9; ++kw) {
        int ph = (kw * w) & 15;
        re[kw] = fmaf(x, tc[ph], re[kw]);
        im[kw] = fmaf(-x, ts[ph], im[kw]);
      }
    }
#pragma unroll
    for (int kw = 0; kw < 9; ++kw) {
      Rf[ci * 315 + kw * 35 + 2 * h]     = re[kw];
      Rf[ci * 315 + kw * 35 + 2 * h + 1] = im[kw];
    }
  }
  __syncthreads();

  {
    const int ci = tid & 15, kh = tid >> 4;
    float ut = 0.f, tt = 0.f;
    for (int kw = 0; kw < 9; ++kw) {
      float fre = 0.f, fim = 0.f;
#pragma unroll
      for (int h = 0; h < 16; ++h) {
        int ph = (kh * h) & 15;
        float c = tc[ph], s = ts[ph];
        float rr = Rf[ci * 315 + kw * 35 + 2 * h];
        float ri = Rf[ci * 315 + kw * 35 + 2 * h + 1];
        fre += rr * c + ri * s;
        fim += ri * c - rr * s;
      }
      float mag = sqrtf(fre * fre + fim * fim + 1e-8f);
      int sh = (kh + 8) & 15;
      int sw2 = kw + 4; if (sw2 >= 9) sw2 -= 9;
      float dh = (float)(sh - 8) / 16.0f;
      float dw = (float)(sw2 - 4) / 9.0f;
      tt += mag;
      if (dh * dh + dw * dw >= 0.25f) ut += mag;
    }
    part2[ci][kh][0] = ut;
    part2[ci][kh][1] = tt;
  }
  __syncthreads();

  if (tid < 16) {
    float ut = 0.f, tt = 0.f;
    for (int kh = 0; kh < 16; ++kh) { ut += part2[tid][kh][0]; tt += part2[tid][kh][1]; }
    features[frame * DI + c0 + tid] = ut / (tt + 1e-8f);
  }
}

// ---------------------------------------------------------------------------
// loss + norms + softmax(mean feat) + attention + A_max/A_min + A out. 1 block.
// Aws is pre-scaled by log2(e): scan kernels use native exp2.
// ---------------------------------------------------------------------------
__global__ __launch_bounds__(256) void alpha_kernel(
    const float* __restrict__ feats, const float* __restrict__ A_log,
    float* __restrict__ Aws, float* __restrict__ loss_out)
{
  __shared__ float red[256];
  __shared__ float invn[32];
  __shared__ float PT[32][257];
  __shared__ float AM[256][17];
  __shared__ float sAmax[16], sAmin[16];
  const int tid = threadIdx.x;

  float pn[32];
#pragma unroll
  for (int i = 0; i < 32; ++i) pn[i] = 0.f;
  float md[8];
#pragma unroll
  for (int j = 0; j < 8; ++j) md[j] = 0.f;
  for (int i = 0; i < 32; ++i) {
#pragma unroll
    for (int j = 0; j < 8; ++j) {
      float v = feats[(i << 11) + tid + (j << 8)];
      pn[i] = fmaf(v, v, pn[i]);
      md[j] += v;
    }
  }
#pragma unroll
  for (int j = 0; j < 8; ++j) md[j] *= (1.f / 32.f);
#pragma unroll
  for (int i = 0; i < 32; ++i) PT[i][tid] = pn[i];
  __syncthreads();
  if (tid < 32) {
    float s = 0.f;
    for (int k = 0; k < 256; ++k) s += PT[tid][k];
    invn[tid] = 1.f / fmaxf(sqrtf(s), 1e-12f);
  }
  __syncthreads();

  float gsq = 0.f;
#pragma unroll
  for (int j = 0; j < 8; ++j) {
    float gd = 0.f;
    for (int i = 0; i < 32; ++i)
      gd = fmaf(feats[(i << 11) + tid + (j << 8)], invn[i], gd);
    gsq = fmaf(gd, gd, gsq);
  }
  red[tid] = gsq; __syncthreads();
  for (int s = 128; s > 0; s >>= 1) { if (tid < s) red[tid] += red[tid + s]; __syncthreads(); }
  if (tid == 0) loss_out[0] = 1.f - red[0] * (1.f / 1024.f);
  __syncthreads();

  float lm = md[0];
#pragma unroll
  for (int j = 1; j < 8; ++j) lm = fmaxf(lm, md[j]);
  red[tid] = lm; __syncthreads();
  for (int s = 128; s > 0; s >>= 1) { if (tid < s) red[tid] = fmaxf(red[tid], red[tid + s]); __syncthreads(); }
  const float mmax = red[0]; __syncthreads();

  float p[8]; float ps = 0.f;
#pragma unroll
  for (int j = 0; j < 8; ++j) { p[j] = __expf(md[j] - mmax); ps += p[j]; }
  red[tid] = ps; __syncthreads();
  for (int s = 128; s > 0; s >>= 1) { if (tid < s) red[tid] += red[tid + s]; __syncthreads(); }
  const float psum = red[0]; __syncthreads();

  float amaxl[16], aminl[16], rn[8];
#pragma unroll
  for (int n = 0; n < 16; ++n) { amaxl[n] = -1e30f; aminl[n] = 1e30f; }
#pragma unroll
  for (int j = 0; j < 8; ++j) {
    const int d = tid + (j << 8);
    float ss = 0.f;
#pragma unroll
    for (int n = 0; n < 16; ++n) {
      float a = A_log[(d << 4) + n];
      float e = __expf(a);
      ss = fmaf(e, e, ss);
      amaxl[n] = fmaxf(amaxl[n], a);
      aminl[n] = fminf(aminl[n], a);
    }
    rn[j] = sqrtf(ss);
  }
  float rm = rn[0];
#pragma unroll
  for (int j = 1; j < 8; ++j) rm = fmaxf(rm, rn[j]);
  red[tid] = rm; __syncthreads();
  for (int s = 128; s > 0; s >>= 1) { if (tid < s) red[tid] = fmaxf(red[tid], red[tid + s]); __syncthreads(); }
  const float rnmax = red[0]; __syncthreads();

#pragma unroll
  for (int n = 0; n < 16; ++n) AM[tid][n] = amaxl[n];
  __syncthreads();
  if (tid < 16) { float m = -1e30f; for (int i = 0; i < 256; ++i) m = fmaxf(m, AM[i][tid]); sAmax[tid] = m; }
  __syncthreads();
#pragma unroll
  for (int n = 0; n < 16; ++n) AM[tid][n] = aminl[n];
  __syncthreads();
  if (tid < 16) { float m = 1e30f; for (int i = 0; i < 256; ++i) m = fminf(m, AM[i][tid]); sAmin[tid] = m; }
  __syncthreads();

  const float irn = 1.f / (rnmax + 1e-8f);
#pragma unroll
  for (int j = 0; j < 8; ++j) {
    const int d = tid + (j << 8);
    const float att = rn[j] * irn;
    const float f = p[j] / psum;
    const float alpha = fminf(fmaxf(f * (1.f - att), 0.f), 1.f);
#pragma unroll
    for (int n = 0; n < 16; ++n) {
      float a = A_log[(d << 4) + n];
      float fl = sAmax[n] + sAmin[n] - a;
      float an = (1.f - alpha) * a + alpha * fl;
      // pre-fold log2(e) so scan kernels can use native v_exp_f32 (exp2)
      Aws[(d << 4) + n] = -__expf(an) * 1.4426950408889634f;
    }
  }
}

// ---------------------------------------------------------------------------
// Depthwise causal conv (k=4) + bias + SiLU, float4 per thread.
// X (b,l,2048) -> U (b,l,2048)
// ---------------------------------------------------------------------------
__global__ __launch_bounds__(256) void conv_kernel(
    const float* __restrict__ X, const float* __restrict__ cw,
    const float* __restrict__ cb, float* __restrict__ U)
{
  const size_t i4 = ((size_t)blockIdx.x << 8) + threadIdx.x;  // < 4,194,304
  const int e4 = (int)(i4 & 511);
  const size_t row = i4 >> 9;          // b*2048 + l
  const int l = (int)(row & 2047);
  const float* xr = X + (row << 11) + (e4 << 2);
  const float4 z4 = make_float4(0.f, 0.f, 0.f, 0.f);
  float4 x0 = *(const float4*)xr;
  float4 x1 = (l >= 1) ? *(const float4*)(xr - 2048) : z4;
  float4 x2 = (l >= 2) ? *(const float4*)(xr - 4096) : z4;
  float4 x3 = (l >= 3) ? *(const float4*)(xr - 6144) : z4;
  const float4* cwf = (const float4*)cw;
  float4 bi = *(const float4*)(cb + (e4 << 2));
  float x0a[4] = {x0.x, x0.y, x0.z, x0.w};
  float x1a[4] = {x1.x, x1.y, x1.z, x1.w};
  float x2a[4] = {x2.x, x2.y, x2.z, x2.w};
  float x3a[4] = {x3.x, x3.y, x3.z, x3.w};
  float bia[4] = {bi.x, bi.y, bi.z, bi.w};
  float o[4];
#pragma unroll
  for (int c = 0; c < 4; ++c) {
    float4 w = cwf[(e4 << 2) + c];
    float acc = bia[c];
    acc = fmaf(x3a[c], w.x, acc);
    acc = fmaf(x2a[c], w.y, acc);
    acc = fmaf(x1a[c], w.z, acc);
    acc = fmaf(x0a[c], w.w, acc);
    o[c] = silu_(acc);
  }
  *(float4*)(U + (i4 << 2)) = make_float4(o[0], o[1], o[2], o[3]);
}

// ---------------------------------------------------------------------------
// Chunked selective scan (delta in X region stride 2048, z in Z stride 2048).
// Aws carries log2(e) factor -> exp2 (single v_exp_f32, no mul).
// ---------------------------------------------------------------------------
__global__ __launch_bounds__(256) void scan_pass1(
    const float* __restrict__ delta, const float* __restrict__ U,
    const float* __restrict__ xdbl, const float* __restrict__ Aws,
    float* __restrict__ cs, float* __restrict__ sdt)
{
  __shared__ float blds[CL * 16];
  const int tid = threadIdx.x;
  const int dg = blockIdx.x & 7;
  const int chunk = (blockIdx.x >> 3) & 31;
  const int b = blockIdx.x >> 8;
  const int d = (dg << 8) | tid;
  const int l0 = chunk * CL;

  for (int i = tid; i < CL * 16; i += 256) {
    int l = i >> 4, j = i & 15;
    blds[i] = xdbl[(size_t)(b * LSEQ + l0 + l) * 96 + 64 + j];
  }
  __syncthreads();

  float Ar[16];
#pragma unroll
  for (int n = 0; n < 16; ++n) Ar[n] = Aws[(d << 4) + n];
  float s[16];
#pragma unroll
  for (int n = 0; n < 16; ++n) s[n] = 0.f;
  float sumdt = 0.f;

  const float* dp = delta + ((size_t)b << 22) + ((size_t)l0 << 11) + d;
  const float* up = U + ((size_t)b << 22) + ((size_t)l0 << 11) + d;

  for (int l = 0; l < CL; ++l) {
    const float dt = dp[(size_t)l << 11];
    const float u = up[(size_t)l << 11];
    sumdt += dt;
    const float du = dt * u;
    const float* bl = &blds[l << 4];
#pragma unroll
    for (int n = 0; n < 16; ++n)
      s[n] = fmaf(s[n], __builtin_amdgcn_exp2f(dt * Ar[n]), du * bl[n]);
  }

  float* csp = cs + ((((size_t)b * NC + chunk) * 2048 + d) << 4);
#pragma unroll
  for (int n = 0; n < 4; ++n)
    *(float4*)(csp + (n << 2)) = make_float4(s[4*n], s[4*n+1], s[4*n+2], s[4*n+3]);
  sdt[((size_t)b * NC + chunk) * 2048 + d] = sumdt;
}

// r8: one thread per (b, d, n) — 16x the parallelism of the old (b,d) map
// (old: 32 blocks = 12.5% of CUs). State update is independent across n;
// same arithmetic order per (b,d,n) slot -> bit-identical.
// Wave's 64 lanes = 4 d x 16 n = 1KB contiguous cs access; sdt broadcast.
__global__ __launch_bounds__(256) void scan_mid(
    float* __restrict__ cs, const float* __restrict__ sdt,
    const float* __restrict__ Aws)
{
  const int gid = (blockIdx.x << 8) + threadIdx.x;   // < 131072
  const int n = gid & 15;
  const int d = (gid >> 4) & 2047;
  const int b = gid >> 15;
  const float Ar = Aws[(d << 4) + n];
  float si = 0.f;

  for (int c = 0; c < NC; ++c) {
    const size_t base = ((size_t)b * NC + c) * 2048 + d;
    float* p = cs + (base << 4) + n;
    const float sl = *p;
    const float sm = sdt[base];
    *p = si;
    si = fmaf(si, __builtin_amdgcn_exp2f(sm * Ar), sl);
  }
}

// scan_pass3 writes y as PACKED u32 (lo_bf16<<16 | hi_bf16) into the same U
// slot it reads u from (same thread, read-then-write, no cross-block hazard).
// gemm_mfma<3,1> (A_PACKED) consumes this directly -> no fp32 split in GEMM.
__global__ __launch_bounds__(256) void scan_pass3(
    const float* __restrict__ delta, const float* __restrict__ Z,
    float* __restrict__ U,
    const float* __restrict__ xdbl, const float* __restrict__ Aws,
    const float* __restrict__ Dp, const float* __restrict__ cs)
{
  __shared__ float bclds[CL * 32];
  const int tid = threadIdx.x;
  const int dg = blockIdx.x & 7;
  const int chunk = (blockIdx.x >> 3) & 31;
  const int b = blockIdx.x >> 8;
  const int d = (dg << 8) | tid;
  const int l0 = chunk * CL;

  for (int i = tid; i < CL * 32; i += 256) {
    int l = i >> 5, j = i & 31;
    bclds[i] = xdbl[(size_t)(b * LSEQ + l0 + l) * 96 + 64 + j];
  }
  __syncthreads();

  float Ar[16];
#pragma unroll
  for (int n = 0; n < 16; ++n) Ar[n] = Aws[(d << 4) + n];
  const float Dd = Dp[d];

  const float* csp = cs + ((((size_t)b * NC + chunk) * 2048 + d) << 4);
  float s[16];
#pragma unroll
  for (int n = 0; n < 4; ++n) {
    float4 v = *(const float4*)(csp + (n << 2));
    s[4*n] = v.x; s[4*n+1] = v.y; s[4*n+2] = v.z; s[4*n+3] = v.w;
  }

  const float* dp = delta + ((size_t)b << 22) + ((size_t)l0 << 11) + d;
  const float* zp = Z + ((size_t)b << 22) + ((size_t)l0 << 11) + d;
  float* up = U + ((size_t)b << 22) + ((size_t)l0 << 11) + d;

  for (int l = 0; l < CL; ++l) {
    const float dt = dp[(size_t)l << 11];
    const float u = up[(size_t)l << 11];
    const float z = zp[(size_t)l << 11];
    const float du = dt * u;
    const float* bcl = &bclds[l << 5];
    float y = 0.f;
#pragma unroll
    for (int n = 0; n < 16; ++n) {
      s[n] = fmaf(s[n], __builtin_amdgcn_exp2f(dt * Ar[n]), du * bcl[n]);
      y = fmaf(s[n], bcl[16 + n], y);
    }
    const float yv = fmaf(u, Dd, y);
    const float yo = yv * silu_(z);
    const unsigned short h = f2bf(yo);
    const unsigned short lo = f2bf(yo - bf2f(h));
    ((unsigned int*)up)[(size_t)l << 11] = (unsigned)h | ((unsigned)lo << 16);
  }
}

// ---------------------------------------------------------------------------
extern "C" void kernel_launch(void* const* d_in, const int* in_sizes, int n_in,
                              void* d_out, int out_size, void* d_ws, size_t ws_size,
                              hipStream_t stream)
{
  const float* hs         = (const float*)d_in[0];
  const float* in_proj_w  = (const float*)d_in[4];
  const float* conv_w     = (const float*)d_in[5];
  const float* conv_b     = (const float*)d_in[6];
  const float* x_proj_w   = (const float*)d_in[7];
  const float* dt_proj_w  = (const float*)d_in[8];
  const float* dt_proj_b  = (const float*)d_in[9];
  const float* A_log      = (const float*)d_in[10];
  const float* Dp         = (const float*)d_in[11];
  const float* out_proj_w = (const float*)d_in[12];
  float* out = (float*)d_out;
  float* ws = (float*)d_ws;

  float* X     = ws + OFF_X;
  float* Z     = ws + OFF_Z;
  float* U     = ws + OFF_U;
  float* cs    = ws + OFF_CS;
  float* sdt   = ws + OFF_SDT;
  float* xdbl  = ws + OFF_XDBL;
  float* feats = ws + OFF_FEAT;
  float* Aws   = ws + OFF_AWS;
  unsigned short* A1s = (unsigned short*)(ws + OFF_S);
  unsigned short* B1s = (unsigned short*)(ws + OFF_B1);
  unsigned short* B2s = (unsigned short*)(ws + OFF_B1);

  const dim3 blk(256);

  // 0. split hs (2,097,152 float4s) + in_proj_w (1,048,576 float4s)
  split2_w<<<12288, blk, 0, stream>>>(hs, A1s, 10, (size_t)2097152,
                                      in_proj_w, B1s, 10);
  // 1a. X half: hs @ in_proj_w[0:2048]^T, full 3-pass (M=8192,N=2048,K=1024)
  //     256^2-tile phase-split; bm-panel per XCD (A fetched once per XCD).
  gemm_8ph<3><<<dim3(8, 32), dim3(512), 0, stream>>>(A1s, B1s, X, 1024, 2048);
  // 1b. Z half: hs @ in_proj_w[2048:4096]^T, hi*hi only (silu-gate budget)
  gemm_8ph<1><<<dim3(8, 32), dim3(512), 0, stream>>>(A1s, B1s + (size_t)2048 * 2048, Z, 1024, 2048);
  // 2. channel-alignment features (reads X)
  feat_kernel<<<4096, blk, 0, stream>>>(X, feats);
  // 3. depthwise conv + silu (X -> U)
  conv_kernel<<<16384, blk, 0, stream>>>(X, conv_w, conv_b, U);
  // 3b. split out_proj_w (524,288 float4s) -> 2048 blocks (overlays dead B1s)
  split2_w<<<2048, blk, 0, stream>>>(out_proj_w, B2s, 11, (size_t)524288,
                                     out_proj_w, B2s, 11);
  // 4. loss + norms + alpha + A
  alpha_kernel<<<1, blk, 0, stream>>>(feats, A_log, Aws, out + 8388608);
  // 5. x_dbl = U @ x_proj_w^T (M=8192,N=96,K=2048) — split-K=4, dual-n-tile
  //    (NB2: one staged A-tile serves both n-tiles -> A traffic halved)
  gemm_nt<0, 1><<<dim3(1, 128, 4), blk, 0, stream>>>(U, DI, x_proj_w, DI, cs, 96, 96, 512, nullptr, (size_t)786432);
  reduce4<<<768, blk, 0, stream>>>(cs, xdbl, (size_t)786432);
  // 6. delta = softplus(x_dbl[:, :64] @ dt_proj_w^T + b) -> X region (dead x)
  gemm_nt<1, 0><<<dim3(32, 128, 1), blk, 0, stream>>>(xdbl, 96, dt_proj_w, 64, X, DI, DI, 64, dt_proj_b, 0);
  // 7. chunked selective scan; y overwrites U as packed bf16 hi/lo u32
  scan_pass1<<<1024, blk, 0, stream>>>(X, U, xdbl, Aws, cs, sdt);
  scan_mid<<<512, blk, 0, stream>>>(cs, sdt, Aws);   // r8: (b,d,n) threads
  scan_pass3<<<1024, blk, 0, stream>>>(X, Z, U, xdbl, Aws, Dp, cs);
  // 8. out = y @ out_proj_w^T — proven 128x128 kernel, packed A,
  //    bm-panel-per-XCD affinity (FETCH 266->66MB verified r7).
  gemm_mfma<3, 1><<<dim3(8, 64), blk, 0, stream>>>(U, B2s, out, 2048, 1024);
}

// Round 9
// 782.552 us; speedup vs baseline: 1.1437x; 1.0704x over previous
//
#include <hip/hip_runtime.h>
#include <math.h>
#include <stdint.h>

// Problem constants (fixed instance)
#define LSEQ 2048
#define DM   1024
#define DI   2048
#define NC   32     // scan chunks per sequence
#define CL   64     // scan chunk length (NC*CL == LSEQ)

// ---------------------------------------------------------------------------
// Workspace layout (float units). Total 62,914,560 floats = 251.7 MB.
//  X  [0,          16777216)  : x half of in_proj output; later delta (in place)
//  Z  [16777216,   33554432)  : z half
//  U  [33554432,   50331648)  : conv output u; scan_pass3 overwrites each slot
//                               with packed u32 (lo_bf16<<16 | hi_bf16) of y
//  S  [50331648,   58720256)  : A1' (hs split bf16) until gemm1 done, then
//                               cs(+xdbl split-K partials)/sdt/xdbl/feats/Aws/alp
//  B1 [58720256,   62914560)  : B1' (in_proj split) -> B2' (out_proj split)
// ---------------------------------------------------------------------------
#define OFF_X     ((size_t)0)
#define OFF_Z     ((size_t)16777216)
#define OFF_U     ((size_t)33554432)
#define OFF_S     ((size_t)50331648)
#define OFF_CS    (OFF_S)                      // 4,194,304 floats (also xdbl partials)
#define OFF_SDT   (OFF_S + 4194304)            //   262,144
#define OFF_XDBL  (OFF_S + 4456448)            //   786,432
#define OFF_FEAT  (OFF_S + 5242880)            //    65,536
#define OFF_AWS   (OFF_S + 5308448)            //    32,768
#define OFF_ALP   (OFF_S + 5341216)            //  md[2048] + pnp[256] + gsqp[8]

#define OFF_B1    ((size_t)58720256)

__device__ __forceinline__ float silu_(float x) { return x / (1.f + __expf(-x)); }
__device__ __forceinline__ float softplus_(float x) {
  return fmaxf(x, 0.f) + log1pf(__expf(-fabsf(x)));
}
__device__ __forceinline__ unsigned short f2bf(float x) {
  unsigned int u = __float_as_uint(x);
  u += 0x7fffu + ((u >> 16) & 1u);      // RNE (inputs finite)
  return (unsigned short)(u >> 16);
}
__device__ __forceinline__ float bf2f(unsigned short h) {
  return __uint_as_float(((unsigned int)h) << 16);
}

typedef __attribute__((ext_vector_type(8))) short bf16x8;
typedef __attribute__((ext_vector_type(4))) float f32x4;

__device__ __forceinline__ void gl2lds16(const void* g, void* l) {
  __builtin_amdgcn_global_load_lds(
      (const __attribute__((address_space(1))) unsigned int*)(uintptr_t)g,
      (__attribute__((address_space(3))) unsigned int*)(uintptr_t)l,
      16, 0, 0);
}

// barrier that is also a compiler memory fence (NOT __syncthreads: that drains
// vmcnt(0) and kills the staged-load pipeline)
#define BARRIER_()                                   \
  do {                                               \
    asm volatile("" ::: "memory");                   \
    __builtin_amdgcn_s_barrier();                    \
    asm volatile("" ::: "memory");                   \
  } while (0)

// ---------------------------------------------------------------------------
// Split fp32 -> [hi | lo] bf16 per row, two tensors in one dispatch.
// Each thread handles ONE float4. Tensor a = first na4 float4-slots.
// ---------------------------------------------------------------------------
__global__ __launch_bounds__(256) void split2_w(
    const float* __restrict__ a, unsigned short* __restrict__ oa, int ksa,
    size_t na4,
    const float* __restrict__ b, unsigned short* __restrict__ ob, int ksb)
{
  size_t i4 = ((size_t)blockIdx.x << 8) + threadIdx.x;
  const float* src; unsigned short* dst; int ks;
  if (i4 < na4) { src = a; dst = oa; ks = ksa; }
  else          { src = b; dst = ob; ks = ksb; i4 -= na4; }
  const size_t flat = i4 << 2;
  const int K = 1 << ks;
  const size_t row = flat >> ks;
  const int k = (int)(flat & (size_t)(K - 1));
  float4 v = *(const float4*)(src + flat);
  float f[4] = {v.x, v.y, v.z, v.w};
  unsigned short h[4], lo[4];
#pragma unroll
  for (int c = 0; c < 4; ++c) { h[c] = f2bf(f[c]); lo[c] = f2bf(f[c] - bf2f(h[c])); }
  unsigned short* o = dst + (row << (ks + 1)) + k;
  *(uint2*)(o)     = make_uint2((unsigned)h[0]  | ((unsigned)h[1]  << 16),
                                (unsigned)h[2]  | ((unsigned)h[3]  << 16));
  *(uint2*)(o + K) = make_uint2((unsigned)lo[0] | ((unsigned)lo[1] << 16),
                                (unsigned)lo[2] | ((unsigned)lo[3] << 16));
}

// ---------------------------------------------------------------------------
// 256x256-tile phase-split split-bf16 MFMA GEMM: C[M,N] = A·B^T.
// T3+T4+T5 schedule (counted vmcnt, never drained in main loop; setprio
// around MFMA clusters; 1 barrier per phase). BK=32, 8 waves (2M x 4N),
// per-wave 128x64 output (8x4 frags). 4 phases per K-tile, one C-quadrant
// each: 24 MFMA + 12 ds_read_b128 (NPASS=3) between barriers.
// LDS: [2 dbuf][4 tensors AH,BH,AL,BL][256x32] = 128 KiB (NPASS=3).
// XOR chunk swizzle: stage slot c of row r holds global k-chunk c^((r>>1)&3);
// reader uses quad^((lm>>1)&3).
// XCD AFFINITY (r6, verified: FETCH 266->66MB): the 8 blocks sharing one
// A-panel (same bm) land on the SAME XCD:
// bm-tile = x*4 + (y>>3), bn-tile = y&7 (linear id % 8 == x = XCD).
// ---------------------------------------------------------------------------
template <int NPASS, int MH, int NH>
__device__ __forceinline__ void phase_mfma(
    const unsigned short* __restrict__ shc, f32x4 (&acc)[8][4],
    int wm, int wn, int lm, int roff)
{
  bf16x8 aH[4], bH[2], aL[4], bL[2];
#pragma unroll
  for (int ii = 0; ii < 4; ++ii) {
    const int ar = (wm + (MH * 4 + ii) * 16 + lm) * 32 + roff;
    aH[ii] = *(const bf16x8*)(shc + ar);
    if constexpr (NPASS > 1) aL[ii] = *(const bf16x8*)(shc + 2 * 8192 + ar);
  }
#pragma unroll
  for (int jj = 0; jj < 2; ++jj) {
    const int br = (wn + (NH * 2 + jj) * 16 + lm) * 32 + roff;
    bH[jj] = *(const bf16x8*)(shc + 8192 + br);
    if constexpr (NPASS > 1) bL[jj] = *(const bf16x8*)(shc + 3 * 8192 + br);
  }
  __builtin_amdgcn_s_setprio(1);
#pragma unroll
  for (int ii = 0; ii < 4; ++ii)
#pragma unroll
    for (int jj = 0; jj < 2; ++jj) {
      const int i = MH * 4 + ii, j = NH * 2 + jj;
      acc[i][j] = __builtin_amdgcn_mfma_f32_16x16x32_bf16(aH[ii], bH[jj], acc[i][j], 0, 0, 0);
      if constexpr (NPASS > 1) {
        acc[i][j] = __builtin_amdgcn_mfma_f32_16x16x32_bf16(aH[ii], bL[jj], acc[i][j], 0, 0, 0);
        acc[i][j] = __builtin_amdgcn_mfma_f32_16x16x32_bf16(aL[ii], bH[jj], acc[i][j], 0, 0, 0);
      }
    }
  __builtin_amdgcn_s_setprio(0);
}

template <int NPASS>
__global__ __launch_bounds__(512, 2) void gemm_8ph(
    const unsigned short* __restrict__ Ap, const unsigned short* __restrict__ Bp,
    float* __restrict__ C, int K, int ldc)
{
  constexpr int NTEN = (NPASS > 1) ? 4 : 2;      // AH,BH[,AL,BL]
  __shared__ unsigned short sh[2][NTEN][256 * 32];
  const int tid = threadIdx.x;
  // XCD affinity: all 8 bn-blocks of a bm-panel on one XCD (x = XCD id)
  const int bm = (((blockIdx.x << 2) | (blockIdx.y >> 3)) << 8);
  const int bn = ((blockIdx.y & 7) << 8);
  const int K2 = K * 2;
  const int wave = tid >> 6, lane = tid & 63;
  const int wm = (wave >> 2) << 7;               // 0 / 128
  const int wn = (wave & 3) << 6;                // 0 / 64 / 128 / 192
  const int lm = lane & 15, quad = lane >> 4;
  const int roff = ((quad ^ ((lm >> 1) & 3)) << 3);

  const int r0 = tid >> 2;
  const int kq = (((tid & 3) ^ ((r0 >> 1) & 3)) << 3);
  const unsigned short* a0 = Ap + (size_t)(bm + r0) * K2 + kq;        // rows 0-127
  const unsigned short* a1 = a0 + (size_t)128 * K2;                   // rows 128-255
  const unsigned short* b0 = Bp + (size_t)(bn + r0) * K2 + kq;
  const unsigned short* b1 = b0 + (size_t)128 * K2;
  const int ls0 = tid * 8, ls1 = 4096 + tid * 8; // ushort offsets in a tensor buf

  f32x4 acc[8][4] = {};
  const int NT = K >> 5;

  // prologue: stage tile 0 into buffer 0
  {
    unsigned short* s = &sh[0][0][0];
    gl2lds16(a0, s + ls0);
    gl2lds16(a1, s + ls1);
    if constexpr (NPASS > 1) {
      gl2lds16(a0 + K, s + 2 * 8192 + ls0);
      gl2lds16(a1 + K, s + 2 * 8192 + ls1);
    }
    gl2lds16(b0, s + 8192 + ls0);
    gl2lds16(b1, s + 8192 + ls1);
    if constexpr (NPASS > 1) {
      gl2lds16(b0 + K, s + 3 * 8192 + ls0);
      gl2lds16(b1 + K, s + 3 * 8192 + ls1);
    }
  }

  for (int t = 0; t < NT - 1; ++t) {
    const unsigned short* cur = &sh[t & 1][0][0];
    unsigned short* nxt = &sh[(t + 1) & 1][0][0];
    const int kn = (t + 1) << 5;

    // ---- phase 0: issue next-tile A units, publish current tile ----
    gl2lds16(a0 + kn, nxt + ls0);
    gl2lds16(a1 + kn, nxt + ls1);
    if constexpr (NPASS > 1) {
      gl2lds16(a0 + K + kn, nxt + 2 * 8192 + ls0);
      gl2lds16(a1 + K + kn, nxt + 2 * 8192 + ls1);
      asm volatile("s_waitcnt vmcnt(4)" ::: "memory");  // current tile's 8 landed
    } else {
      asm volatile("s_waitcnt vmcnt(2)" ::: "memory");  // current tile's 4 landed
    }
    BARRIER_();
    phase_mfma<NPASS, 0, 0>(cur, acc, wm, wn, lm, roff);
    BARRIER_();
    // ---- phase 1: issue next-tile B units ----
    gl2lds16(b0 + kn, nxt + 8192 + ls0);
    gl2lds16(b1 + kn, nxt + 8192 + ls1);
    if constexpr (NPASS > 1) {
      gl2lds16(b0 + K + kn, nxt + 3 * 8192 + ls0);
      gl2lds16(b1 + K + kn, nxt + 3 * 8192 + ls1);
    }
    phase_mfma<NPASS, 0, 1>(cur, acc, wm, wn, lm, roff);
    BARRIER_();
    // ---- phase 2 ----
    phase_mfma<NPASS, 1, 0>(cur, acc, wm, wn, lm, roff);
    BARRIER_();
    // ---- phase 3 (trailing barrier protects next tile's stage overwrite) ----
    phase_mfma<NPASS, 1, 1>(cur, acc, wm, wn, lm, roff);
    BARRIER_();
  }

  // peeled last tile: nothing left to issue -> drain is allowed here only
  {
    const unsigned short* cur = &sh[(NT - 1) & 1][0][0];
    asm volatile("s_waitcnt vmcnt(0)" ::: "memory");
    BARRIER_();
    phase_mfma<NPASS, 0, 0>(cur, acc, wm, wn, lm, roff);
    BARRIER_();
    phase_mfma<NPASS, 0, 1>(cur, acc, wm, wn, lm, roff);
    BARRIER_();
    phase_mfma<NPASS, 1, 0>(cur, acc, wm, wn, lm, roff);
    BARRIER_();
    phase_mfma<NPASS, 1, 1>(cur, acc, wm, wn, lm, roff);
  }

  // epilogue: C/D layout col=lane&15 (n), row=quad*4+reg (m)
#pragma unroll
  for (int i = 0; i < 8; ++i) {
    const int m = bm + wm + i * 16 + quad * 4;
#pragma unroll
    for (int j = 0; j < 4; ++j) {
      const int n = bn + wn + j * 16 + lm;
#pragma unroll
      for (int r = 0; r < 4; ++r)
        C[(size_t)(m + r) * ldc + n] = acc[i][j][r];
    }
  }
}

// ---------------------------------------------------------------------------
// Split-bf16 MFMA GEMM (m97-style 128x128) — gemm8 (structural floor 116µs).
// A_PACKED=1: A is u32 (lo<<16|hi) from scan_pass3; staging de-interleaves
// in-register (~32 bitfield VALU/thread/tile).
// XCD AFFINITY (r7-verified: FETCH 266->66MB): bm-tile = (bx<<3)|(by>>3),
// bn-tile = by&7 -> the 8 bn-blocks of each A-panel co-XCD.
// ---------------------------------------------------------------------------
template <int NPASS, int A_PACKED>
__global__ __launch_bounds__(256) void gemm_mfma(
    const void* __restrict__ Avp, const unsigned short* __restrict__ Bp,
    float* __restrict__ C, int K, int ldc)
{
  __shared__ unsigned short AsH[128 * 32];
  __shared__ unsigned short BsH[128 * 32];
  __shared__ unsigned short AsL[(NPASS > 1) ? 128 * 32 : 8];
  __shared__ unsigned short BsL[(NPASS > 1) ? 128 * 32 : 8];
  const int tid = threadIdx.x;
  // bm-panel-per-XCD affinity (x = XCD id under x-fastest linear dispatch)
  const int bm = (((blockIdx.x << 3) | (blockIdx.y >> 3)) << 7);
  const int bn = ((blockIdx.y & 7) << 7);
  const int K2 = K * 2;

  const int wave = tid >> 6, lane = tid & 63;
  const int wm = (wave >> 1) << 6, wn = (wave & 1) << 6;
  const int lm = lane & 15, quad = lane >> 4;
  const int sw = (lm >> 1) & 3;        // reader swizzle (row>>1)&3 == (lm>>1)&3

  f32x4 acc[4][4] = {};

  const int r0 = tid >> 2;
  const int kq = ((tid & 3) ^ ((r0 >> 1) & 3)) << 3;   // element offset
  const unsigned short* BgH0 = Bp + (size_t)(bn + r0) * K2 + kq;
  const unsigned short* BgH1 = Bp + (size_t)(bn + 64 + r0) * K2 + kq;
  unsigned short* lA0 = &AsH[(size_t)tid * 8];
  unsigned short* lA1 = &AsH[(size_t)(256 + tid) * 8];
  unsigned short* lB0 = &BsH[(size_t)tid * 8];
  unsigned short* lB1 = &BsH[(size_t)(256 + tid) * 8];
  unsigned short* lAl0 = (NPASS > 1) ? &AsL[(size_t)tid * 8] : nullptr;
  unsigned short* lAl1 = (NPASS > 1) ? &AsL[(size_t)(256 + tid) * 8] : nullptr;
  unsigned short* lBl0 = (NPASS > 1) ? &BsL[(size_t)tid * 8] : nullptr;
  unsigned short* lBl1 = (NPASS > 1) ? &BsL[(size_t)(256 + tid) * 8] : nullptr;

  const unsigned short* AgH0 = nullptr; const unsigned short* AgH1 = nullptr;
  const unsigned int* Apk0 = nullptr; const unsigned int* Apk1 = nullptr;
  if (A_PACKED) {
    const unsigned int* Au = (const unsigned int*)Avp;
    Apk0 = Au + (size_t)(bm + r0) * K + kq;
    Apk1 = Au + (size_t)(bm + 64 + r0) * K + kq;
  } else {
    const unsigned short* Ab = (const unsigned short*)Avp;
    AgH0 = Ab + (size_t)(bm + r0) * K2 + kq;
    AgH1 = Ab + (size_t)(bm + 64 + r0) * K2 + kq;
  }

  for (int k0 = 0; k0 < K; k0 += 32) {
    __syncthreads();
    if (A_PACKED) {
      uint4 u0 = *(const uint4*)(Apk0 + k0);
      uint4 u1 = *(const uint4*)(Apk0 + k0 + 4);
      uint4 v0 = *(const uint4*)(Apk1 + k0);
      uint4 v1 = *(const uint4*)(Apk1 + k0 + 4);
      unsigned p[8] = {u0.x, u0.y, u0.z, u0.w, u1.x, u1.y, u1.z, u1.w};
      unsigned q[8] = {v0.x, v0.y, v0.z, v0.w, v1.x, v1.y, v1.z, v1.w};
      unsigned hu[4], lu[4], hv[4], lv[4];
#pragma unroll
      for (int c = 0; c < 4; ++c) {
        hu[c] = (p[2*c] & 0xffffu) | (p[2*c+1] << 16);
        lu[c] = (p[2*c] >> 16)     | (p[2*c+1] & 0xffff0000u);
        hv[c] = (q[2*c] & 0xffffu) | (q[2*c+1] << 16);
        lv[c] = (q[2*c] >> 16)     | (q[2*c+1] & 0xffff0000u);
      }
      *(uint4*)lA0  = make_uint4(hu[0], hu[1], hu[2], hu[3]);
      *(uint4*)lA1  = make_uint4(hv[0], hv[1], hv[2], hv[3]);
      if (NPASS > 1) {
        *(uint4*)lAl0 = make_uint4(lu[0], lu[1], lu[2], lu[3]);
        *(uint4*)lAl1 = make_uint4(lv[0], lv[1], lv[2], lv[3]);
      }
    } else {
      gl2lds16(AgH0 + k0, lA0);
      gl2lds16(AgH1 + k0, lA1);
      if (NPASS > 1) {
        gl2lds16(AgH0 + K + k0, lAl0);
        gl2lds16(AgH1 + K + k0, lAl1);
      }
    }
    gl2lds16(BgH0 + k0, lB0);
    gl2lds16(BgH1 + k0, lB1);
    if (NPASS > 1) {
      gl2lds16(BgH0 + K + k0, lBl0);
      gl2lds16(BgH1 + K + k0, lBl1);
    }
    __syncthreads();

    bf16x8 aH[4], bH[4];
#pragma unroll
    for (int i = 0; i < 4; ++i)
      aH[i] = *(const bf16x8*)&AsH[(wm + i * 16 + lm) * 32 + ((quad ^ sw) << 3)];
#pragma unroll
    for (int j = 0; j < 4; ++j)
      bH[j] = *(const bf16x8*)&BsH[(wn + j * 16 + lm) * 32 + ((quad ^ sw) << 3)];
#pragma unroll
    for (int i = 0; i < 4; ++i)
#pragma unroll
      for (int j = 0; j < 4; ++j)
        acc[i][j] = __builtin_amdgcn_mfma_f32_16x16x32_bf16(aH[i], bH[j], acc[i][j], 0, 0, 0);
    if (NPASS > 1) {
      bf16x8 aL[4], bL[4];
#pragma unroll
      for (int i = 0; i < 4; ++i)
        aL[i] = *(const bf16x8*)&AsL[(wm + i * 16 + lm) * 32 + ((quad ^ sw) << 3)];
#pragma unroll
      for (int j = 0; j < 4; ++j)
        bL[j] = *(const bf16x8*)&BsL[(wn + j * 16 + lm) * 32 + ((quad ^ sw) << 3)];
#pragma unroll
      for (int i = 0; i < 4; ++i)
#pragma unroll
        for (int j = 0; j < 4; ++j) {
          acc[i][j] = __builtin_amdgcn_mfma_f32_16x16x32_bf16(aH[i], bL[j], acc[i][j], 0, 0, 0);
          acc[i][j] = __builtin_amdgcn_mfma_f32_16x16x32_bf16(aL[i], bH[j], acc[i][j], 0, 0, 0);
        }
    }
  }

  // epilogue: C/D layout col=lane&15 (n, from B), row=quad*4+reg (m, from A)
#pragma unroll
  for (int i = 0; i < 4; ++i) {
    const int m = bm + wm + i * 16 + quad * 4;
#pragma unroll
    for (int j = 0; j < 4; ++j) {
      const int n = bn + wn + j * 16 + lm;
#pragma unroll
      for (int r = 0; r < 4; ++r)
        C[(size_t)(m + r) * ldc + n] = acc[i][j][r];
    }
  }
}

// ---------------------------------------------------------------------------
// fp32 NT GEMM (small shapes): C[M,N] = A[M,K]·B[N,K]^T. 64x64 tile, BK=16.
// EPI: 0 none, 1 softplus(acc + bias[n]). Split-K via blockIdx.z.
// NB2=1: one block column computes TWO n-tiles from one staged A-tile.
// ---------------------------------------------------------------------------
template <int EPI, int NB2>
__global__ __launch_bounds__(256) void gemm_nt(
    const float* __restrict__ A, int lda,
    const float* __restrict__ B, int ldb,
    float* __restrict__ C, int ldc,
    int N, int K, const float* __restrict__ bias, size_t cseg)
{
  constexpr int NBT = NB2 ? 2 : 1;
  __shared__ float As[16][68];
  __shared__ float Bs[NBT][16][68];
  const int tid = threadIdx.x;
  const int bm = blockIdx.y << 6;
  const int bn = blockIdx.x << 6;
  const int kz = blockIdx.z;
  A += (size_t)kz * K;
  B += (size_t)kz * K;
  C += (size_t)kz * cseg;
  const int lr = tid >> 2;
  const int lk = (tid & 3) << 2;
  const int tx = tid & 15, ty = tid >> 4;

  float acc[NBT][4][4];
#pragma unroll
  for (int nb = 0; nb < NBT; ++nb)
#pragma unroll
    for (int i = 0; i < 4; ++i)
#pragma unroll
      for (int j = 0; j < 4; ++j) acc[nb][i][j] = 0.f;

  const float* Apt  = A + (size_t)(bm + lr) * lda + lk;
  const float* Bpt0 = B + (size_t)(bn + lr) * ldb + lk;
  const float* Bpt1 = NB2 ? (B + (size_t)(bn + 64 + lr) * ldb + lk) : nullptr;
  const bool bv0 = (bn + lr) < N;
  const bool bv1 = NB2 ? ((bn + 64 + lr) < N) : false;

  for (int k0 = 0; k0 < K; k0 += 16) {
    float4 a4 = *(const float4*)(Apt + k0);
    float4 b40 = bv0 ? *(const float4*)(Bpt0 + k0) : make_float4(0.f, 0.f, 0.f, 0.f);
    float4 b41 = (NB2 && bv1) ? *(const float4*)(Bpt1 + k0) : make_float4(0.f, 0.f, 0.f, 0.f);
    __syncthreads();
    As[lk + 0][lr] = a4.x; As[lk + 1][lr] = a4.y;
    As[lk + 2][lr] = a4.z; As[lk + 3][lr] = a4.w;
    Bs[0][lk + 0][lr] = b40.x; Bs[0][lk + 1][lr] = b40.y;
    Bs[0][lk + 2][lr] = b40.z; Bs[0][lk + 3][lr] = b40.w;
    if (NB2) {
      Bs[1][lk + 0][lr] = b41.x; Bs[1][lk + 1][lr] = b41.y;
      Bs[1][lk + 2][lr] = b41.z; Bs[1][lk + 3][lr] = b41.w;
    }
    __syncthreads();
#pragma unroll
    for (int k = 0; k < 16; ++k) {
      const float4 av = *(const float4*)(&As[k][ty << 2]);
      float a4r[4] = {av.x, av.y, av.z, av.w};
#pragma unroll
      for (int nb = 0; nb < NBT; ++nb) {
        const float4 bw = *(const float4*)(&Bs[nb][k][tx << 2]);
        float b4r[4] = {bw.x, bw.y, bw.z, bw.w};
#pragma unroll
        for (int i = 0; i < 4; ++i)
#pragma unroll
          for (int j = 0; j < 4; ++j)
            acc[nb][i][j] = fmaf(a4r[i], b4r[j], acc[nb][i][j]);
      }
    }
  }

  const int m = bm + (ty << 2);
#pragma unroll
  for (int nb = 0; nb < NBT; ++nb) {
    const int n = bn + nb * 64 + (tx << 2);
#pragma unroll
    for (int i = 0; i < 4; ++i) {
      float v[4] = {acc[nb][i][0], acc[nb][i][1], acc[nb][i][2], acc[nb][i][3]};
      if (EPI == 1) {
#pragma unroll
        for (int j = 0; j < 4; ++j)
          if (n + j < N) v[j] = softplus_(v[j] + bias[n + j]);
      }
      if (n + 3 < N) {
        *(float4*)(C + (size_t)(m + i) * ldc + n) = make_float4(v[0], v[1], v[2], v[3]);
      } else {
#pragma unroll
        for (int j = 0; j < 4; ++j)
          if (n + j < N) C[(size_t)(m + i) * ldc + n + j] = v[j];
      }
    }
  }
}

// ---------------------------------------------------------------------------
// 4-way split-K reduce: O[i] = sum_z P[z*seg + i], over n4 float4s.
// ---------------------------------------------------------------------------
__global__ __launch_bounds__(256) void reduce4(
    const float* __restrict__ P, float* __restrict__ O, size_t seg)
{
  const size_t i = ((size_t)blockIdx.x << 8) + threadIdx.x;
  float4 a = ((const float4*)P)[i];
  float4 b = ((const float4*)(P + seg))[i];
  float4 c = ((const float4*)(P + 2 * seg))[i];
  float4 d = ((const float4*)(P + 3 * seg))[i];
  ((float4*)O)[i] = make_float4(a.x + b.x + c.x + d.x,
                                a.y + b.y + c.y + d.y,
                                a.z + b.z + c.z + d.z,
                                a.w + b.w + c.w + d.w);
}

// ---------------------------------------------------------------------------
// Channel alignment features (rfft2 16x16 magnitude band ratio). X stride 2048.
// ---------------------------------------------------------------------------
__global__ __launch_bounds__(256) void feat_kernel(
    const float* __restrict__ X, float* __restrict__ features)
{
  __shared__ float xin[256][17];
  __shared__ float Rf[16 * 315];
  __shared__ float tc[16], ts[16];
  __shared__ float part2[16][16][2];

  const int tid = threadIdx.x;
  const int frame = blockIdx.x >> 7;
  const int cg = blockIdx.x & 127;
  const int b = frame >> 3, t = frame & 7;
  const int c0 = cg << 4;

  if (tid < 16) {
    float ang = 0.39269908169872414f * (float)tid;
    tc[tid] = cosf(ang);
    ts[tid] = sinf(ang);
  }
  const float* xb = X + ((size_t)(b * LSEQ + t * 256) << 11) + c0;
  for (int i = tid; i < 256 * 16; i += 256) {
    int hw = i >> 4, ci = i & 15;
    xin[hw][ci] = xb[((size_t)hw << 11) + ci];
  }
  __syncthreads();

  {
    const int ci = tid & 15, h = tid >> 4;
    float re[9], im[9];
#pragma unroll
    for (int kw = 0; kw < 9; ++kw) { re[kw] = 0.f; im[kw] = 0.f; }
#pragma unroll
    for (int w = 0; w < 16; ++w) {
      float x = xin[(h << 4) + w][ci];
#pragma unroll
      for (int kw = 0; kw < 9; ++kw) {
        int ph = (kw * w) & 15;
        re[kw] = fmaf(x, tc[ph], re[kw]);
        im[kw] = fmaf(-x, ts[ph], im[kw]);
      }
    }
#pragma unroll
    for (int kw = 0; kw < 9; ++kw) {
      Rf[ci * 315 + kw * 35 + 2 * h]     = re[kw];
      Rf[ci * 315 + kw * 35 + 2 * h + 1] = im[kw];
    }
  }
  __syncthreads();

  {
    const int ci = tid & 15, kh = tid >> 4;
    float ut = 0.f, tt = 0.f;
    for (int kw = 0; kw < 9; ++kw) {
      float fre = 0.f, fim = 0.f;
#pragma unroll
      for (int h = 0; h < 16; ++h) {
        int ph = (kh * h) & 15;
        float c = tc[ph], s = ts[ph];
        float rr = Rf[ci * 315 + kw * 35 + 2 * h];
        float ri = Rf[ci * 315 + kw * 35 + 2 * h + 1];
        fre += rr * c + ri * s;
        fim += ri * c - rr * s;
      }
      float mag = sqrtf(fre * fre + fim * fim + 1e-8f);
      int sh = (kh + 8) & 15;
      int sw2 = kw + 4; if (sw2 >= 9) sw2 -= 9;
      float dh = (float)(sh - 8) / 16.0f;
      float dw = (float)(sw2 - 4) / 9.0f;
      tt += mag;
      if (dh * dh + dw * dw >= 0.25f) ut += mag;
    }
    part2[ci][kh][0] = ut;
    part2[ci][kh][1] = tt;
  }
  __syncthreads();

  if (tid < 16) {
    float ut = 0.f, tt = 0.f;
    for (int kh = 0; kh < 16; ++kh) { ut += part2[tid][kh][0]; tt += part2[tid][kh][1]; }
    features[frame * DI + c0 + tid] = ut / (tt + 1e-8f);
  }
}

// ---------------------------------------------------------------------------
// alpha split (r9): the old 1-block alpha_kernel serialized 512KB of feats
// reads + ~30 barriers on a single CU. Split:
//  alpha_pre (8 blocks): md[d] = mean_i feats  +  per-block pn[i] partials
//  alpha_mid (8 blocks): gd[d] = sum_i feats*invn[i]; per-block gsq partials
//  alpha_fin (1 block) : loss + softmax(md) + A_log stats + Aws
// Aws path is bit-identical (depends on md + A_log only, same order);
// loss scalar differs by summation-order ulps only.
// ---------------------------------------------------------------------------
__global__ __launch_bounds__(256) void alpha_pre(
    const float* __restrict__ feats, float* __restrict__ md_o,
    float* __restrict__ pnp)
{
  __shared__ float wp[4][32];
  const int tid = threadIdx.x;
  const int d = (blockIdx.x << 8) + tid;
  const int lane = tid & 63, wave = tid >> 6;
  float md = 0.f;
#pragma unroll
  for (int i = 0; i < 32; ++i) {
    float v = feats[(i << 11) + d];
    md += v;
    float sq = v * v;
#pragma unroll
    for (int o = 1; o < 64; o <<= 1) sq += __shfl_xor(sq, o, 64);
    if (lane == 0) wp[wave][i] = sq;
  }
  md_o[d] = md * (1.f / 32.f);
  __syncthreads();
  if (tid < 32)
    pnp[(blockIdx.x << 5) + tid] = wp[0][tid] + wp[1][tid] + wp[2][tid] + wp[3][tid];
}

__global__ __launch_bounds__(256) void alpha_mid(
    const float* __restrict__ feats, const float* __restrict__ pnp,
    float* __restrict__ gsqp)
{
  __shared__ float invn[32];
  __shared__ float red[256];
  const int tid = threadIdx.x;
  const int d = (blockIdx.x << 8) + tid;
  if (tid < 32) {
    float s = 0.f;
    for (int b = 0; b < 8; ++b) s += pnp[(b << 5) + tid];
    invn[tid] = 1.f / fmaxf(sqrtf(s), 1e-12f);
  }
  __syncthreads();
  float gd = 0.f;
#pragma unroll
  for (int i = 0; i < 32; ++i)
    gd = fmaf(feats[(i << 11) + d], invn[i], gd);
  red[tid] = gd * gd;
  __syncthreads();
  for (int s = 128; s > 0; s >>= 1) { if (tid < s) red[tid] += red[tid + s]; __syncthreads(); }
  if (tid == 0) gsqp[blockIdx.x] = red[0];
}

__global__ __launch_bounds__(256) void alpha_fin(
    const float* __restrict__ md_ws, const float* __restrict__ gsqp,
    const float* __restrict__ A_log, float* __restrict__ Aws,
    float* __restrict__ loss_out)
{
  __shared__ float red[256];
  __shared__ float AM[256][17];
  __shared__ float sAmax[16], sAmin[16];
  const int tid = threadIdx.x;

  if (tid == 0) {
    float s = 0.f;
    for (int b = 0; b < 8; ++b) s += gsqp[b];
    loss_out[0] = 1.f - s * (1.f / 1024.f);
  }

  float md[8];
#pragma unroll
  for (int j = 0; j < 8; ++j) md[j] = md_ws[tid + (j << 8)];

  float lm = md[0];
#pragma unroll
  for (int j = 1; j < 8; ++j) lm = fmaxf(lm, md[j]);
  red[tid] = lm; __syncthreads();
  for (int s = 128; s > 0; s >>= 1) { if (tid < s) red[tid] = fmaxf(red[tid], red[tid + s]); __syncthreads(); }
  const float mmax = red[0]; __syncthreads();

  float p[8]; float ps = 0.f;
#pragma unroll
  for (int j = 0; j < 8; ++j) { p[j] = __expf(md[j] - mmax); ps += p[j]; }
  red[tid] = ps; __syncthreads();
  for (int s = 128; s > 0; s >>= 1) { if (tid < s) red[tid] += red[tid + s]; __syncthreads(); }
  const float psum = red[0]; __syncthreads();

  float amaxl[16], aminl[16], rn[8];
#pragma unroll
  for (int n = 0; n < 16; ++n) { amaxl[n] = -1e30f; aminl[n] = 1e30f; }
#pragma unroll
  for (int j = 0; j < 8; ++j) {
    const int d = tid + (j << 8);
    float ss = 0.f;
#pragma unroll
    for (int n = 0; n < 16; ++n) {
      float a = A_log[(d << 4) + n];
      float e = __expf(a);
      ss = fmaf(e, e, ss);
      amaxl[n] = fmaxf(amaxl[n], a);
      aminl[n] = fminf(aminl[n], a);
    }
    rn[j] = sqrtf(ss);
  }
  float rm = rn[0];
#pragma unroll
  for (int j = 1; j < 8; ++j) rm = fmaxf(rm, rn[j]);
  red[tid] = rm; __syncthreads();
  for (int s = 128; s > 0; s >>= 1) { if (tid < s) red[tid] = fmaxf(red[tid], red[tid + s]); __syncthreads(); }
  const float rnmax = red[0]; __syncthreads();

#pragma unroll
  for (int n = 0; n < 16; ++n) AM[tid][n] = amaxl[n];
  __syncthreads();
  if (tid < 16) { float m = -1e30f; for (int i = 0; i < 256; ++i) m = fmaxf(m, AM[i][tid]); sAmax[tid] = m; }
  __syncthreads();
#pragma unroll
  for (int n = 0; n < 16; ++n) AM[tid][n] = aminl[n];
  __syncthreads();
  if (tid < 16) { float m = 1e30f; for (int i = 0; i < 256; ++i) m = fminf(m, AM[i][tid]); sAmin[tid] = m; }
  __syncthreads();

  const float irn = 1.f / (rnmax + 1e-8f);
#pragma unroll
  for (int j = 0; j < 8; ++j) {
    const int d = tid + (j << 8);
    const float att = rn[j] * irn;
    const float f = p[j] / psum;
    const float alpha = fminf(fmaxf(f * (1.f - att), 0.f), 1.f);
#pragma unroll
    for (int n = 0; n < 16; ++n) {
      float a = A_log[(d << 4) + n];
      float fl = sAmax[n] + sAmin[n] - a;
      float an = (1.f - alpha) * a + alpha * fl;
      // pre-fold log2(e) so scan kernels can use native v_exp_f32 (exp2)
      Aws[(d << 4) + n] = -__expf(an) * 1.4426950408889634f;
    }
  }
}

// ---------------------------------------------------------------------------
// Depthwise causal conv (k=4) + bias + SiLU.
// r9: 4 consecutive l per thread -> 7 staged loads per 4 outputs (was 4/1),
// cutting X read traffic ~2.3x. Same fma order per output -> bit-identical.
// X (b,l,2048) -> U (b,l,2048)
// ---------------------------------------------------------------------------
__global__ __launch_bounds__(256) void conv_kernel(
    const float* __restrict__ X, const float* __restrict__ cw,
    const float* __restrict__ cb, float* __restrict__ U)
{
  const size_t gid = ((size_t)blockIdx.x << 8) + threadIdx.x;  // < 1,048,576
  const int e4 = (int)(gid & 511);
  const size_t rowg = gid >> 9;        // b*512 + lg
  const int lg = (int)(rowg & 511);
  const size_t b = rowg >> 9;
  const int l0 = lg << 2;
  const size_t row0 = ((size_t)b << 11) + l0;   // b*2048 + l0
  const float* xr = X + (row0 << 11) + (e4 << 2);

  float xf[7][4];
  if (lg > 0) {
#pragma unroll
    for (int k = 0; k < 3; ++k) {
      float4 v = *(const float4*)(xr + (ptrdiff_t)(k - 3) * 2048);
      xf[k][0] = v.x; xf[k][1] = v.y; xf[k][2] = v.z; xf[k][3] = v.w;
    }
  } else {
#pragma unroll
    for (int k = 0; k < 3; ++k) { xf[k][0] = xf[k][1] = xf[k][2] = xf[k][3] = 0.f; }
  }
#pragma unroll
  for (int k = 3; k < 7; ++k) {
    float4 v = *(const float4*)(xr + (ptrdiff_t)(k - 3) * 2048);
    xf[k][0] = v.x; xf[k][1] = v.y; xf[k][2] = v.z; xf[k][3] = v.w;
  }

  const float4* cwf = (const float4*)cw;
  float4 w4[4];
#pragma unroll
  for (int c = 0; c < 4; ++c) w4[c] = cwf[(e4 << 2) + c];
  float4 bi = *(const float4*)(cb + (e4 << 2));
  float bia[4] = {bi.x, bi.y, bi.z, bi.w};

#pragma unroll
  for (int j = 0; j < 4; ++j) {
    float o[4];
#pragma unroll
    for (int c = 0; c < 4; ++c) {
      float acc = bia[c];
      acc = fmaf(xf[j][c],     w4[c].x, acc);   // x[l-3]
      acc = fmaf(xf[j + 1][c], w4[c].y, acc);   // x[l-2]
      acc = fmaf(xf[j + 2][c], w4[c].z, acc);   // x[l-1]
      acc = fmaf(xf[j + 3][c], w4[c].w, acc);   // x[l]
      o[c] = silu_(acc);
    }
    *(float4*)(U + ((row0 + j) << 11) + (e4 << 2)) =
        make_float4(o[0], o[1], o[2], o[3]);
  }
}

// ---------------------------------------------------------------------------
// Chunked selective scan (delta in X region stride 2048, z in Z stride 2048).
// Aws carries log2(e) factor -> exp2 (single v_exp_f32, no mul).
// ---------------------------------------------------------------------------
__global__ __launch_bounds__(256) void scan_pass1(
    const float* __restrict__ delta, const float* __restrict__ U,
    const float* __restrict__ xdbl, const float* __restrict__ Aws,
    float* __restrict__ cs, float* __restrict__ sdt)
{
  __shared__ float blds[CL * 16];
  const int tid = threadIdx.x;
  const int dg = blockIdx.x & 7;
  const int chunk = (blockIdx.x >> 3) & 31;
  const int b = blockIdx.x >> 8;
  const int d = (dg << 8) | tid;
  const int l0 = chunk * CL;

  for (int i = tid; i < CL * 16; i += 256) {
    int l = i >> 4, j = i & 15;
    blds[i] = xdbl[(size_t)(b * LSEQ + l0 + l) * 96 + 64 + j];
  }
  __syncthreads();

  float Ar[16];
#pragma unroll
  for (int n = 0; n < 16; ++n) Ar[n] = Aws[(d << 4) + n];
  float s[16];
#pragma unroll
  for (int n = 0; n < 16; ++n) s[n] = 0.f;
  float sumdt = 0.f;

  const float* dp = delta + ((size_t)b << 22) + ((size_t)l0 << 11) + d;
  const float* up = U + ((size_t)b << 22) + ((size_t)l0 << 11) + d;

  for (int l = 0; l < CL; ++l) {
    const float dt = dp[(size_t)l << 11];
    const float u = up[(size_t)l << 11];
    sumdt += dt;
    const float du = dt * u;
    const float* bl = &blds[l << 4];
#pragma unroll
    for (int n = 0; n < 16; ++n)
      s[n] = fmaf(s[n], __builtin_amdgcn_exp2f(dt * Ar[n]), du * bl[n]);
  }

  float* csp = cs + ((((size_t)b * NC + chunk) * 2048 + d) << 4);
#pragma unroll
  for (int n = 0; n < 4; ++n)
    *(float4*)(csp + (n << 2)) = make_float4(s[4*n], s[4*n+1], s[4*n+2], s[4*n+3]);
  sdt[((size_t)b * NC + chunk) * 2048 + d] = sumdt;
}

// one thread per (b, d, n) — 16x parallelism (r8-verified). Bit-identical.
__global__ __launch_bounds__(256) void scan_mid(
    float* __restrict__ cs, const float* __restrict__ sdt,
    const float* __restrict__ Aws)
{
  const int gid = (blockIdx.x << 8) + threadIdx.x;   // < 131072
  const int n = gid & 15;
  const int d = (gid >> 4) & 2047;
  const int b = gid >> 15;
  const float Ar = Aws[(d << 4) + n];
  float si = 0.f;

  for (int c = 0; c < NC; ++c) {
    const size_t base = ((size_t)b * NC + c) * 2048 + d;
    float* p = cs + (base << 4) + n;
    const float sl = *p;
    const float sm = sdt[base];
    *p = si;
    si = fmaf(si, __builtin_amdgcn_exp2f(sm * Ar), sl);
  }
}

// scan_pass3 writes y as PACKED u32 (lo_bf16<<16 | hi_bf16) into the same U
// slot it reads u from (same thread, read-then-write, no cross-block hazard).
// gemm_mfma<3,1> (A_PACKED) consumes this directly -> no fp32 split in GEMM.
__global__ __launch_bounds__(256) void scan_pass3(
    const float* __restrict__ delta, const float* __restrict__ Z,
    float* __restrict__ U,
    const float* __restrict__ xdbl, const float* __restrict__ Aws,
    const float* __restrict__ Dp, const float* __restrict__ cs)
{
  __shared__ float bclds[CL * 32];
  const int tid = threadIdx.x;
  const int dg = blockIdx.x & 7;
  const int chunk = (blockIdx.x >> 3) & 31;
  const int b = blockIdx.x >> 8;
  const int d = (dg << 8) | tid;
  const int l0 = chunk * CL;

  for (int i = tid; i < CL * 32; i += 256) {
    int l = i >> 5, j = i & 31;
    bclds[i] = xdbl[(size_t)(b * LSEQ + l0 + l) * 96 + 64 + j];
  }
  __syncthreads();

  float Ar[16];
#pragma unroll
  for (int n = 0; n < 16; ++n) Ar[n] = Aws[(d << 4) + n];
  const float Dd = Dp[d];

  const float* csp = cs + ((((size_t)b * NC + chunk) * 2048 + d) << 4);
  float s[16];
#pragma unroll
  for (int n = 0; n < 4; ++n) {
    float4 v = *(const float4*)(csp + (n << 2));
    s[4*n] = v.x; s[4*n+1] = v.y; s[4*n+2] = v.z; s[4*n+3] = v.w;
  }

  const float* dp = delta + ((size_t)b << 22) + ((size_t)l0 << 11) + d;
  const float* zp = Z + ((size_t)b << 22) + ((size_t)l0 << 11) + d;
  float* up = U + ((size_t)b << 22) + ((size_t)l0 << 11) + d;

  for (int l = 0; l < CL; ++l) {
    const float dt = dp[(size_t)l << 11];
    const float u = up[(size_t)l << 11];
    const float z = zp[(size_t)l << 11];
    const float du = dt * u;
    const float* bcl = &bclds[l << 5];
    float y = 0.f;
#pragma unroll
    for (int n = 0; n < 16; ++n) {
      s[n] = fmaf(s[n], __builtin_amdgcn_exp2f(dt * Ar[n]), du * bcl[n]);
      y = fmaf(s[n], bcl[16 + n], y);
    }
    const float yv = fmaf(u, Dd, y);
    const float yo = yv * silu_(z);
    const unsigned short h = f2bf(yo);
    const unsigned short lo = f2bf(yo - bf2f(h));
    ((unsigned int*)up)[(size_t)l << 11] = (unsigned)h | ((unsigned)lo << 16);
  }
}

// ---------------------------------------------------------------------------
extern "C" void kernel_launch(void* const* d_in, const int* in_sizes, int n_in,
                              void* d_out, int out_size, void* d_ws, size_t ws_size,
                              hipStream_t stream)
{
  const float* hs         = (const float*)d_in[0];
  const float* in_proj_w  = (const float*)d_in[4];
  const float* conv_w     = (const float*)d_in[5];
  const float* conv_b     = (const float*)d_in[6];
  const float* x_proj_w   = (const float*)d_in[7];
  const float* dt_proj_w  = (const float*)d_in[8];
  const float* dt_proj_b  = (const float*)d_in[9];
  const float* A_log      = (const float*)d_in[10];
  const float* Dp         = (const float*)d_in[11];
  const float* out_proj_w = (const float*)d_in[12];
  float* out = (float*)d_out;
  float* ws = (float*)d_ws;

  float* X     = ws + OFF_X;
  float* Z     = ws + OFF_Z;
  float* U     = ws + OFF_U;
  float* cs    = ws + OFF_CS;
  float* sdt   = ws + OFF_SDT;
  float* xdbl  = ws + OFF_XDBL;
  float* feats = ws + OFF_FEAT;
  float* Aws   = ws + OFF_AWS;
  float* md_ws = ws + OFF_ALP;
  float* pnp   = md_ws + 2048;
  float* gsqp  = pnp + 256;
  unsigned short* A1s = (unsigned short*)(ws + OFF_S);
  unsigned short* B1s = (unsigned short*)(ws + OFF_B1);
  unsigned short* B2s = (unsigned short*)(ws + OFF_B1);

  const dim3 blk(256);

  // 0. split hs (2,097,152 float4s) + in_proj_w (1,048,576 float4s)
  split2_w<<<12288, blk, 0, stream>>>(hs, A1s, 10, (size_t)2097152,
                                      in_proj_w, B1s, 10);
  // 1a. X half: hs @ in_proj_w[0:2048]^T, full 3-pass (M=8192,N=2048,K=1024)
  //     256^2-tile phase-split; bm-panel per XCD (A fetched once per XCD).
  gemm_8ph<3><<<dim3(8, 32), dim3(512), 0, stream>>>(A1s, B1s, X, 1024, 2048);
  // 1b. Z half: hs @ in_proj_w[2048:4096]^T, hi*hi only (silu-gate budget)
  gemm_8ph<1><<<dim3(8, 32), dim3(512), 0, stream>>>(A1s, B1s + (size_t)2048 * 2048, Z, 1024, 2048);
  // 2. channel-alignment features (reads X)
  feat_kernel<<<4096, blk, 0, stream>>>(X, feats);
  // 3. depthwise conv + silu (X -> U), 4 l per thread (r9 read-reuse)
  conv_kernel<<<4096, blk, 0, stream>>>(X, conv_w, conv_b, U);
  // 3b. split out_proj_w (524,288 float4s) -> 2048 blocks (overlays dead B1s)
  split2_w<<<2048, blk, 0, stream>>>(out_proj_w, B2s, 11, (size_t)524288,
                                     out_proj_w, B2s, 11);
  // 4. loss + alpha + A: 3-stage parallel split (r9)
  alpha_pre<<<8, blk, 0, stream>>>(feats, md_ws, pnp);
  alpha_mid<<<8, blk, 0, stream>>>(feats, pnp, gsqp);
  alpha_fin<<<1, blk, 0, stream>>>(md_ws, gsqp, A_log, Aws, out + 8388608);
  // 5. x_dbl = U @ x_proj_w^T (M=8192,N=96,K=2048) — split-K=4, dual-n-tile
  gemm_nt<0, 1><<<dim3(1, 128, 4), blk, 0, stream>>>(U, DI, x_proj_w, DI, cs, 96, 96, 512, nullptr, (size_t)786432);
  reduce4<<<768, blk, 0, stream>>>(cs, xdbl, (size_t)786432);
  // 6. delta = softplus(x_dbl[:, :64] @ dt_proj_w^T + b) -> X region (dead x)
  gemm_nt<1, 0><<<dim3(32, 128, 1), blk, 0, stream>>>(xdbl, 96, dt_proj_w, 64, X, DI, DI, 64, dt_proj_b, 0);
  // 7. chunked selective scan; y overwrites U as packed bf16 hi/lo u32
  scan_pass1<<<1024, blk, 0, stream>>>(X, U, xdbl, Aws, cs, sdt);
  scan_mid<<<512, blk, 0, stream>>>(cs, sdt, Aws);
  scan_pass3<<<1024, blk, 0, stream>>>(X, Z, U, xdbl, Aws, Dp, cs);
  // 8. out = y @ out_proj_w^T — proven 128x128 kernel, packed A,
  //    bm-panel-per-XCD affinity (FETCH 266->66MB verified r7).
  gemm_mfma<3, 1><<<dim3(8, 64), blk, 0, stream>>>(U, B2s, out, 2048, 1024);
}